// Round 8
// baseline (1240.124 us; speedup 1.0000x reference)
//
#include <hip/hip_runtime.h>
#include <hip/hip_bf16.h>
#include <hip/hip_fp16.h>

// GConvGRU with h=0 reduces to:
//   xagg = scatter_add(norm * x[src] -> dst)          [N,128]
//   z    = sigmoid(xagg @ W_xz + b_z)
//   ht   = tanh   (xagg @ W_xh + b_h)
//   out  = ((1-z)*ht) @ W_lin + b_lin                 [N,16]
// R6/R7 model (confirmed by WRITE_SIZE arithmetic): every scattered global
// write/atomic costs a 32B HBM write-through granule @ ~0.9TB/s.
// R8: zero per-edge scattered global writes:
//   partition edges by dst-range (LDS-histogram + LDS-cursor, contiguous
//   chunk writes) then per-range LDS f32 accumulation (ds_add, 2-way banks),
//   fp16 pre-scaled x rows, wsum in LDS (deg_in never materialized).

#define CH 128
#define HEADS 16
#define TM 64      // nodes per block in k_final2
#define KC 32      // K-chunk
#define DRANGE 12800   // deg histogram: nodes per range (4 ranges)
#define DSLICES 64     // deg histogram: edge slices per range
#define RN 98      // nodes per partition range
#define NR 512     // partition ranges (512*98 >= 50000)
#define NB 256     // partition blocks (edge slices)

// =============== deg_out: LDS histogram over src ===============
__global__ __launch_bounds__(256) void k_deg(const int* __restrict__ src,
                                             const float* __restrict__ w,
                                             float* __restrict__ partial, int E) {
    __shared__ float h[DRANGE];
    const int r = blockIdx.x / DSLICES;
    const int sl = blockIdx.x % DSLICES;
    const int base = r * DRANGE;
    for (int i = threadIdx.x; i < DRANGE; i += 256) h[i] = 0.f;
    __syncthreads();
    const int per = (E + DSLICES - 1) / DSLICES;
    const int lo = sl * per;
    const int hi = min(lo + per, E);
    int e = lo + threadIdx.x * 4;
    for (; e + 3 < hi; e += 1024) {
        int4 s4 = *reinterpret_cast<const int4*>(src + e);
        float4 w4 = *reinterpret_cast<const float4*>(w + e);
        int a;
        a = s4.x - base; if ((unsigned)a < DRANGE) atomicAdd(&h[a], w4.x);
        a = s4.y - base; if ((unsigned)a < DRANGE) atomicAdd(&h[a], w4.y);
        a = s4.z - base; if ((unsigned)a < DRANGE) atomicAdd(&h[a], w4.z);
        a = s4.w - base; if ((unsigned)a < DRANGE) atomicAdd(&h[a], w4.w);
    }
    for (; e < hi; ++e) {
        int a = src[e] - base;
        if ((unsigned)a < DRANGE) atomicAdd(&h[a], w[e]);
    }
    __syncthreads();
    float* dstp = partial + ((size_t)r * DSLICES + sl) * DRANGE;
    for (int i = threadIdx.x; i < DRANGE; i += 256) dstp[i] = h[i];
}

__global__ __launch_bounds__(256) void k_degred2(const float* __restrict__ partial,
                                                 float* __restrict__ deg_out, int n) {
    int i = blockIdx.x * blockDim.x + threadIdx.x;
    if (i >= n) return;
    int r = i / DRANGE;
    int idx = i - r * DRANGE;
    const float* p = partial + (size_t)r * DSLICES * DRANGE + idx;
    float s = 0.f;
#pragma unroll 8
    for (int sl = 0; sl < DSLICES; ++sl) s += p[(size_t)sl * DRANGE];
    deg_out[i] = s;
}

// =============== xh[s] = half(x[s] * rsqrt(deg_out[s])) ===============
__global__ __launch_bounds__(256) void k_xcast(const float* __restrict__ x,
                                               const float* __restrict__ deg_out,
                                               __half* __restrict__ xh, int n) {
    int idx = blockIdx.x * blockDim.x + threadIdx.x;
    int node = idx >> 4;
    if (node >= n) return;
    int c8 = (idx & 15) * 8;
    float dg = deg_out[node];
    float sc = dg > 0.f ? rsqrtf(dg) : 0.f;
    float4 a = *reinterpret_cast<const float4*>(x + (size_t)node * CH + c8);
    float4 b = *reinterpret_cast<const float4*>(x + (size_t)node * CH + c8 + 4);
    __half2 h0 = __floats2half2_rn(a.x * sc, a.y * sc);
    __half2 h1 = __floats2half2_rn(a.z * sc, a.w * sc);
    __half2 h2 = __floats2half2_rn(b.x * sc, b.y * sc);
    __half2 h3 = __floats2half2_rn(b.z * sc, b.w * sc);
    uint4 packed = make_uint4(*(unsigned*)&h0, *(unsigned*)&h1, *(unsigned*)&h2, *(unsigned*)&h3);
    *reinterpret_cast<uint4*>(xh + (size_t)node * CH + c8) = packed;
}

// =============== partition pass 1: per-block dst-range histogram ===============
__global__ __launch_bounds__(256) void k_count(const int* __restrict__ dst,
                                               unsigned* __restrict__ counts, int E) {
    __shared__ unsigned h[NR];
    const int b = blockIdx.x;
    for (int i = threadIdx.x; i < NR; i += 256) h[i] = 0u;
    __syncthreads();
    const int per = (E + NB - 1) / NB;
    const int lo = b * per;
    const int hi = min(lo + per, E);
    for (int e = lo + threadIdx.x; e < hi; e += 256)
        atomicAdd(&h[dst[e] / RN], 1u);
    __syncthreads();
    for (int i = threadIdx.x; i < NR; i += 256) counts[(size_t)i * NB + b] = h[i];
}

// per-range exclusive scan over blocks; counts[r][b] -> prefix, total[r] = sum
__global__ __launch_bounds__(256) void k_scanR(unsigned* __restrict__ counts,
                                               unsigned* __restrict__ total) {
    __shared__ unsigned s[256];
    const int r = blockIdx.x;
    const int t = threadIdx.x;
    unsigned v = counts[(size_t)r * NB + t];
    s[t] = v;
    __syncthreads();
    for (int ofs = 1; ofs < 256; ofs <<= 1) {
        unsigned u = (t >= ofs) ? s[t - ofs] : 0u;
        __syncthreads();
        s[t] += u;
        __syncthreads();
    }
    counts[(size_t)r * NB + t] = s[t] - v;   // exclusive
    if (t == 255) total[r] = s[255];
}

// exclusive scan of total[NR] -> rbase[NR]
__global__ __launch_bounds__(512) void k_scanT(const unsigned* __restrict__ total,
                                               unsigned* __restrict__ rbase) {
    __shared__ unsigned s[NR];
    const int t = threadIdx.x;
    unsigned v = total[t];
    s[t] = v;
    __syncthreads();
    for (int ofs = 1; ofs < NR; ofs <<= 1) {
        unsigned u = (t >= ofs) ? s[t - ofs] : 0u;
        __syncthreads();
        s[t] += u;
        __syncthreads();
    }
    rbase[t] = s[t] - v;
}

// =============== partition pass 2: scatter into contiguous chunks ===============
// rec2[pos] = { w(f32), dl<<16 | src }  (requires n <= 65536)
__global__ __launch_bounds__(256) void k_part(const int* __restrict__ src,
                                              const int* __restrict__ dst,
                                              const float* __restrict__ w,
                                              const unsigned* __restrict__ counts,
                                              const unsigned* __restrict__ rbase,
                                              int2* __restrict__ rec2, int E) {
    __shared__ unsigned cursor[NR];
    const int b = blockIdx.x;
    for (int r = threadIdx.x; r < NR; r += 256)
        cursor[r] = rbase[r] + counts[(size_t)r * NB + b];
    __syncthreads();
    const int per = (E + NB - 1) / NB;
    const int lo = b * per;
    const int hi = min(lo + per, E);
    for (int e = lo + threadIdx.x; e < hi; e += 256) {
        int d = dst[e];
        int r = d / RN;
        int dl = d - r * RN;
        unsigned pos = atomicAdd(&cursor[r], 1u);
        rec2[pos] = make_int2(__float_as_int(w[e]), (dl << 16) | src[e]);
    }
}

// =============== per-range LDS accumulation ===============
// block r: acc[RN][CH] f32 in LDS; records contiguous [rbase[r], +total[r]).
// Wave loads 64 records coalesced, broadcasts via shfl; lane owns ch {lane, lane+64}.
__global__ __launch_bounds__(256) void k_acc(const unsigned* __restrict__ rbase,
                                             const unsigned* __restrict__ total,
                                             const int2* __restrict__ rec2,
                                             const __half* __restrict__ xh,
                                             float* __restrict__ xagg, int n) {
    __shared__ float acc[RN * CH];
    __shared__ float wsum[RN];
    const int r = blockIdx.x;
    const int base_node = r * RN;
    if (base_node >= n) return;
    const int rn = min(RN, n - base_node);

    for (int i = threadIdx.x; i < rn * CH; i += 256) acc[i] = 0.f;
    for (int i = threadIdx.x; i < rn; i += 256) wsum[i] = 0.f;
    __syncthreads();

    const unsigned start = rbase[r];
    const unsigned end = start + total[r];
    const int wid = threadIdx.x >> 6;
    const int lane = threadIdx.x & 63;

    for (unsigned chunk = start + wid * 64u; chunk < end; chunk += 256u) {
        unsigned idx = chunk + lane;
        int2 myrec = (idx < end) ? rec2[idx] : make_int2(0, 0);
        int m = min(64u, end - chunk);
        for (int k = 0; k < m; ++k) {
            int rx = __shfl(myrec.x, k);
            int ry = __shfl(myrec.y, k);
            float wk = __int_as_float(rx);
            int sk = ry & 0xFFFF;
            int dl = ry >> 16;
            float v0 = __half2float(xh[(size_t)sk * CH + lane]);
            float v1 = __half2float(xh[(size_t)sk * CH + 64 + lane]);
            atomicAdd(&acc[dl * CH + lane], wk * v0);
            atomicAdd(&acc[dl * CH + 64 + lane], wk * v1);
            if (lane == 0) atomicAdd(&wsum[dl], wk);
        }
    }
    __syncthreads();

    // write out: float2 per thread
    for (int i = threadIdx.x; i < rn * 64; i += 256) {
        int node = i >> 6;
        int c2 = (i & 63) * 2;
        float ws = wsum[node];
        float sc = ws > 0.f ? rsqrtf(ws) : 0.f;
        float2 v = make_float2(acc[node * CH + c2] * sc, acc[node * CH + c2 + 1] * sc);
        *reinterpret_cast<float2*>(xagg + (size_t)(base_node + node) * CH + c2) = v;
    }
}

// =============== Tier B (CSR fallback, proven) ===============
__global__ __launch_bounds__(256) void k1B(const int* __restrict__ src,
                                           const int* __restrict__ dst,
                                           const float* __restrict__ w,
                                           float* __restrict__ deg_out,
                                           unsigned* __restrict__ cnt, int E) {
    int e = blockIdx.x * blockDim.x + threadIdx.x;
    if (e >= E) return;
    unsafeAtomicAdd(deg_out + src[e], w[e]);
    atomicAdd(cnt + dst[e], 1u);
}

__global__ __launch_bounds__(1024) void k_scan(unsigned* __restrict__ off, int n) {
    __shared__ unsigned s[1024];
    const int t = threadIdx.x;
    const int per = (n + 1023) / 1024;
    int lo = t * per;
    int hi = lo + per; if (hi > n) hi = n;
    unsigned sum = 0;
    for (int i = lo; i < hi; ++i) sum += off[i];
    s[t] = sum;
    __syncthreads();
    for (int ofs = 1; ofs < 1024; ofs <<= 1) {
        unsigned v = (t >= ofs) ? s[t - ofs] : 0u;
        __syncthreads();
        s[t] += v;
        __syncthreads();
    }
    unsigned run = s[t] - sum;
    for (int i = lo; i < hi; ++i) {
        unsigned c = off[i];
        off[i] = run;
        run += c;
    }
}

__global__ __launch_bounds__(256) void k_fillB(const int* __restrict__ src,
                                               const int* __restrict__ dst,
                                               const float* __restrict__ w,
                                               unsigned* __restrict__ off,
                                               int2* __restrict__ rec, int E) {
    int e = blockIdx.x * blockDim.x + threadIdx.x;
    if (e >= E) return;
    unsigned pos = atomicAdd(off + dst[e], 1u);
    rec[pos] = make_int2(__float_as_int(w[e]), src[e]);
}

__global__ __launch_bounds__(256) void k_gatherB(const unsigned* __restrict__ off,
                                                 const int2* __restrict__ rec,
                                                 const float* __restrict__ deg_out,
                                                 const float* __restrict__ x,
                                                 float* __restrict__ xagg, int n) {
    int node = blockIdx.x * 4 + (threadIdx.x >> 6);
    if (node >= n) return;
    int lane = threadIdx.x & 63;
    unsigned i = node ? off[node - 1] : 0u;
    unsigned end = off[node];
    float2 acc = make_float2(0.f, 0.f);
    float wsum = 0.f;
    for (; i < end; ++i) {
        int2 r0 = rec[i];
        float w0 = __int_as_float(r0.x);
        float d0 = deg_out[r0.y];
        float c0 = w0 * (d0 > 0.f ? rsqrtf(d0) : 0.f);
        float2 v = *reinterpret_cast<const float2*>(x + (size_t)r0.y * CH + lane * 2);
        wsum += w0;
        acc.x = fmaf(c0, v.x, acc.x);
        acc.y = fmaf(c0, v.y, acc.y);
    }
    float sc = wsum > 0.f ? rsqrtf(wsum) : 0.f;
    *reinterpret_cast<float2*>(xagg + (size_t)node * CH + lane * 2) =
        make_float2(acc.x * sc, acc.y * sc);
}

// =============== fused epilogue: tiled GEMM + gates + head (R4, proven) ===============
__global__ __launch_bounds__(256) void k_final2(const float* __restrict__ xagg,
                                                const float* __restrict__ Wxz,
                                                const float* __restrict__ bz,
                                                const float* __restrict__ Wxh,
                                                const float* __restrict__ bh,
                                                const float* __restrict__ Wlin,
                                                const float* __restrict__ blin,
                                                float* __restrict__ out, int n) {
    __shared__ float smem[10560];
    float* sA = smem;           // [64][36]
    float* sWz = smem + 2304;   // [32][128]
    float* sWh = smem + 6400;   // [32][128]

    const int tid = threadIdx.x;
    const int tx = tid & 31;
    const int ty = tid >> 5;
    const int base = blockIdx.x * TM;

    float az[8][4] = {{0.f}};
    float ah[8][4] = {{0.f}};

    for (int kc = 0; kc < CH; kc += KC) {
        {
            int i = tid;
#pragma unroll
            for (int r2 = 0; r2 < 2; ++r2, i += 256) {
                int row = i >> 3;
                int c4 = (i & 7) * 4;
                int grow = base + row; if (grow > n - 1) grow = n - 1;
                float4 v = *reinterpret_cast<const float4*>(xagg + (size_t)grow * CH + kc + c4);
                *reinterpret_cast<float4*>(&sA[row * 36 + c4]) = v;
            }
            int j = tid;
#pragma unroll
            for (int r2 = 0; r2 < 4; ++r2, j += 256) {
                int row = j >> 5;
                int c4 = (j & 31) * 4;
                *reinterpret_cast<float4*>(&sWz[row * 128 + c4]) =
                    *reinterpret_cast<const float4*>(Wxz + (size_t)(kc + row) * CH + c4);
                *reinterpret_cast<float4*>(&sWh[row * 128 + c4]) =
                    *reinterpret_cast<const float4*>(Wxh + (size_t)(kc + row) * CH + c4);
            }
        }
        __syncthreads();
#pragma unroll 4
        for (int kk = 0; kk < KC; ++kk) {
            float4 wz = *reinterpret_cast<float4*>(&sWz[kk * 128 + tx * 4]);
            float4 wh = *reinterpret_cast<float4*>(&sWh[kk * 128 + tx * 4]);
#pragma unroll
            for (int r = 0; r < 8; ++r) {
                float a = sA[(ty * 8 + r) * 36 + kk];
                az[r][0] = fmaf(a, wz.x, az[r][0]);
                az[r][1] = fmaf(a, wz.y, az[r][1]);
                az[r][2] = fmaf(a, wz.z, az[r][2]);
                az[r][3] = fmaf(a, wz.w, az[r][3]);
                ah[r][0] = fmaf(a, wh.x, ah[r][0]);
                ah[r][1] = fmaf(a, wh.y, ah[r][1]);
                ah[r][2] = fmaf(a, wh.z, ah[r][2]);
                ah[r][3] = fmaf(a, wh.w, ah[r][3]);
            }
        }
        __syncthreads();
    }

    float* sG = smem;
    const float4 bz4 = *reinterpret_cast<const float4*>(bz + tx * 4);
    const float4 bh4 = *reinterpret_cast<const float4*>(bh + tx * 4);
#pragma unroll
    for (int r = 0; r < 8; ++r) {
        int row = ty * 8 + r;
        float4 g4;
        float zp = az[r][0] + bz4.x, hp = ah[r][0] + bh4.x;
        g4.x = (1.f - 1.f / (1.f + __expf(-zp))) * tanhf(hp);
        zp = az[r][1] + bz4.y; hp = ah[r][1] + bh4.y;
        g4.y = (1.f - 1.f / (1.f + __expf(-zp))) * tanhf(hp);
        zp = az[r][2] + bz4.z; hp = ah[r][2] + bh4.z;
        g4.z = (1.f - 1.f / (1.f + __expf(-zp))) * tanhf(hp);
        zp = az[r][3] + bz4.w; hp = ah[r][3] + bh4.w;
        g4.w = (1.f - 1.f / (1.f + __expf(-zp))) * tanhf(hp);
        *reinterpret_cast<float4*>(&sG[row * 132 + tx * 4]) = g4;
    }
    __syncthreads();

#pragma unroll
    for (int it = 0; it < 4; ++it) {
        int idx = it * 256 + tid;
        int node = idx >> 4;
        int hh = idx & 15;
        float acc = blin[hh];
#pragma unroll 8
        for (int j = 0; j < CH; ++j)
            acc = fmaf(sG[node * 132 + j], Wlin[j * HEADS + hh], acc);
        if (base + node < n) out[(size_t)(base + node) * HEADS + hh] = acc;
    }
}

extern "C" void kernel_launch(void* const* d_in, const int* in_sizes, int n_in,
                              void* d_out, int out_size, void* d_ws, size_t ws_size,
                              hipStream_t stream) {
    const float* x = (const float*)d_in[0];
    const int* ei = (const int*)d_in[1];     // int32 on device (harness narrows int64)
    const float* w = (const float*)d_in[2];
    const float* Wxz = (const float*)d_in[3];
    const float* bz = (const float*)d_in[5];
    const float* Wxh = (const float*)d_in[9];
    const float* bh = (const float*)d_in[11];
    const float* Wlin = (const float*)d_in[12];
    const float* blin = (const float*)d_in[13];
    float* out = (float*)d_out;

    const int Nn = in_sizes[0] / CH;  // 50000
    const int E = in_sizes[2];        // 1,600,000

    const int* src = ei;
    const int* dst = ei + E;
    int eb = (E + 255) / 256;
    char* base = (char*)d_ws;

    // New-path layout:
    size_t off_counts = 0;                                     // NR*NB u32 = 512KB
    size_t off_total = off_counts + (size_t)NR * NB * 4;       // NR u32
    size_t off_rbase = off_total + NR * 4;                     // NR u32
    size_t off_deg = off_rbase + NR * 4;                       // N f32
    size_t off_xh = off_deg + (size_t)Nn * 4;                  // N*CH half
    size_t off_rec = off_xh + (size_t)Nn * CH * 2;             // E int2
    size_t off_xagg = off_rec + (size_t)E * 8;                 // N*CH f32 (deg partials overlay)
    size_t needNew = off_xagg + (size_t)Nn * CH * 4;
    size_t partial_bytes = (size_t)4 * DSLICES * DRANGE * 4;

    if (ws_size >= needNew && Nn <= 65536 && (size_t)NR * RN >= (size_t)Nn &&
        partial_bytes <= (size_t)Nn * CH * 4) {
        unsigned* counts = (unsigned*)(base + off_counts);
        unsigned* total = (unsigned*)(base + off_total);
        unsigned* rbase = (unsigned*)(base + off_rbase);
        float* deg_out = (float*)(base + off_deg);
        __half* xh = (__half*)(base + off_xh);
        int2* rec2 = (int2*)(base + off_rec);
        float* xagg = (float*)(base + off_xagg);
        float* partial = xagg;  // overlay: dead after k_degred2

        k_deg<<<4 * DSLICES, 256, 0, stream>>>(src, w, partial, E);
        k_degred2<<<(Nn + 255) / 256, 256, 0, stream>>>(partial, deg_out, Nn);
        k_xcast<<<(Nn * 16 + 255) / 256, 256, 0, stream>>>(x, deg_out, xh, Nn);
        k_count<<<NB, 256, 0, stream>>>(dst, counts, E);
        k_scanR<<<NR, 256, 0, stream>>>(counts, total);
        k_scanT<<<1, NR, 0, stream>>>(total, rbase);
        k_part<<<NB, 256, 0, stream>>>(src, dst, w, counts, rbase, rec2, E);
        k_acc<<<NR, 256, 0, stream>>>(rbase, total, rec2, xh, xagg, Nn);
        k_final2<<<(Nn + TM - 1) / TM, 256, 0, stream>>>(xagg, Wxz, bz, Wxh, bh, Wlin, blin, out, Nn);
    } else {
        // Tier B: CSR fallback (proven)
        unsigned* off = (unsigned*)base;
        float* deg_out = (float*)(base + (size_t)Nn * 4);
        int2* rec = (int2*)(base + (size_t)2 * Nn * 4);
        float* xagg = (float*)((char*)rec + (size_t)E * 8);

        hipMemsetAsync(d_ws, 0, (size_t)2 * Nn * 4, stream);
        k1B<<<eb, 256, 0, stream>>>(src, dst, w, deg_out, off, E);
        k_scan<<<1, 1024, 0, stream>>>(off, Nn);
        k_fillB<<<eb, 256, 0, stream>>>(src, dst, w, off, rec, E);
        k_gatherB<<<(Nn + 3) / 4, 256, 0, stream>>>(off, rec, deg_out, x, xagg, Nn);
        k_final2<<<(Nn + TM - 1) / TM, 256, 0, stream>>>(xagg, Wxz, bz, Wxh, bh, Wlin, blin, out, Nn);
    }
}

// Round 9
// 228.377 us; speedup vs baseline: 5.4302x; 5.4302x over previous
//
#include <hip/hip_runtime.h>
#include <hip/hip_bf16.h>
#include <hip/hip_fp16.h>

// GConvGRU with h=0 reduces to:
//   xagg = scatter_add(norm * x[src] -> dst)          [N,128]
//   z    = sigmoid(xagg @ W_xz + b_z)
//   ht   = tanh   (xagg @ W_xh + b_h)
//   out  = ((1-z)*ht) @ W_lin + b_lin                 [N,16]
// Model (R6-R8): scattered global writes cost 32B granules unless clustered;
// gather at high occupancy is near its transaction floor (~90us).
// R9: partition by dst-range (R8, proven cheap) + per-range LDS counting sort
//     -> CSR rec3/off -> R7's proven high-occupancy gather. k_acc's serial
//     broadcast (1118us latency chain) is gone. deg reduce + xcast fused.

#define CH 128
#define HEADS 16
#define TM 64          // nodes per block in k_final2
#define KC 32          // K-chunk
#define DRANGE 12800   // deg histogram: nodes per range (4 ranges)
#define DSLICES 64     // deg histogram: edge slices per range
#define RN 98          // nodes per partition range
#define NR 512         // partition ranges (512*98 >= 50000)
#define NB 256         // partition blocks (edge slices)
#define SCAP 3840      // sort stage capacity (mean 3136, +12 sigma; global fallback)

// =============== deg partials: LDS histogram over src ===============
__global__ __launch_bounds__(256) void k_deg(const int* __restrict__ src,
                                             const float* __restrict__ w,
                                             float* __restrict__ partial, int E) {
    __shared__ float h[DRANGE];
    const int r = blockIdx.x / DSLICES;
    const int sl = blockIdx.x % DSLICES;
    const int base = r * DRANGE;
    for (int i = threadIdx.x; i < DRANGE; i += 256) h[i] = 0.f;
    __syncthreads();
    const int per = (E + DSLICES - 1) / DSLICES;
    const int lo = sl * per;
    const int hi = min(lo + per, E);
    int e = lo + threadIdx.x * 4;
    for (; e + 3 < hi; e += 1024) {
        int4 s4 = *reinterpret_cast<const int4*>(src + e);
        float4 w4 = *reinterpret_cast<const float4*>(w + e);
        int a;
        a = s4.x - base; if ((unsigned)a < DRANGE) atomicAdd(&h[a], w4.x);
        a = s4.y - base; if ((unsigned)a < DRANGE) atomicAdd(&h[a], w4.y);
        a = s4.z - base; if ((unsigned)a < DRANGE) atomicAdd(&h[a], w4.z);
        a = s4.w - base; if ((unsigned)a < DRANGE) atomicAdd(&h[a], w4.w);
    }
    for (; e < hi; ++e) {
        int a = src[e] - base;
        if ((unsigned)a < DRANGE) atomicAdd(&h[a], w[e]);
    }
    __syncthreads();
    float* dstp = partial + ((size_t)r * DSLICES + sl) * DRANGE;
    for (int i = threadIdx.x; i < DRANGE; i += 256) dstp[i] = h[i];
}

// =============== fused: deg reduce + xh = half(x * rsqrt(deg)) ===============
__global__ __launch_bounds__(256) void k_degxc(const float* __restrict__ partial,
                                               const float* __restrict__ x,
                                               __half* __restrict__ xh, int n) {
    __shared__ float degl[256];
    const int bb = blockIdx.x * 256;
    const int t = threadIdx.x;
    int i = bb + t;
    if (i < n) {
        int r = i / DRANGE;
        int idx = i - r * DRANGE;
        const float* p = partial + (size_t)r * DSLICES * DRANGE + idx;
        float s = 0.f;
#pragma unroll 8
        for (int sl = 0; sl < DSLICES; ++sl) s += p[(size_t)sl * DRANGE];
        degl[t] = s;
    }
    __syncthreads();
#pragma unroll
    for (int g = 0; g < 16; ++g) {
        int ln = g * 16 + (t >> 4);
        int node = bb + ln;
        if (node >= n) break;
        int c8 = (t & 15) * 8;
        float dg = degl[ln];
        float sc = dg > 0.f ? rsqrtf(dg) : 0.f;
        float4 a = *reinterpret_cast<const float4*>(x + (size_t)node * CH + c8);
        float4 b = *reinterpret_cast<const float4*>(x + (size_t)node * CH + c8 + 4);
        __half2 h0 = __floats2half2_rn(a.x * sc, a.y * sc);
        __half2 h1 = __floats2half2_rn(a.z * sc, a.w * sc);
        __half2 h2 = __floats2half2_rn(b.x * sc, b.y * sc);
        __half2 h3 = __floats2half2_rn(b.z * sc, b.w * sc);
        uint4 packed = make_uint4(*(unsigned*)&h0, *(unsigned*)&h1, *(unsigned*)&h2, *(unsigned*)&h3);
        *reinterpret_cast<uint4*>(xh + (size_t)node * CH + c8) = packed;
    }
}

// =============== partition pass 1: per-block dst-range histogram ===============
__global__ __launch_bounds__(256) void k_count(const int* __restrict__ dst,
                                               unsigned* __restrict__ counts, int E) {
    __shared__ unsigned h[NR];
    const int b = blockIdx.x;
    for (int i = threadIdx.x; i < NR; i += 256) h[i] = 0u;
    __syncthreads();
    const int per = (E + NB - 1) / NB;
    const int lo = b * per;
    const int hi = min(lo + per, E);
    for (int e = lo + threadIdx.x; e < hi; e += 256)
        atomicAdd(&h[dst[e] / RN], 1u);
    __syncthreads();
    for (int i = threadIdx.x; i < NR; i += 256) counts[(size_t)i * NB + b] = h[i];
}

// per-range exclusive scan over blocks
__global__ __launch_bounds__(256) void k_scanR(unsigned* __restrict__ counts,
                                               unsigned* __restrict__ total) {
    __shared__ unsigned s[256];
    const int r = blockIdx.x;
    const int t = threadIdx.x;
    unsigned v = counts[(size_t)r * NB + t];
    s[t] = v;
    __syncthreads();
    for (int ofs = 1; ofs < 256; ofs <<= 1) {
        unsigned u = (t >= ofs) ? s[t - ofs] : 0u;
        __syncthreads();
        s[t] += u;
        __syncthreads();
    }
    counts[(size_t)r * NB + t] = s[t] - v;
    if (t == 255) total[r] = s[255];
}

// exclusive scan of total[NR] -> rbase[NR]; also off[n] = E
__global__ __launch_bounds__(512) void k_scanT(const unsigned* __restrict__ total,
                                               unsigned* __restrict__ rbase,
                                               unsigned* __restrict__ node_off,
                                               int n, int E) {
    __shared__ unsigned s[NR];
    const int t = threadIdx.x;
    unsigned v = total[t];
    s[t] = v;
    __syncthreads();
    for (int ofs = 1; ofs < NR; ofs <<= 1) {
        unsigned u = (t >= ofs) ? s[t - ofs] : 0u;
        __syncthreads();
        s[t] += u;
        __syncthreads();
    }
    rbase[t] = s[t] - v;
    if (t == 0) node_off[n] = (unsigned)E;
}

// =============== partition pass 2: scatter into contiguous chunks ===============
// rec2[pos] = { w(f32), dl<<16 | src }  (requires n <= 65536)
__global__ __launch_bounds__(256) void k_part(const int* __restrict__ src,
                                              const int* __restrict__ dst,
                                              const float* __restrict__ w,
                                              const unsigned* __restrict__ counts,
                                              const unsigned* __restrict__ rbase,
                                              int2* __restrict__ rec2, int E) {
    __shared__ unsigned cursor[NR];
    const int b = blockIdx.x;
    for (int r = threadIdx.x; r < NR; r += 256)
        cursor[r] = rbase[r] + counts[(size_t)r * NB + b];
    __syncthreads();
    const int per = (E + NB - 1) / NB;
    const int lo = b * per;
    const int hi = min(lo + per, E);
    for (int e = lo + threadIdx.x; e < hi; e += 256) {
        int d = dst[e];
        int r = d / RN;
        int dl = d - r * RN;
        unsigned pos = atomicAdd(&cursor[r], 1u);
        rec2[pos] = make_int2(__float_as_int(w[e]), (dl << 16) | src[e]);
    }
}

// =============== per-range LDS counting sort -> CSR rec3 + node_off ===============
__global__ __launch_bounds__(256) void k_sortR(const unsigned* __restrict__ rbase,
                                               const unsigned* __restrict__ total,
                                               const int2* __restrict__ rec2,
                                               int2* __restrict__ rec3,
                                               unsigned* __restrict__ node_off, int n) {
    __shared__ int2 stage[SCAP];
    __shared__ unsigned hist[RN];
    __shared__ unsigned curx[RN];
    const int r = blockIdx.x;
    const int bn = r * RN;
    if (bn >= n) return;
    const int rn = min(RN, n - bn);
    const unsigned gbase = rbase[r];
    const unsigned tot = total[r];

    for (int i = threadIdx.x; i < RN; i += 256) hist[i] = 0u;
    __syncthreads();
    for (unsigned i = threadIdx.x; i < tot; i += 256) {
        int2 v = rec2[gbase + i];
        if (i < SCAP) stage[i] = v;
        atomicAdd(&hist[v.y >> 16], 1u);
    }
    __syncthreads();
    if (threadIdx.x == 0) {
        unsigned run = 0;
        for (int j = 0; j < rn; ++j) {
            unsigned c = hist[j];
            hist[j] = run;     // exclusive prefix
            curx[j] = run;
            run += c;
        }
    }
    __syncthreads();
    for (int j = threadIdx.x; j < rn; j += 256)
        node_off[bn + j] = gbase + hist[j];
    for (unsigned i = threadIdx.x; i < tot; i += 256) {
        int2 v = (i < SCAP) ? stage[i] : rec2[gbase + i];
        int dl = v.y >> 16;
        unsigned pos = atomicAdd(&curx[dl], 1u);
        rec3[gbase + pos] = make_int2(v.x, v.y & 0xFFFF);
    }
}

// =============== gather: one wave per dst node (R7 structure, CSR) ===============
__global__ __launch_bounds__(256) void k_gather3(const unsigned* __restrict__ off,
                                                 const int2* __restrict__ rec3,
                                                 const __half* __restrict__ xh,
                                                 float* __restrict__ xagg, int n) {
    int node = blockIdx.x * 4 + (threadIdx.x >> 6);
    if (node >= n) return;
    int lane = threadIdx.x & 63;
    unsigned i = off[node];
    unsigned end = off[node + 1];
    const int2* r = rec3;
    float2 acc = make_float2(0.f, 0.f);
    float wsum = 0.f;
    for (; i + 4 <= end; i += 4) {
        int2 r0 = r[i], r1 = r[i + 1], r2 = r[i + 2], r3 = r[i + 3];
        float w0 = __int_as_float(r0.x), w1 = __int_as_float(r1.x);
        float w2 = __int_as_float(r2.x), w3 = __int_as_float(r3.x);
        float2 v0 = __half22float2(*(reinterpret_cast<const __half2*>(xh + (size_t)r0.y * CH) + lane));
        float2 v1 = __half22float2(*(reinterpret_cast<const __half2*>(xh + (size_t)r1.y * CH) + lane));
        float2 v2 = __half22float2(*(reinterpret_cast<const __half2*>(xh + (size_t)r2.y * CH) + lane));
        float2 v3 = __half22float2(*(reinterpret_cast<const __half2*>(xh + (size_t)r3.y * CH) + lane));
        wsum += (w0 + w1) + (w2 + w3);
        acc.x = fmaf(w0, v0.x, acc.x); acc.y = fmaf(w0, v0.y, acc.y);
        acc.x = fmaf(w1, v1.x, acc.x); acc.y = fmaf(w1, v1.y, acc.y);
        acc.x = fmaf(w2, v2.x, acc.x); acc.y = fmaf(w2, v2.y, acc.y);
        acc.x = fmaf(w3, v3.x, acc.x); acc.y = fmaf(w3, v3.y, acc.y);
    }
    for (; i < end; ++i) {
        int2 r0 = r[i];
        float w0 = __int_as_float(r0.x);
        float2 v0 = __half22float2(*(reinterpret_cast<const __half2*>(xh + (size_t)r0.y * CH) + lane));
        wsum += w0;
        acc.x = fmaf(w0, v0.x, acc.x); acc.y = fmaf(w0, v0.y, acc.y);
    }
    float sc = wsum > 0.f ? rsqrtf(wsum) : 0.f;
    *reinterpret_cast<float2*>(xagg + (size_t)node * CH + lane * 2) =
        make_float2(acc.x * sc, acc.y * sc);
}

// =============== Tier B (CSR fallback, proven) ===============
__global__ __launch_bounds__(256) void k1B(const int* __restrict__ src,
                                           const int* __restrict__ dst,
                                           const float* __restrict__ w,
                                           float* __restrict__ deg_out,
                                           unsigned* __restrict__ cnt, int E) {
    int e = blockIdx.x * blockDim.x + threadIdx.x;
    if (e >= E) return;
    unsafeAtomicAdd(deg_out + src[e], w[e]);
    atomicAdd(cnt + dst[e], 1u);
}

__global__ __launch_bounds__(1024) void k_scan(unsigned* __restrict__ off, int n) {
    __shared__ unsigned s[1024];
    const int t = threadIdx.x;
    const int per = (n + 1023) / 1024;
    int lo = t * per;
    int hi = lo + per; if (hi > n) hi = n;
    unsigned sum = 0;
    for (int i = lo; i < hi; ++i) sum += off[i];
    s[t] = sum;
    __syncthreads();
    for (int ofs = 1; ofs < 1024; ofs <<= 1) {
        unsigned v = (t >= ofs) ? s[t - ofs] : 0u;
        __syncthreads();
        s[t] += v;
        __syncthreads();
    }
    unsigned run = s[t] - sum;
    for (int i = lo; i < hi; ++i) {
        unsigned c = off[i];
        off[i] = run;
        run += c;
    }
}

__global__ __launch_bounds__(256) void k_fillB(const int* __restrict__ src,
                                               const int* __restrict__ dst,
                                               const float* __restrict__ w,
                                               unsigned* __restrict__ off,
                                               int2* __restrict__ rec, int E) {
    int e = blockIdx.x * blockDim.x + threadIdx.x;
    if (e >= E) return;
    unsigned pos = atomicAdd(off + dst[e], 1u);
    rec[pos] = make_int2(__float_as_int(w[e]), src[e]);
}

__global__ __launch_bounds__(256) void k_gatherB(const unsigned* __restrict__ off,
                                                 const int2* __restrict__ rec,
                                                 const float* __restrict__ deg_out,
                                                 const float* __restrict__ x,
                                                 float* __restrict__ xagg, int n) {
    int node = blockIdx.x * 4 + (threadIdx.x >> 6);
    if (node >= n) return;
    int lane = threadIdx.x & 63;
    unsigned i = node ? off[node - 1] : 0u;
    unsigned end = off[node];
    float2 acc = make_float2(0.f, 0.f);
    float wsum = 0.f;
    for (; i < end; ++i) {
        int2 r0 = rec[i];
        float w0 = __int_as_float(r0.x);
        float d0 = deg_out[r0.y];
        float c0 = w0 * (d0 > 0.f ? rsqrtf(d0) : 0.f);
        float2 v = *reinterpret_cast<const float2*>(x + (size_t)r0.y * CH + lane * 2);
        wsum += w0;
        acc.x = fmaf(c0, v.x, acc.x);
        acc.y = fmaf(c0, v.y, acc.y);
    }
    float sc = wsum > 0.f ? rsqrtf(wsum) : 0.f;
    *reinterpret_cast<float2*>(xagg + (size_t)node * CH + lane * 2) =
        make_float2(acc.x * sc, acc.y * sc);
}

// =============== fused epilogue: tiled GEMM + gates + head (R4, proven) ===============
__global__ __launch_bounds__(256) void k_final2(const float* __restrict__ xagg,
                                                const float* __restrict__ Wxz,
                                                const float* __restrict__ bz,
                                                const float* __restrict__ Wxh,
                                                const float* __restrict__ bh,
                                                const float* __restrict__ Wlin,
                                                const float* __restrict__ blin,
                                                float* __restrict__ out, int n) {
    __shared__ float smem[10560];
    float* sA = smem;           // [64][36]
    float* sWz = smem + 2304;   // [32][128]
    float* sWh = smem + 6400;   // [32][128]

    const int tid = threadIdx.x;
    const int tx = tid & 31;
    const int ty = tid >> 5;
    const int base = blockIdx.x * TM;

    float az[8][4] = {{0.f}};
    float ah[8][4] = {{0.f}};

    for (int kc = 0; kc < CH; kc += KC) {
        {
            int i = tid;
#pragma unroll
            for (int r2 = 0; r2 < 2; ++r2, i += 256) {
                int row = i >> 3;
                int c4 = (i & 7) * 4;
                int grow = base + row; if (grow > n - 1) grow = n - 1;
                float4 v = *reinterpret_cast<const float4*>(xagg + (size_t)grow * CH + kc + c4);
                *reinterpret_cast<float4*>(&sA[row * 36 + c4]) = v;
            }
            int j = tid;
#pragma unroll
            for (int r2 = 0; r2 < 4; ++r2, j += 256) {
                int row = j >> 5;
                int c4 = (j & 31) * 4;
                *reinterpret_cast<float4*>(&sWz[row * 128 + c4]) =
                    *reinterpret_cast<const float4*>(Wxz + (size_t)(kc + row) * CH + c4);
                *reinterpret_cast<float4*>(&sWh[row * 128 + c4]) =
                    *reinterpret_cast<const float4*>(Wxh + (size_t)(kc + row) * CH + c4);
            }
        }
        __syncthreads();
#pragma unroll 4
        for (int kk = 0; kk < KC; ++kk) {
            float4 wz = *reinterpret_cast<float4*>(&sWz[kk * 128 + tx * 4]);
            float4 wh = *reinterpret_cast<float4*>(&sWh[kk * 128 + tx * 4]);
#pragma unroll
            for (int r = 0; r < 8; ++r) {
                float a = sA[(ty * 8 + r) * 36 + kk];
                az[r][0] = fmaf(a, wz.x, az[r][0]);
                az[r][1] = fmaf(a, wz.y, az[r][1]);
                az[r][2] = fmaf(a, wz.z, az[r][2]);
                az[r][3] = fmaf(a, wz.w, az[r][3]);
                ah[r][0] = fmaf(a, wh.x, ah[r][0]);
                ah[r][1] = fmaf(a, wh.y, ah[r][1]);
                ah[r][2] = fmaf(a, wh.z, ah[r][2]);
                ah[r][3] = fmaf(a, wh.w, ah[r][3]);
            }
        }
        __syncthreads();
    }

    float* sG = smem;
    const float4 bz4 = *reinterpret_cast<const float4*>(bz + tx * 4);
    const float4 bh4 = *reinterpret_cast<const float4*>(bh + tx * 4);
#pragma unroll
    for (int r = 0; r < 8; ++r) {
        int row = ty * 8 + r;
        float4 g4;
        float zp = az[r][0] + bz4.x, hp = ah[r][0] + bh4.x;
        g4.x = (1.f - 1.f / (1.f + __expf(-zp))) * tanhf(hp);
        zp = az[r][1] + bz4.y; hp = ah[r][1] + bh4.y;
        g4.y = (1.f - 1.f / (1.f + __expf(-zp))) * tanhf(hp);
        zp = az[r][2] + bz4.z; hp = ah[r][2] + bh4.z;
        g4.z = (1.f - 1.f / (1.f + __expf(-zp))) * tanhf(hp);
        zp = az[r][3] + bz4.w; hp = ah[r][3] + bh4.w;
        g4.w = (1.f - 1.f / (1.f + __expf(-zp))) * tanhf(hp);
        *reinterpret_cast<float4*>(&sG[row * 132 + tx * 4]) = g4;
    }
    __syncthreads();

#pragma unroll
    for (int it = 0; it < 4; ++it) {
        int idx = it * 256 + tid;
        int node = idx >> 4;
        int hh = idx & 15;
        float acc = blin[hh];
#pragma unroll 8
        for (int j = 0; j < CH; ++j)
            acc = fmaf(sG[node * 132 + j], Wlin[j * HEADS + hh], acc);
        if (base + node < n) out[(size_t)(base + node) * HEADS + hh] = acc;
    }
}

extern "C" void kernel_launch(void* const* d_in, const int* in_sizes, int n_in,
                              void* d_out, int out_size, void* d_ws, size_t ws_size,
                              hipStream_t stream) {
    const float* x = (const float*)d_in[0];
    const int* ei = (const int*)d_in[1];     // int32 on device (harness narrows int64)
    const float* w = (const float*)d_in[2];
    const float* Wxz = (const float*)d_in[3];
    const float* bz = (const float*)d_in[5];
    const float* Wxh = (const float*)d_in[9];
    const float* bh = (const float*)d_in[11];
    const float* Wlin = (const float*)d_in[12];
    const float* blin = (const float*)d_in[13];
    float* out = (float*)d_out;

    const int Nn = in_sizes[0] / CH;  // 50000
    const int E = in_sizes[2];        // 1,600,000

    const int* src = ei;
    const int* dst = ei + E;
    int eb = (E + 255) / 256;
    char* base = (char*)d_ws;

    // Layout:
    size_t off_counts = 0;                                     // NR*NB u32 = 512KB
    size_t off_total = off_counts + (size_t)NR * NB * 4;       // NR u32
    size_t off_rbase = off_total + NR * 4;                     // NR u32
    size_t off_noff = off_rbase + NR * 4;                      // (N+1) u32
    size_t off_xh = off_noff + ((size_t)Nn + 1) * 4;           // N*CH half
    size_t off_rec2 = off_xh + (size_t)Nn * CH * 2;            // E int2
    size_t off_rec3 = off_rec2 + (size_t)E * 8;                // E int2
    size_t off_xagg = off_rec3 + (size_t)E * 8;                // N*CH f32 (deg partials overlay)
    size_t needNew = off_xagg + (size_t)Nn * CH * 4;
    size_t partial_bytes = (size_t)4 * DSLICES * DRANGE * 4;

    if (ws_size >= needNew && Nn <= 65536 && (size_t)NR * RN >= (size_t)Nn &&
        partial_bytes <= (size_t)Nn * CH * 4) {
        unsigned* counts = (unsigned*)(base + off_counts);
        unsigned* total = (unsigned*)(base + off_total);
        unsigned* rbase = (unsigned*)(base + off_rbase);
        unsigned* noff = (unsigned*)(base + off_noff);
        __half* xh = (__half*)(base + off_xh);
        int2* rec2 = (int2*)(base + off_rec2);
        int2* rec3 = (int2*)(base + off_rec3);
        float* xagg = (float*)(base + off_xagg);
        float* partial = xagg;  // overlay: dead after k_degxc

        k_deg<<<4 * DSLICES, 256, 0, stream>>>(src, w, partial, E);
        k_degxc<<<(Nn + 255) / 256, 256, 0, stream>>>(partial, x, xh, Nn);
        k_count<<<NB, 256, 0, stream>>>(dst, counts, E);
        k_scanR<<<NR, 256, 0, stream>>>(counts, total);
        k_scanT<<<1, NR, 0, stream>>>(total, rbase, noff, Nn, E);
        k_part<<<NB, 256, 0, stream>>>(src, dst, w, counts, rbase, rec2, E);
        k_sortR<<<NR, 256, 0, stream>>>(rbase, total, rec2, rec3, noff, Nn);
        k_gather3<<<(Nn + 3) / 4, 256, 0, stream>>>(noff, rec3, xh, xagg, Nn);
        k_final2<<<(Nn + TM - 1) / TM, 256, 0, stream>>>(xagg, Wxz, bz, Wxh, bh, Wlin, blin, out, Nn);
    } else {
        // Tier B: CSR fallback (proven)
        unsigned* off = (unsigned*)base;
        float* deg_out = (float*)(base + (size_t)Nn * 4);
        int2* rec = (int2*)(base + (size_t)2 * Nn * 4);
        float* xagg = (float*)((char*)rec + (size_t)E * 8);

        hipMemsetAsync(d_ws, 0, (size_t)2 * Nn * 4, stream);
        k1B<<<eb, 256, 0, stream>>>(src, dst, w, deg_out, off, E);
        k_scan<<<1, 1024, 0, stream>>>(off, Nn);
        k_fillB<<<eb, 256, 0, stream>>>(src, dst, w, off, rec, E);
        k_gatherB<<<(Nn + 3) / 4, 256, 0, stream>>>(off, rec, deg_out, x, xagg, Nn);
        k_final2<<<(Nn + TM - 1) / TM, 256, 0, stream>>>(xagg, Wxz, bz, Wxh, bh, Wlin, blin, out, Nn);
    }
}

// Round 10
// 193.177 us; speedup vs baseline: 6.4196x; 1.1822x over previous
//
#include <hip/hip_runtime.h>
#include <hip/hip_bf16.h>
#include <hip/hip_fp16.h>

// GConvGRU with h=0 reduces to:
//   xagg = scatter_add(norm * x[src] -> dst)          [N,128]
//   z    = sigmoid(xagg @ W_xz + b_z)
//   ht   = tanh   (xagg @ W_xh + b_h)
//   out  = ((1-z)*ht) @ W_lin + b_lin                 [N,16]
// Model (R6-R9): scattered global writes cost 32B granules unless clustered;
// gather at high occupancy is near its transaction floor; f32 VALU epilogue
// was issue/occupancy-bound at 83us (39% VALU, 3 blk/CU).
// R10: epilogue on matrix cores: fp16 xagg (gather writes fp16), fp16
//      transposed weights (k_wcast), k_final3 = 68 mfma_f32_16x16x32_f16
//      per 64-node block + VALU gates + LDS-staged fp16 g for the head MFMA.

#define CH 128
#define HEADS 16
#define TM 64          // nodes per block in k_final2 (tier B)
#define KC 32          // K-chunk (tier B)
#define DRANGE 12800   // deg histogram: nodes per range (4 ranges)
#define DSLICES 64     // deg histogram: edge slices per range
#define RN 98          // nodes per partition range
#define NR 512         // partition ranges (512*98 >= 50000)
#define NB 256         // partition blocks (edge slices)
#define SCAP 3840      // sort stage capacity (mean 3136; global fallback)

typedef _Float16 half8 __attribute__((ext_vector_type(8)));
typedef float floatx4 __attribute__((ext_vector_type(4)));

// =============== deg partials: LDS histogram over src ===============
__global__ __launch_bounds__(256) void k_deg(const int* __restrict__ src,
                                             const float* __restrict__ w,
                                             float* __restrict__ partial, int E) {
    __shared__ float h[DRANGE];
    const int r = blockIdx.x / DSLICES;
    const int sl = blockIdx.x % DSLICES;
    const int base = r * DRANGE;
    for (int i = threadIdx.x; i < DRANGE; i += 256) h[i] = 0.f;
    __syncthreads();
    const int per = (E + DSLICES - 1) / DSLICES;
    const int lo = sl * per;
    const int hi = min(lo + per, E);
    int e = lo + threadIdx.x * 4;
    for (; e + 3 < hi; e += 1024) {
        int4 s4 = *reinterpret_cast<const int4*>(src + e);
        float4 w4 = *reinterpret_cast<const float4*>(w + e);
        int a;
        a = s4.x - base; if ((unsigned)a < DRANGE) atomicAdd(&h[a], w4.x);
        a = s4.y - base; if ((unsigned)a < DRANGE) atomicAdd(&h[a], w4.y);
        a = s4.z - base; if ((unsigned)a < DRANGE) atomicAdd(&h[a], w4.z);
        a = s4.w - base; if ((unsigned)a < DRANGE) atomicAdd(&h[a], w4.w);
    }
    for (; e < hi; ++e) {
        int a = src[e] - base;
        if ((unsigned)a < DRANGE) atomicAdd(&h[a], w[e]);
    }
    __syncthreads();
    float* dstp = partial + ((size_t)r * DSLICES + sl) * DRANGE;
    for (int i = threadIdx.x; i < DRANGE; i += 256) dstp[i] = h[i];
}

// =============== fused: deg reduce + xh = half(x * rsqrt(deg)) ===============
__global__ __launch_bounds__(256) void k_degxc(const float* __restrict__ partial,
                                               const float* __restrict__ x,
                                               __half* __restrict__ xh, int n) {
    __shared__ float degl[256];
    const int bb = blockIdx.x * 256;
    const int t = threadIdx.x;
    int i = bb + t;
    if (i < n) {
        int r = i / DRANGE;
        int idx = i - r * DRANGE;
        const float* p = partial + (size_t)r * DSLICES * DRANGE + idx;
        float s = 0.f;
#pragma unroll 8
        for (int sl = 0; sl < DSLICES; ++sl) s += p[(size_t)sl * DRANGE];
        degl[t] = s;
    }
    __syncthreads();
#pragma unroll
    for (int g = 0; g < 16; ++g) {
        int ln = g * 16 + (t >> 4);
        int node = bb + ln;
        if (node >= n) break;
        int c8 = (t & 15) * 8;
        float dg = degl[ln];
        float sc = dg > 0.f ? rsqrtf(dg) : 0.f;
        float4 a = *reinterpret_cast<const float4*>(x + (size_t)node * CH + c8);
        float4 b = *reinterpret_cast<const float4*>(x + (size_t)node * CH + c8 + 4);
        __half2 h0 = __floats2half2_rn(a.x * sc, a.y * sc);
        __half2 h1 = __floats2half2_rn(a.z * sc, a.w * sc);
        __half2 h2 = __floats2half2_rn(b.x * sc, b.y * sc);
        __half2 h3 = __floats2half2_rn(b.z * sc, b.w * sc);
        uint4 packed = make_uint4(*(unsigned*)&h0, *(unsigned*)&h1, *(unsigned*)&h2, *(unsigned*)&h3);
        *reinterpret_cast<uint4*>(xh + (size_t)node * CH + c8) = packed;
    }
}

// =============== weight cast: WzT/WhT = fp16 W^T [outcol][k]; WlT [head][k] ===============
__global__ __launch_bounds__(256) void k_wcast(const float* __restrict__ Wxz,
                                               const float* __restrict__ Wxh,
                                               const float* __restrict__ Wlin,
                                               __half* __restrict__ WzT,
                                               __half* __restrict__ WhT,
                                               __half* __restrict__ WlT) {
    int i = blockIdx.x * 256 + threadIdx.x;
    if (i < CH * CH) {
        int nn = i >> 7, k = i & 127;
        WzT[i] = __float2half(Wxz[k * CH + nn]);
        WhT[i] = __float2half(Wxh[k * CH + nn]);
    } else if (i < CH * CH + HEADS * CH) {
        int j = i - CH * CH;
        int nn = j >> 7, k = j & 127;
        WlT[j] = __float2half(Wlin[k * HEADS + nn]);
    }
}

// =============== partition pass 1: per-block dst-range histogram ===============
__global__ __launch_bounds__(256) void k_count(const int* __restrict__ dst,
                                               unsigned* __restrict__ counts, int E) {
    __shared__ unsigned h[NR];
    const int b = blockIdx.x;
    for (int i = threadIdx.x; i < NR; i += 256) h[i] = 0u;
    __syncthreads();
    const int per = (E + NB - 1) / NB;
    const int lo = b * per;
    const int hi = min(lo + per, E);
    for (int e = lo + threadIdx.x; e < hi; e += 256)
        atomicAdd(&h[dst[e] / RN], 1u);
    __syncthreads();
    for (int i = threadIdx.x; i < NR; i += 256) counts[(size_t)i * NB + b] = h[i];
}

// per-range exclusive scan over blocks
__global__ __launch_bounds__(256) void k_scanR(unsigned* __restrict__ counts,
                                               unsigned* __restrict__ total) {
    __shared__ unsigned s[256];
    const int r = blockIdx.x;
    const int t = threadIdx.x;
    unsigned v = counts[(size_t)r * NB + t];
    s[t] = v;
    __syncthreads();
    for (int ofs = 1; ofs < 256; ofs <<= 1) {
        unsigned u = (t >= ofs) ? s[t - ofs] : 0u;
        __syncthreads();
        s[t] += u;
        __syncthreads();
    }
    counts[(size_t)r * NB + t] = s[t] - v;
    if (t == 255) total[r] = s[255];
}

// exclusive scan of total[NR] -> rbase[NR]; also off[n] = E
__global__ __launch_bounds__(512) void k_scanT(const unsigned* __restrict__ total,
                                               unsigned* __restrict__ rbase,
                                               unsigned* __restrict__ node_off,
                                               int n, int E) {
    __shared__ unsigned s[NR];
    const int t = threadIdx.x;
    unsigned v = total[t];
    s[t] = v;
    __syncthreads();
    for (int ofs = 1; ofs < NR; ofs <<= 1) {
        unsigned u = (t >= ofs) ? s[t - ofs] : 0u;
        __syncthreads();
        s[t] += u;
        __syncthreads();
    }
    rbase[t] = s[t] - v;
    if (t == 0) node_off[n] = (unsigned)E;
}

// =============== partition pass 2: scatter into contiguous chunks ===============
// rec2[pos] = { w(f32), dl<<16 | src }  (requires n <= 65536)
__global__ __launch_bounds__(256) void k_part(const int* __restrict__ src,
                                              const int* __restrict__ dst,
                                              const float* __restrict__ w,
                                              const unsigned* __restrict__ counts,
                                              const unsigned* __restrict__ rbase,
                                              int2* __restrict__ rec2, int E) {
    __shared__ unsigned cursor[NR];
    const int b = blockIdx.x;
    for (int r = threadIdx.x; r < NR; r += 256)
        cursor[r] = rbase[r] + counts[(size_t)r * NB + b];
    __syncthreads();
    const int per = (E + NB - 1) / NB;
    const int lo = b * per;
    const int hi = min(lo + per, E);
    for (int e = lo + threadIdx.x; e < hi; e += 256) {
        int d = dst[e];
        int r = d / RN;
        int dl = d - r * RN;
        unsigned pos = atomicAdd(&cursor[r], 1u);
        rec2[pos] = make_int2(__float_as_int(w[e]), (dl << 16) | src[e]);
    }
}

// =============== per-range LDS counting sort -> CSR rec3 + node_off ===============
__global__ __launch_bounds__(256) void k_sortR(const unsigned* __restrict__ rbase,
                                               const unsigned* __restrict__ total,
                                               const int2* __restrict__ rec2,
                                               int2* __restrict__ rec3,
                                               unsigned* __restrict__ node_off, int n) {
    __shared__ int2 stage[SCAP];
    __shared__ unsigned hist[RN];
    __shared__ unsigned curx[RN];
    const int r = blockIdx.x;
    const int bn = r * RN;
    if (bn >= n) return;
    const int rn = min(RN, n - bn);
    const unsigned gbase = rbase[r];
    const unsigned tot = total[r];

    for (int i = threadIdx.x; i < RN; i += 256) hist[i] = 0u;
    __syncthreads();
    for (unsigned i = threadIdx.x; i < tot; i += 256) {
        int2 v = rec2[gbase + i];
        if (i < SCAP) stage[i] = v;
        atomicAdd(&hist[v.y >> 16], 1u);
    }
    __syncthreads();
    if (threadIdx.x == 0) {
        unsigned run = 0;
        for (int j = 0; j < rn; ++j) {
            unsigned c = hist[j];
            hist[j] = run;
            curx[j] = run;
            run += c;
        }
    }
    __syncthreads();
    for (int j = threadIdx.x; j < rn; j += 256)
        node_off[bn + j] = gbase + hist[j];
    for (unsigned i = threadIdx.x; i < tot; i += 256) {
        int2 v = (i < SCAP) ? stage[i] : rec2[gbase + i];
        int dl = v.y >> 16;
        unsigned pos = atomicAdd(&curx[dl], 1u);
        rec3[gbase + pos] = make_int2(v.x, v.y & 0xFFFF);
    }
}

// =============== gather: one wave per dst node -> fp16 xagg ===============
__global__ __launch_bounds__(256) void k_gather3(const unsigned* __restrict__ off,
                                                 const int2* __restrict__ rec3,
                                                 const __half* __restrict__ xh,
                                                 __half* __restrict__ xaggh, int n) {
    int node = blockIdx.x * 4 + (threadIdx.x >> 6);
    if (node >= n) return;
    int lane = threadIdx.x & 63;
    unsigned i = off[node];
    unsigned end = off[node + 1];
    const int2* r = rec3;
    float2 acc = make_float2(0.f, 0.f);
    float wsum = 0.f;
    for (; i + 4 <= end; i += 4) {
        int2 r0 = r[i], r1 = r[i + 1], r2 = r[i + 2], r3 = r[i + 3];
        float w0 = __int_as_float(r0.x), w1 = __int_as_float(r1.x);
        float w2 = __int_as_float(r2.x), w3 = __int_as_float(r3.x);
        float2 v0 = __half22float2(*(reinterpret_cast<const __half2*>(xh + (size_t)r0.y * CH) + lane));
        float2 v1 = __half22float2(*(reinterpret_cast<const __half2*>(xh + (size_t)r1.y * CH) + lane));
        float2 v2 = __half22float2(*(reinterpret_cast<const __half2*>(xh + (size_t)r2.y * CH) + lane));
        float2 v3 = __half22float2(*(reinterpret_cast<const __half2*>(xh + (size_t)r3.y * CH) + lane));
        wsum += (w0 + w1) + (w2 + w3);
        acc.x = fmaf(w0, v0.x, acc.x); acc.y = fmaf(w0, v0.y, acc.y);
        acc.x = fmaf(w1, v1.x, acc.x); acc.y = fmaf(w1, v1.y, acc.y);
        acc.x = fmaf(w2, v2.x, acc.x); acc.y = fmaf(w2, v2.y, acc.y);
        acc.x = fmaf(w3, v3.x, acc.x); acc.y = fmaf(w3, v3.y, acc.y);
    }
    for (; i < end; ++i) {
        int2 r0 = r[i];
        float w0 = __int_as_float(r0.x);
        float2 v0 = __half22float2(*(reinterpret_cast<const __half2*>(xh + (size_t)r0.y * CH) + lane));
        wsum += w0;
        acc.x = fmaf(w0, v0.x, acc.x); acc.y = fmaf(w0, v0.y, acc.y);
    }
    float sc = wsum > 0.f ? rsqrtf(wsum) : 0.f;
    __half2 hv = __floats2half2_rn(acc.x * sc, acc.y * sc);
    *(reinterpret_cast<__half2*>(xaggh + (size_t)node * CH) + lane) = hv;
}

// =============== MFMA epilogue: 64 nodes/block, 4 waves, fp16 in / f32 acc ===============
// Per wave (16 nodes): z/h preacts via 2x8x4 mfma_f32_16x16x32_f16 (A from global
// xaggh, B from WzT/WhT), VALU gates, g -> per-wave LDS fp16 [16][136], head via
// 4 MFMA vs WlT. Verified layouts: A[m=l%16][k=8*(l/16)+j], B[k][n=l%16],
// D[row=4*(l/16)+r][col=l%16].
__global__ __launch_bounds__(256) void k_final3(const __half* __restrict__ xaggh,
                                                const __half* __restrict__ WzT,
                                                const __half* __restrict__ WhT,
                                                const __half* __restrict__ WlT,
                                                const float* __restrict__ bz,
                                                const float* __restrict__ bh,
                                                const float* __restrict__ blin,
                                                float* __restrict__ out, int n) {
    __shared__ __half gL[4][16][136];
    const int tid = threadIdx.x;
    const int w = tid >> 6;
    const int l = tid & 63;
    const int lr = l & 15;
    const int lk = l >> 4;
    const int nodeb = blockIdx.x * 64 + w * 16;

    int arow = nodeb + lr;
    if (arow > n - 1) arow = n - 1;

    floatx4 accz[8], acch[8];
#pragma unroll
    for (int ct = 0; ct < 8; ++ct) {
        accz[ct] = (floatx4){0.f, 0.f, 0.f, 0.f};
        acch[ct] = (floatx4){0.f, 0.f, 0.f, 0.f};
    }

#pragma unroll
    for (int kc = 0; kc < 4; ++kc) {
        half8 a = *reinterpret_cast<const half8*>(xaggh + (size_t)arow * CH + kc * 32 + lk * 8);
#pragma unroll
        for (int ct = 0; ct < 8; ++ct) {
            half8 bzf = *reinterpret_cast<const half8*>(WzT + (ct * 16 + lr) * CH + kc * 32 + lk * 8);
            accz[ct] = __builtin_amdgcn_mfma_f32_16x16x32_f16(a, bzf, accz[ct], 0, 0, 0);
            half8 bhf = *reinterpret_cast<const half8*>(WhT + (ct * 16 + lr) * CH + kc * 32 + lk * 8);
            acch[ct] = __builtin_amdgcn_mfma_f32_16x16x32_f16(a, bhf, acch[ct], 0, 0, 0);
        }
    }

    // gates -> per-wave LDS fp16 tile
#pragma unroll
    for (int ct = 0; ct < 8; ++ct) {
        float bzv = bz[ct * 16 + lr];
        float bhv = bh[ct * 16 + lr];
#pragma unroll
        for (int r = 0; r < 4; ++r) {
            float zp = accz[ct][r] + bzv;
            float hp = acch[ct][r] + bhv;
            float g = (1.f - 1.f / (1.f + __expf(-zp))) * tanhf(hp);
            gL[w][lk * 4 + r][ct * 16 + lr] = __float2half(g);
        }
    }
    __syncthreads();

    // head: 16 nodes x 16 heads
    floatx4 acco = (floatx4){0.f, 0.f, 0.f, 0.f};
#pragma unroll
    for (int kc = 0; kc < 4; ++kc) {
        half8 a = *reinterpret_cast<const half8*>(&gL[w][lr][kc * 32 + lk * 8]);
        half8 b = *reinterpret_cast<const half8*>(WlT + lr * CH + kc * 32 + lk * 8);
        acco = __builtin_amdgcn_mfma_f32_16x16x32_f16(a, b, acco, 0, 0, 0);
    }
    float bl = blin[lr];
#pragma unroll
    for (int r = 0; r < 4; ++r) {
        int node = nodeb + lk * 4 + r;
        if (node < n) out[(size_t)node * HEADS + lr] = acco[r] + bl;
    }
}

// =============== Tier B (CSR fallback, proven) ===============
__global__ __launch_bounds__(256) void k1B(const int* __restrict__ src,
                                           const int* __restrict__ dst,
                                           const float* __restrict__ w,
                                           float* __restrict__ deg_out,
                                           unsigned* __restrict__ cnt, int E) {
    int e = blockIdx.x * blockDim.x + threadIdx.x;
    if (e >= E) return;
    unsafeAtomicAdd(deg_out + src[e], w[e]);
    atomicAdd(cnt + dst[e], 1u);
}

__global__ __launch_bounds__(1024) void k_scan(unsigned* __restrict__ off, int n) {
    __shared__ unsigned s[1024];
    const int t = threadIdx.x;
    const int per = (n + 1023) / 1024;
    int lo = t * per;
    int hi = lo + per; if (hi > n) hi = n;
    unsigned sum = 0;
    for (int i = lo; i < hi; ++i) sum += off[i];
    s[t] = sum;
    __syncthreads();
    for (int ofs = 1; ofs < 1024; ofs <<= 1) {
        unsigned v = (t >= ofs) ? s[t - ofs] : 0u;
        __syncthreads();
        s[t] += v;
        __syncthreads();
    }
    unsigned run = s[t] - sum;
    for (int i = lo; i < hi; ++i) {
        unsigned c = off[i];
        off[i] = run;
        run += c;
    }
}

__global__ __launch_bounds__(256) void k_fillB(const int* __restrict__ src,
                                               const int* __restrict__ dst,
                                               const float* __restrict__ w,
                                               unsigned* __restrict__ off,
                                               int2* __restrict__ rec, int E) {
    int e = blockIdx.x * blockDim.x + threadIdx.x;
    if (e >= E) return;
    unsigned pos = atomicAdd(off + dst[e], 1u);
    rec[pos] = make_int2(__float_as_int(w[e]), src[e]);
}

__global__ __launch_bounds__(256) void k_gatherB(const unsigned* __restrict__ off,
                                                 const int2* __restrict__ rec,
                                                 const float* __restrict__ deg_out,
                                                 const float* __restrict__ x,
                                                 float* __restrict__ xagg, int n) {
    int node = blockIdx.x * 4 + (threadIdx.x >> 6);
    if (node >= n) return;
    int lane = threadIdx.x & 63;
    unsigned i = node ? off[node - 1] : 0u;
    unsigned end = off[node];
    float2 acc = make_float2(0.f, 0.f);
    float wsum = 0.f;
    for (; i < end; ++i) {
        int2 r0 = rec[i];
        float w0 = __int_as_float(r0.x);
        float d0 = deg_out[r0.y];
        float c0 = w0 * (d0 > 0.f ? rsqrtf(d0) : 0.f);
        float2 v = *reinterpret_cast<const float2*>(x + (size_t)r0.y * CH + lane * 2);
        wsum += w0;
        acc.x = fmaf(c0, v.x, acc.x);
        acc.y = fmaf(c0, v.y, acc.y);
    }
    float sc = wsum > 0.f ? rsqrtf(wsum) : 0.f;
    *reinterpret_cast<float2*>(xagg + (size_t)node * CH + lane * 2) =
        make_float2(acc.x * sc, acc.y * sc);
}

__global__ __launch_bounds__(256) void k_final2(const float* __restrict__ xagg,
                                                const float* __restrict__ Wxz,
                                                const float* __restrict__ bz,
                                                const float* __restrict__ Wxh,
                                                const float* __restrict__ bh,
                                                const float* __restrict__ Wlin,
                                                const float* __restrict__ blin,
                                                float* __restrict__ out, int n) {
    __shared__ float smem[10560];
    float* sA = smem;
    float* sWz = smem + 2304;
    float* sWh = smem + 6400;

    const int tid = threadIdx.x;
    const int tx = tid & 31;
    const int ty = tid >> 5;
    const int base = blockIdx.x * TM;

    float az[8][4] = {{0.f}};
    float ah[8][4] = {{0.f}};

    for (int kc = 0; kc < CH; kc += KC) {
        {
            int i = tid;
#pragma unroll
            for (int r2 = 0; r2 < 2; ++r2, i += 256) {
                int row = i >> 3;
                int c4 = (i & 7) * 4;
                int grow = base + row; if (grow > n - 1) grow = n - 1;
                float4 v = *reinterpret_cast<const float4*>(xagg + (size_t)grow * CH + kc + c4);
                *reinterpret_cast<float4*>(&sA[row * 36 + c4]) = v;
            }
            int j = tid;
#pragma unroll
            for (int r2 = 0; r2 < 4; ++r2, j += 256) {
                int row = j >> 5;
                int c4 = (j & 31) * 4;
                *reinterpret_cast<float4*>(&sWz[row * 128 + c4]) =
                    *reinterpret_cast<const float4*>(Wxz + (size_t)(kc + row) * CH + c4);
                *reinterpret_cast<float4*>(&sWh[row * 128 + c4]) =
                    *reinterpret_cast<const float4*>(Wxh + (size_t)(kc + row) * CH + c4);
            }
        }
        __syncthreads();
#pragma unroll 4
        for (int kk = 0; kk < KC; ++kk) {
            float4 wz = *reinterpret_cast<float4*>(&sWz[kk * 128 + tx * 4]);
            float4 wh = *reinterpret_cast<float4*>(&sWh[kk * 128 + tx * 4]);
#pragma unroll
            for (int r = 0; r < 8; ++r) {
                float a = sA[(ty * 8 + r) * 36 + kk];
                az[r][0] = fmaf(a, wz.x, az[r][0]);
                az[r][1] = fmaf(a, wz.y, az[r][1]);
                az[r][2] = fmaf(a, wz.z, az[r][2]);
                az[r][3] = fmaf(a, wz.w, az[r][3]);
                ah[r][0] = fmaf(a, wh.x, ah[r][0]);
                ah[r][1] = fmaf(a, wh.y, ah[r][1]);
                ah[r][2] = fmaf(a, wh.z, ah[r][2]);
                ah[r][3] = fmaf(a, wh.w, ah[r][3]);
            }
        }
        __syncthreads();
    }

    float* sG = smem;
    const float4 bz4 = *reinterpret_cast<const float4*>(bz + tx * 4);
    const float4 bh4 = *reinterpret_cast<const float4*>(bh + tx * 4);
#pragma unroll
    for (int r = 0; r < 8; ++r) {
        int row = ty * 8 + r;
        float4 g4;
        float zp = az[r][0] + bz4.x, hp = ah[r][0] + bh4.x;
        g4.x = (1.f - 1.f / (1.f + __expf(-zp))) * tanhf(hp);
        zp = az[r][1] + bz4.y; hp = ah[r][1] + bh4.y;
        g4.y = (1.f - 1.f / (1.f + __expf(-zp))) * tanhf(hp);
        zp = az[r][2] + bz4.z; hp = ah[r][2] + bh4.z;
        g4.z = (1.f - 1.f / (1.f + __expf(-zp))) * tanhf(hp);
        zp = az[r][3] + bz4.w; hp = ah[r][3] + bh4.w;
        g4.w = (1.f - 1.f / (1.f + __expf(-zp))) * tanhf(hp);
        *reinterpret_cast<float4*>(&sG[row * 132 + tx * 4]) = g4;
    }
    __syncthreads();

#pragma unroll
    for (int it = 0; it < 4; ++it) {
        int idx = it * 256 + tid;
        int node = idx >> 4;
        int hh = idx & 15;
        float acc = blin[hh];
#pragma unroll 8
        for (int j = 0; j < CH; ++j)
            acc = fmaf(sG[node * 132 + j], Wlin[j * HEADS + hh], acc);
        if (base + node < n) out[(size_t)(base + node) * HEADS + hh] = acc;
    }
}

static inline size_t align256(size_t v) { return (v + 255) & ~(size_t)255; }

extern "C" void kernel_launch(void* const* d_in, const int* in_sizes, int n_in,
                              void* d_out, int out_size, void* d_ws, size_t ws_size,
                              hipStream_t stream) {
    const float* x = (const float*)d_in[0];
    const int* ei = (const int*)d_in[1];     // int32 on device (harness narrows int64)
    const float* w = (const float*)d_in[2];
    const float* Wxz = (const float*)d_in[3];
    const float* bz = (const float*)d_in[5];
    const float* Wxh = (const float*)d_in[9];
    const float* bh = (const float*)d_in[11];
    const float* Wlin = (const float*)d_in[12];
    const float* blin = (const float*)d_in[13];
    float* out = (float*)d_out;

    const int Nn = in_sizes[0] / CH;  // 50000
    const int E = in_sizes[2];        // 1,600,000

    const int* src = ei;
    const int* dst = ei + E;
    int eb = (E + 255) / 256;
    char* base = (char*)d_ws;

    // Tier A layout (aligned):
    size_t off_counts = 0;                                         // NR*NB u32
    size_t off_total = align256(off_counts + (size_t)NR * NB * 4); // NR u32
    size_t off_rbase = align256(off_total + NR * 4);               // NR u32
    size_t off_noff = align256(off_rbase + NR * 4);                // (N+1) u32
    size_t off_xh = align256(off_noff + ((size_t)Nn + 1) * 4);     // N*CH half
    size_t off_xaggh = align256(off_xh + (size_t)Nn * CH * 2);     // N*CH half
    size_t off_wz = align256(off_xaggh + (size_t)Nn * CH * 2);     // CH*CH half
    size_t off_wh = align256(off_wz + (size_t)CH * CH * 2);        // CH*CH half
    size_t off_wl = align256(off_wh + (size_t)CH * CH * 2);        // HEADS*CH half
    size_t off_rec2 = align256(off_wl + (size_t)HEADS * CH * 2);   // E int2
    size_t off_rec3 = align256(off_rec2 + (size_t)E * 8);          // E int2
    size_t needNew = off_rec3 + (size_t)E * 8;
    size_t partial_bytes = (size_t)4 * DSLICES * DRANGE * 4;       // 13.1MB, overlays rec2+rec3

    if (ws_size >= needNew && Nn <= 65536 && (size_t)NR * RN >= (size_t)Nn &&
        partial_bytes <= (size_t)2 * E * 8) {
        unsigned* counts = (unsigned*)(base + off_counts);
        unsigned* total = (unsigned*)(base + off_total);
        unsigned* rbase = (unsigned*)(base + off_rbase);
        unsigned* noff = (unsigned*)(base + off_noff);
        __half* xh = (__half*)(base + off_xh);
        __half* xaggh = (__half*)(base + off_xaggh);
        __half* WzT = (__half*)(base + off_wz);
        __half* WhT = (__half*)(base + off_wh);
        __half* WlT = (__half*)(base + off_wl);
        int2* rec2 = (int2*)(base + off_rec2);
        int2* rec3 = (int2*)(base + off_rec3);
        float* partial = (float*)(base + off_rec2);  // overlay: dead after k_degxc

        k_deg<<<4 * DSLICES, 256, 0, stream>>>(src, w, partial, E);
        k_degxc<<<(Nn + 255) / 256, 256, 0, stream>>>(partial, x, xh, Nn);
        k_wcast<<<(CH * CH + HEADS * CH + 255) / 256, 256, 0, stream>>>(Wxz, Wxh, Wlin, WzT, WhT, WlT);
        k_count<<<NB, 256, 0, stream>>>(dst, counts, E);
        k_scanR<<<NR, 256, 0, stream>>>(counts, total);
        k_scanT<<<1, NR, 0, stream>>>(total, rbase, noff, Nn, E);
        k_part<<<NB, 256, 0, stream>>>(src, dst, w, counts, rbase, rec2, E);
        k_sortR<<<NR, 256, 0, stream>>>(rbase, total, rec2, rec3, noff, Nn);
        k_gather3<<<(Nn + 3) / 4, 256, 0, stream>>>(noff, rec3, xh, xaggh, Nn);
        k_final3<<<(Nn + 63) / 64, 256, 0, stream>>>(xaggh, WzT, WhT, WlT, bz, bh, blin, out, Nn);
    } else {
        // Tier B: CSR fallback (proven)
        unsigned* off = (unsigned*)base;
        float* deg_out = (float*)(base + (size_t)Nn * 4);
        int2* rec = (int2*)(base + (size_t)2 * Nn * 4);
        float* xagg = (float*)((char*)rec + (size_t)E * 8);

        hipMemsetAsync(d_ws, 0, (size_t)2 * Nn * 4, stream);
        k1B<<<eb, 256, 0, stream>>>(src, dst, w, deg_out, off, E);
        k_scan<<<1, 1024, 0, stream>>>(off, Nn);
        k_fillB<<<eb, 256, 0, stream>>>(src, dst, w, off, rec, E);
        k_gatherB<<<(Nn + 3) / 4, 256, 0, stream>>>(off, rec, deg_out, x, xagg, Nn);
        k_final2<<<(Nn + TM - 1) / TM, 256, 0, stream>>>(xagg, Wxz, bz, Wxh, bh, Wlin, blin, out, Nn);
    }
}

// Round 11
// 174.209 us; speedup vs baseline: 7.1186x; 1.1089x over previous
//
#include <hip/hip_runtime.h>
#include <hip/hip_bf16.h>
#include <hip/hip_fp16.h>

// GConvGRU with h=0 reduces to:
//   xagg = scatter_add(norm * x[src] -> dst)          [N,128]
//   z    = sigmoid(xagg @ W_xz + b_z)
//   ht   = tanh   (xagg @ W_xh + b_h)
//   out  = ((1-z)*ht) @ W_lin + b_lin                 [N,16]
// Model (R6-R10): scattered global writes cost 32B granules unless clustered;
// xh (12.8MB) misses per-XCD L2 ~2/3 of the time (FETCH 151MB = 410/2.7);
// MFMA epilogue proven (R10). R11: gather with 2 nodes/wave (half4 lanes,
// unroll 4 -> 8 rows in flight) + rec3 packed to u32 {fp16 w | u16 src}.

#define CH 128
#define HEADS 16
#define TM 64          // nodes per block in k_final2 (tier B)
#define KC 32          // K-chunk (tier B)
#define DRANGE 12800   // deg histogram: nodes per range (4 ranges)
#define DSLICES 64     // deg histogram: edge slices per range
#define RN 98          // nodes per partition range
#define NR 512         // partition ranges (512*98 >= 50000)
#define NB 256         // partition blocks (edge slices)
#define SCAP 3840      // sort stage capacity (mean 3136; global fallback)

typedef _Float16 half8 __attribute__((ext_vector_type(8)));
typedef _Float16 half4v __attribute__((ext_vector_type(4)));
typedef float floatx4 __attribute__((ext_vector_type(4)));

// =============== deg partials: LDS histogram over src ===============
__global__ __launch_bounds__(256) void k_deg(const int* __restrict__ src,
                                             const float* __restrict__ w,
                                             float* __restrict__ partial, int E) {
    __shared__ float h[DRANGE];
    const int r = blockIdx.x / DSLICES;
    const int sl = blockIdx.x % DSLICES;
    const int base = r * DRANGE;
    for (int i = threadIdx.x; i < DRANGE; i += 256) h[i] = 0.f;
    __syncthreads();
    const int per = (E + DSLICES - 1) / DSLICES;
    const int lo = sl * per;
    const int hi = min(lo + per, E);
    int e = lo + threadIdx.x * 4;
    for (; e + 3 < hi; e += 1024) {
        int4 s4 = *reinterpret_cast<const int4*>(src + e);
        float4 w4 = *reinterpret_cast<const float4*>(w + e);
        int a;
        a = s4.x - base; if ((unsigned)a < DRANGE) atomicAdd(&h[a], w4.x);
        a = s4.y - base; if ((unsigned)a < DRANGE) atomicAdd(&h[a], w4.y);
        a = s4.z - base; if ((unsigned)a < DRANGE) atomicAdd(&h[a], w4.z);
        a = s4.w - base; if ((unsigned)a < DRANGE) atomicAdd(&h[a], w4.w);
    }
    for (; e < hi; ++e) {
        int a = src[e] - base;
        if ((unsigned)a < DRANGE) atomicAdd(&h[a], w[e]);
    }
    __syncthreads();
    float* dstp = partial + ((size_t)r * DSLICES + sl) * DRANGE;
    for (int i = threadIdx.x; i < DRANGE; i += 256) dstp[i] = h[i];
}

// =============== fused: deg reduce + xh = half(x * rsqrt(deg)) ===============
__global__ __launch_bounds__(256) void k_degxc(const float* __restrict__ partial,
                                               const float* __restrict__ x,
                                               __half* __restrict__ xh, int n) {
    __shared__ float degl[256];
    const int bb = blockIdx.x * 256;
    const int t = threadIdx.x;
    int i = bb + t;
    if (i < n) {
        int r = i / DRANGE;
        int idx = i - r * DRANGE;
        const float* p = partial + (size_t)r * DSLICES * DRANGE + idx;
        float s = 0.f;
#pragma unroll 8
        for (int sl = 0; sl < DSLICES; ++sl) s += p[(size_t)sl * DRANGE];
        degl[t] = s;
    }
    __syncthreads();
#pragma unroll
    for (int g = 0; g < 16; ++g) {
        int ln = g * 16 + (t >> 4);
        int node = bb + ln;
        if (node >= n) break;
        int c8 = (t & 15) * 8;
        float dg = degl[ln];
        float sc = dg > 0.f ? rsqrtf(dg) : 0.f;
        float4 a = *reinterpret_cast<const float4*>(x + (size_t)node * CH + c8);
        float4 b = *reinterpret_cast<const float4*>(x + (size_t)node * CH + c8 + 4);
        __half2 h0 = __floats2half2_rn(a.x * sc, a.y * sc);
        __half2 h1 = __floats2half2_rn(a.z * sc, a.w * sc);
        __half2 h2 = __floats2half2_rn(b.x * sc, b.y * sc);
        __half2 h3 = __floats2half2_rn(b.z * sc, b.w * sc);
        uint4 packed = make_uint4(*(unsigned*)&h0, *(unsigned*)&h1, *(unsigned*)&h2, *(unsigned*)&h3);
        *reinterpret_cast<uint4*>(xh + (size_t)node * CH + c8) = packed;
    }
}

// =============== weight cast: WzT/WhT = fp16 W^T [outcol][k]; WlT [head][k] ===============
__global__ __launch_bounds__(256) void k_wcast(const float* __restrict__ Wxz,
                                               const float* __restrict__ Wxh,
                                               const float* __restrict__ Wlin,
                                               __half* __restrict__ WzT,
                                               __half* __restrict__ WhT,
                                               __half* __restrict__ WlT) {
    int i = blockIdx.x * 256 + threadIdx.x;
    if (i < CH * CH) {
        int nn = i >> 7, k = i & 127;
        WzT[i] = __float2half(Wxz[k * CH + nn]);
        WhT[i] = __float2half(Wxh[k * CH + nn]);
    } else if (i < CH * CH + HEADS * CH) {
        int j = i - CH * CH;
        int nn = j >> 7, k = j & 127;
        WlT[j] = __float2half(Wlin[k * HEADS + nn]);
    }
}

// =============== partition pass 1: per-block dst-range histogram ===============
__global__ __launch_bounds__(256) void k_count(const int* __restrict__ dst,
                                               unsigned* __restrict__ counts, int E) {
    __shared__ unsigned h[NR];
    const int b = blockIdx.x;
    for (int i = threadIdx.x; i < NR; i += 256) h[i] = 0u;
    __syncthreads();
    const int per = (E + NB - 1) / NB;
    const int lo = b * per;
    const int hi = min(lo + per, E);
    for (int e = lo + threadIdx.x; e < hi; e += 256)
        atomicAdd(&h[dst[e] / RN], 1u);
    __syncthreads();
    for (int i = threadIdx.x; i < NR; i += 256) counts[(size_t)i * NB + b] = h[i];
}

// per-range exclusive scan over blocks
__global__ __launch_bounds__(256) void k_scanR(unsigned* __restrict__ counts,
                                               unsigned* __restrict__ total) {
    __shared__ unsigned s[256];
    const int r = blockIdx.x;
    const int t = threadIdx.x;
    unsigned v = counts[(size_t)r * NB + t];
    s[t] = v;
    __syncthreads();
    for (int ofs = 1; ofs < 256; ofs <<= 1) {
        unsigned u = (t >= ofs) ? s[t - ofs] : 0u;
        __syncthreads();
        s[t] += u;
        __syncthreads();
    }
    counts[(size_t)r * NB + t] = s[t] - v;
    if (t == 255) total[r] = s[255];
}

// exclusive scan of total[NR] -> rbase[NR]; also off[n] = E
__global__ __launch_bounds__(512) void k_scanT(const unsigned* __restrict__ total,
                                               unsigned* __restrict__ rbase,
                                               unsigned* __restrict__ node_off,
                                               int n, int E) {
    __shared__ unsigned s[NR];
    const int t = threadIdx.x;
    unsigned v = total[t];
    s[t] = v;
    __syncthreads();
    for (int ofs = 1; ofs < NR; ofs <<= 1) {
        unsigned u = (t >= ofs) ? s[t - ofs] : 0u;
        __syncthreads();
        s[t] += u;
        __syncthreads();
    }
    rbase[t] = s[t] - v;
    if (t == 0) node_off[n] = (unsigned)E;
}

// =============== partition pass 2: scatter into contiguous chunks ===============
// rec2[pos] = { w(f32), dl<<16 | src }  (requires n <= 65536)
__global__ __launch_bounds__(256) void k_part(const int* __restrict__ src,
                                              const int* __restrict__ dst,
                                              const float* __restrict__ w,
                                              const unsigned* __restrict__ counts,
                                              const unsigned* __restrict__ rbase,
                                              int2* __restrict__ rec2, int E) {
    __shared__ unsigned cursor[NR];
    const int b = blockIdx.x;
    for (int r = threadIdx.x; r < NR; r += 256)
        cursor[r] = rbase[r] + counts[(size_t)r * NB + b];
    __syncthreads();
    const int per = (E + NB - 1) / NB;
    const int lo = b * per;
    const int hi = min(lo + per, E);
    for (int e = lo + threadIdx.x; e < hi; e += 256) {
        int d = dst[e];
        int r = d / RN;
        int dl = d - r * RN;
        unsigned pos = atomicAdd(&cursor[r], 1u);
        rec2[pos] = make_int2(__float_as_int(w[e]), (dl << 16) | src[e]);
    }
}

// =============== per-range LDS counting sort -> packed CSR rec3 + node_off ===============
// rec3[pos] = (fp16(w) << 16) | src
__global__ __launch_bounds__(256) void k_sortR(const unsigned* __restrict__ rbase,
                                               const unsigned* __restrict__ total,
                                               const int2* __restrict__ rec2,
                                               unsigned* __restrict__ rec3,
                                               unsigned* __restrict__ node_off, int n) {
    __shared__ int2 stage[SCAP];
    __shared__ unsigned hist[RN];
    __shared__ unsigned curx[RN];
    const int r = blockIdx.x;
    const int bn = r * RN;
    if (bn >= n) return;
    const int rn = min(RN, n - bn);
    const unsigned gbase = rbase[r];
    const unsigned tot = total[r];

    for (int i = threadIdx.x; i < RN; i += 256) hist[i] = 0u;
    __syncthreads();
    for (unsigned i = threadIdx.x; i < tot; i += 256) {
        int2 v = rec2[gbase + i];
        if (i < SCAP) stage[i] = v;
        atomicAdd(&hist[v.y >> 16], 1u);
    }
    __syncthreads();
    if (threadIdx.x == 0) {
        unsigned run = 0;
        for (int j = 0; j < rn; ++j) {
            unsigned c = hist[j];
            hist[j] = run;
            curx[j] = run;
            run += c;
        }
    }
    __syncthreads();
    for (int j = threadIdx.x; j < rn; j += 256)
        node_off[bn + j] = gbase + hist[j];
    for (unsigned i = threadIdx.x; i < tot; i += 256) {
        int2 v = (i < SCAP) ? stage[i] : rec2[gbase + i];
        int dl = v.y >> 16;
        __half hw = __float2half(__int_as_float(v.x));
        unsigned packed = ((unsigned)__half_as_ushort(hw) << 16) | (unsigned)(v.y & 0xFFFF);
        unsigned pos = atomicAdd(&curx[dl], 1u);
        rec3[gbase + pos] = packed;
    }
}

// =============== gather: 2 nodes per wave, 32 lanes/row (half4), unroll 4 ===============
__global__ __launch_bounds__(256) void k_gather4(const unsigned* __restrict__ off,
                                                 const unsigned* __restrict__ rec3,
                                                 const __half* __restrict__ xh,
                                                 __half* __restrict__ xaggh, int n) {
    int node = blockIdx.x * 8 + (threadIdx.x >> 5);
    if (node >= n) return;
    int lane = threadIdx.x & 31;
    unsigned i = off[node];
    unsigned end = off[node + 1];
    float acc0 = 0.f, acc1 = 0.f, acc2 = 0.f, acc3 = 0.f;
    float wsum = 0.f;
    for (; i + 4 <= end; i += 4) {
        unsigned r0 = rec3[i], r1 = rec3[i + 1], r2 = rec3[i + 2], r3 = rec3[i + 3];
        float w0 = __half2float(__ushort_as_half((unsigned short)(r0 >> 16)));
        float w1 = __half2float(__ushort_as_half((unsigned short)(r1 >> 16)));
        float w2 = __half2float(__ushort_as_half((unsigned short)(r2 >> 16)));
        float w3 = __half2float(__ushort_as_half((unsigned short)(r3 >> 16)));
        half4v v0 = *reinterpret_cast<const half4v*>(xh + (size_t)(r0 & 0xFFFFu) * CH + lane * 4);
        half4v v1 = *reinterpret_cast<const half4v*>(xh + (size_t)(r1 & 0xFFFFu) * CH + lane * 4);
        half4v v2 = *reinterpret_cast<const half4v*>(xh + (size_t)(r2 & 0xFFFFu) * CH + lane * 4);
        half4v v3 = *reinterpret_cast<const half4v*>(xh + (size_t)(r3 & 0xFFFFu) * CH + lane * 4);
        wsum += (w0 + w1) + (w2 + w3);
        acc0 = fmaf(w0, (float)v0[0], acc0); acc1 = fmaf(w0, (float)v0[1], acc1);
        acc2 = fmaf(w0, (float)v0[2], acc2); acc3 = fmaf(w0, (float)v0[3], acc3);
        acc0 = fmaf(w1, (float)v1[0], acc0); acc1 = fmaf(w1, (float)v1[1], acc1);
        acc2 = fmaf(w1, (float)v1[2], acc2); acc3 = fmaf(w1, (float)v1[3], acc3);
        acc0 = fmaf(w2, (float)v2[0], acc0); acc1 = fmaf(w2, (float)v2[1], acc1);
        acc2 = fmaf(w2, (float)v2[2], acc2); acc3 = fmaf(w2, (float)v2[3], acc3);
        acc0 = fmaf(w3, (float)v3[0], acc0); acc1 = fmaf(w3, (float)v3[1], acc1);
        acc2 = fmaf(w3, (float)v3[2], acc2); acc3 = fmaf(w3, (float)v3[3], acc3);
    }
    for (; i < end; ++i) {
        unsigned r0 = rec3[i];
        float w0 = __half2float(__ushort_as_half((unsigned short)(r0 >> 16)));
        half4v v0 = *reinterpret_cast<const half4v*>(xh + (size_t)(r0 & 0xFFFFu) * CH + lane * 4);
        wsum += w0;
        acc0 = fmaf(w0, (float)v0[0], acc0); acc1 = fmaf(w0, (float)v0[1], acc1);
        acc2 = fmaf(w0, (float)v0[2], acc2); acc3 = fmaf(w0, (float)v0[3], acc3);
    }
    float sc = wsum > 0.f ? rsqrtf(wsum) : 0.f;
    half4v hv;
    hv[0] = (_Float16)(acc0 * sc); hv[1] = (_Float16)(acc1 * sc);
    hv[2] = (_Float16)(acc2 * sc); hv[3] = (_Float16)(acc3 * sc);
    *reinterpret_cast<half4v*>(xaggh + (size_t)node * CH + lane * 4) = hv;
}

// =============== MFMA epilogue (R10, proven) ===============
__global__ __launch_bounds__(256) void k_final3(const __half* __restrict__ xaggh,
                                                const __half* __restrict__ WzT,
                                                const __half* __restrict__ WhT,
                                                const __half* __restrict__ WlT,
                                                const float* __restrict__ bz,
                                                const float* __restrict__ bh,
                                                const float* __restrict__ blin,
                                                float* __restrict__ out, int n) {
    __shared__ __half gL[4][16][136];
    const int tid = threadIdx.x;
    const int w = tid >> 6;
    const int l = tid & 63;
    const int lr = l & 15;
    const int lk = l >> 4;
    const int nodeb = blockIdx.x * 64 + w * 16;

    int arow = nodeb + lr;
    if (arow > n - 1) arow = n - 1;

    floatx4 accz[8], acch[8];
#pragma unroll
    for (int ct = 0; ct < 8; ++ct) {
        accz[ct] = (floatx4){0.f, 0.f, 0.f, 0.f};
        acch[ct] = (floatx4){0.f, 0.f, 0.f, 0.f};
    }

#pragma unroll
    for (int kc = 0; kc < 4; ++kc) {
        half8 a = *reinterpret_cast<const half8*>(xaggh + (size_t)arow * CH + kc * 32 + lk * 8);
#pragma unroll
        for (int ct = 0; ct < 8; ++ct) {
            half8 bzf = *reinterpret_cast<const half8*>(WzT + (ct * 16 + lr) * CH + kc * 32 + lk * 8);
            accz[ct] = __builtin_amdgcn_mfma_f32_16x16x32_f16(a, bzf, accz[ct], 0, 0, 0);
            half8 bhf = *reinterpret_cast<const half8*>(WhT + (ct * 16 + lr) * CH + kc * 32 + lk * 8);
            acch[ct] = __builtin_amdgcn_mfma_f32_16x16x32_f16(a, bhf, acch[ct], 0, 0, 0);
        }
    }

#pragma unroll
    for (int ct = 0; ct < 8; ++ct) {
        float bzv = bz[ct * 16 + lr];
        float bhv = bh[ct * 16 + lr];
#pragma unroll
        for (int r = 0; r < 4; ++r) {
            float zp = accz[ct][r] + bzv;
            float hp = acch[ct][r] + bhv;
            float g = (1.f - 1.f / (1.f + __expf(-zp))) * tanhf(hp);
            gL[w][lk * 4 + r][ct * 16 + lr] = __float2half(g);
        }
    }
    __syncthreads();

    floatx4 acco = (floatx4){0.f, 0.f, 0.f, 0.f};
#pragma unroll
    for (int kc = 0; kc < 4; ++kc) {
        half8 a = *reinterpret_cast<const half8*>(&gL[w][lr][kc * 32 + lk * 8]);
        half8 b = *reinterpret_cast<const half8*>(WlT + lr * CH + kc * 32 + lk * 8);
        acco = __builtin_amdgcn_mfma_f32_16x16x32_f16(a, b, acco, 0, 0, 0);
    }
    float bl = blin[lr];
#pragma unroll
    for (int r = 0; r < 4; ++r) {
        int node = nodeb + lk * 4 + r;
        if (node < n) out[(size_t)node * HEADS + lr] = acco[r] + bl;
    }
}

// =============== Tier B (CSR fallback, proven) ===============
__global__ __launch_bounds__(256) void k1B(const int* __restrict__ src,
                                           const int* __restrict__ dst,
                                           const float* __restrict__ w,
                                           float* __restrict__ deg_out,
                                           unsigned* __restrict__ cnt, int E) {
    int e = blockIdx.x * blockDim.x + threadIdx.x;
    if (e >= E) return;
    unsafeAtomicAdd(deg_out + src[e], w[e]);
    atomicAdd(cnt + dst[e], 1u);
}

__global__ __launch_bounds__(1024) void k_scan(unsigned* __restrict__ off, int n) {
    __shared__ unsigned s[1024];
    const int t = threadIdx.x;
    const int per = (n + 1023) / 1024;
    int lo = t * per;
    int hi = lo + per; if (hi > n) hi = n;
    unsigned sum = 0;
    for (int i = lo; i < hi; ++i) sum += off[i];
    s[t] = sum;
    __syncthreads();
    for (int ofs = 1; ofs < 1024; ofs <<= 1) {
        unsigned v = (t >= ofs) ? s[t - ofs] : 0u;
        __syncthreads();
        s[t] += v;
        __syncthreads();
    }
    unsigned run = s[t] - sum;
    for (int i = lo; i < hi; ++i) {
        unsigned c = off[i];
        off[i] = run;
        run += c;
    }
}

__global__ __launch_bounds__(256) void k_fillB(const int* __restrict__ src,
                                               const int* __restrict__ dst,
                                               const float* __restrict__ w,
                                               unsigned* __restrict__ off,
                                               int2* __restrict__ rec, int E) {
    int e = blockIdx.x * blockDim.x + threadIdx.x;
    if (e >= E) return;
    unsigned pos = atomicAdd(off + dst[e], 1u);
    rec[pos] = make_int2(__float_as_int(w[e]), src[e]);
}

__global__ __launch_bounds__(256) void k_gatherB(const unsigned* __restrict__ off,
                                                 const int2* __restrict__ rec,
                                                 const float* __restrict__ deg_out,
                                                 const float* __restrict__ x,
                                                 float* __restrict__ xagg, int n) {
    int node = blockIdx.x * 4 + (threadIdx.x >> 6);
    if (node >= n) return;
    int lane = threadIdx.x & 63;
    unsigned i = node ? off[node - 1] : 0u;
    unsigned end = off[node];
    float2 acc = make_float2(0.f, 0.f);
    float wsum = 0.f;
    for (; i < end; ++i) {
        int2 r0 = rec[i];
        float w0 = __int_as_float(r0.x);
        float d0 = deg_out[r0.y];
        float c0 = w0 * (d0 > 0.f ? rsqrtf(d0) : 0.f);
        float2 v = *reinterpret_cast<const float2*>(x + (size_t)r0.y * CH + lane * 2);
        wsum += w0;
        acc.x = fmaf(c0, v.x, acc.x);
        acc.y = fmaf(c0, v.y, acc.y);
    }
    float sc = wsum > 0.f ? rsqrtf(wsum) : 0.f;
    *reinterpret_cast<float2*>(xagg + (size_t)node * CH + lane * 2) =
        make_float2(acc.x * sc, acc.y * sc);
}

__global__ __launch_bounds__(256) void k_final2(const float* __restrict__ xagg,
                                                const float* __restrict__ Wxz,
                                                const float* __restrict__ bz,
                                                const float* __restrict__ Wxh,
                                                const float* __restrict__ bh,
                                                const float* __restrict__ Wlin,
                                                const float* __restrict__ blin,
                                                float* __restrict__ out, int n) {
    __shared__ float smem[10560];
    float* sA = smem;
    float* sWz = smem + 2304;
    float* sWh = smem + 6400;

    const int tid = threadIdx.x;
    const int tx = tid & 31;
    const int ty = tid >> 5;
    const int base = blockIdx.x * TM;

    float az[8][4] = {{0.f}};
    float ah[8][4] = {{0.f}};

    for (int kc = 0; kc < CH; kc += KC) {
        {
            int i = tid;
#pragma unroll
            for (int r2 = 0; r2 < 2; ++r2, i += 256) {
                int row = i >> 3;
                int c4 = (i & 7) * 4;
                int grow = base + row; if (grow > n - 1) grow = n - 1;
                float4 v = *reinterpret_cast<const float4*>(xagg + (size_t)grow * CH + kc + c4);
                *reinterpret_cast<float4*>(&sA[row * 36 + c4]) = v;
            }
            int j = tid;
#pragma unroll
            for (int r2 = 0; r2 < 4; ++r2, j += 256) {
                int row = j >> 5;
                int c4 = (j & 31) * 4;
                *reinterpret_cast<float4*>(&sWz[row * 128 + c4]) =
                    *reinterpret_cast<const float4*>(Wxz + (size_t)(kc + row) * CH + c4);
                *reinterpret_cast<float4*>(&sWh[row * 128 + c4]) =
                    *reinterpret_cast<const float4*>(Wxh + (size_t)(kc + row) * CH + c4);
            }
        }
        __syncthreads();
#pragma unroll 4
        for (int kk = 0; kk < KC; ++kk) {
            float4 wz = *reinterpret_cast<float4*>(&sWz[kk * 128 + tx * 4]);
            float4 wh = *reinterpret_cast<float4*>(&sWh[kk * 128 + tx * 4]);
#pragma unroll
            for (int r = 0; r < 8; ++r) {
                float a = sA[(ty * 8 + r) * 36 + kk];
                az[r][0] = fmaf(a, wz.x, az[r][0]);
                az[r][1] = fmaf(a, wz.y, az[r][1]);
                az[r][2] = fmaf(a, wz.z, az[r][2]);
                az[r][3] = fmaf(a, wz.w, az[r][3]);
                ah[r][0] = fmaf(a, wh.x, ah[r][0]);
                ah[r][1] = fmaf(a, wh.y, ah[r][1]);
                ah[r][2] = fmaf(a, wh.z, ah[r][2]);
                ah[r][3] = fmaf(a, wh.w, ah[r][3]);
            }
        }
        __syncthreads();
    }

    float* sG = smem;
    const float4 bz4 = *reinterpret_cast<const float4*>(bz + tx * 4);
    const float4 bh4 = *reinterpret_cast<const float4*>(bh + tx * 4);
#pragma unroll
    for (int r = 0; r < 8; ++r) {
        int row = ty * 8 + r;
        float4 g4;
        float zp = az[r][0] + bz4.x, hp = ah[r][0] + bh4.x;
        g4.x = (1.f - 1.f / (1.f + __expf(-zp))) * tanhf(hp);
        zp = az[r][1] + bz4.y; hp = ah[r][1] + bh4.y;
        g4.y = (1.f - 1.f / (1.f + __expf(-zp))) * tanhf(hp);
        zp = az[r][2] + bz4.z; hp = ah[r][2] + bh4.z;
        g4.z = (1.f - 1.f / (1.f + __expf(-zp))) * tanhf(hp);
        zp = az[r][3] + bz4.w; hp = ah[r][3] + bh4.w;
        g4.w = (1.f - 1.f / (1.f + __expf(-zp))) * tanhf(hp);
        *reinterpret_cast<float4*>(&sG[row * 132 + tx * 4]) = g4;
    }
    __syncthreads();

#pragma unroll
    for (int it = 0; it < 4; ++it) {
        int idx = it * 256 + tid;
        int node = idx >> 4;
        int hh = idx & 15;
        float acc = blin[hh];
#pragma unroll 8
        for (int j = 0; j < CH; ++j)
            acc = fmaf(sG[node * 132 + j], Wlin[j * HEADS + hh], acc);
        if (base + node < n) out[(size_t)(base + node) * HEADS + hh] = acc;
    }
}

static inline size_t align256(size_t v) { return (v + 255) & ~(size_t)255; }

extern "C" void kernel_launch(void* const* d_in, const int* in_sizes, int n_in,
                              void* d_out, int out_size, void* d_ws, size_t ws_size,
                              hipStream_t stream) {
    const float* x = (const float*)d_in[0];
    const int* ei = (const int*)d_in[1];     // int32 on device (harness narrows int64)
    const float* w = (const float*)d_in[2];
    const float* Wxz = (const float*)d_in[3];
    const float* bz = (const float*)d_in[5];
    const float* Wxh = (const float*)d_in[9];
    const float* bh = (const float*)d_in[11];
    const float* Wlin = (const float*)d_in[12];
    const float* blin = (const float*)d_in[13];
    float* out = (float*)d_out;

    const int Nn = in_sizes[0] / CH;  // 50000
    const int E = in_sizes[2];        // 1,600,000

    const int* src = ei;
    const int* dst = ei + E;
    int eb = (E + 255) / 256;
    char* base = (char*)d_ws;

    // Tier A layout (aligned):
    size_t off_counts = 0;                                         // NR*NB u32
    size_t off_total = align256(off_counts + (size_t)NR * NB * 4); // NR u32
    size_t off_rbase = align256(off_total + NR * 4);               // NR u32
    size_t off_noff = align256(off_rbase + NR * 4);                // (N+1) u32
    size_t off_xh = align256(off_noff + ((size_t)Nn + 1) * 4);     // N*CH half
    size_t off_xaggh = align256(off_xh + (size_t)Nn * CH * 2);     // N*CH half
    size_t off_wz = align256(off_xaggh + (size_t)Nn * CH * 2);     // CH*CH half
    size_t off_wh = align256(off_wz + (size_t)CH * CH * 2);        // CH*CH half
    size_t off_wl = align256(off_wh + (size_t)CH * CH * 2);        // HEADS*CH half
    size_t off_rec2 = align256(off_wl + (size_t)HEADS * CH * 2);   // E int2
    size_t off_rec3 = align256(off_rec2 + (size_t)E * 8);          // E u32 (packed)
    size_t needNew = off_rec3 + (size_t)E * 4;
    size_t partial_bytes = (size_t)4 * DSLICES * DRANGE * 4;       // 13.1MB, overlays rec2+rec3

    if (ws_size >= needNew && Nn <= 65536 && (size_t)NR * RN >= (size_t)Nn &&
        partial_bytes <= (size_t)E * 12) {
        unsigned* counts = (unsigned*)(base + off_counts);
        unsigned* total = (unsigned*)(base + off_total);
        unsigned* rbase = (unsigned*)(base + off_rbase);
        unsigned* noff = (unsigned*)(base + off_noff);
        __half* xh = (__half*)(base + off_xh);
        __half* xaggh = (__half*)(base + off_xaggh);
        __half* WzT = (__half*)(base + off_wz);
        __half* WhT = (__half*)(base + off_wh);
        __half* WlT = (__half*)(base + off_wl);
        int2* rec2 = (int2*)(base + off_rec2);
        unsigned* rec3 = (unsigned*)(base + off_rec3);
        float* partial = (float*)(base + off_rec2);  // overlay: dead after k_degxc

        k_deg<<<4 * DSLICES, 256, 0, stream>>>(src, w, partial, E);
        k_degxc<<<(Nn + 255) / 256, 256, 0, stream>>>(partial, x, xh, Nn);
        k_wcast<<<(CH * CH + HEADS * CH + 255) / 256, 256, 0, stream>>>(Wxz, Wxh, Wlin, WzT, WhT, WlT);
        k_count<<<NB, 256, 0, stream>>>(dst, counts, E);
        k_scanR<<<NR, 256, 0, stream>>>(counts, total);
        k_scanT<<<1, NR, 0, stream>>>(total, rbase, noff, Nn, E);
        k_part<<<NB, 256, 0, stream>>>(src, dst, w, counts, rbase, rec2, E);
        k_sortR<<<NR, 256, 0, stream>>>(rbase, total, rec2, rec3, noff, Nn);
        k_gather4<<<(Nn + 7) / 8, 256, 0, stream>>>(noff, rec3, xh, xaggh, Nn);
        k_final3<<<(Nn + 63) / 64, 256, 0, stream>>>(xaggh, WzT, WhT, WlT, bz, bh, blin, out, Nn);
    } else {
        // Tier B: CSR fallback (proven)
        unsigned* off = (unsigned*)base;
        float* deg_out = (float*)(base + (size_t)Nn * 4);
        int2* rec = (int2*)(base + (size_t)2 * Nn * 4);
        float* xagg = (float*)((char*)rec + (size_t)E * 8);

        hipMemsetAsync(d_ws, 0, (size_t)2 * Nn * 4, stream);
        k1B<<<eb, 256, 0, stream>>>(src, dst, w, deg_out, off, E);
        k_scan<<<1, 1024, 0, stream>>>(off, Nn);
        k_fillB<<<eb, 256, 0, stream>>>(src, dst, w, off, rec, E);
        k_gatherB<<<(Nn + 3) / 4, 256, 0, stream>>>(off, rec, deg_out, x, xagg, Nn);
        k_final2<<<(Nn + TM - 1) / TM, 256, 0, stream>>>(xagg, Wxz, bz, Wxh, bh, Wlin, blin, out, Nn);
    }
}

// Round 12
// 171.413 us; speedup vs baseline: 7.2347x; 1.0163x over previous
//
#include <hip/hip_runtime.h>
#include <hip/hip_bf16.h>
#include <hip/hip_fp16.h>

// GConvGRU with h=0 reduces to:
//   xagg = scatter_add(norm * x[src] -> dst)          [N,128]
//   z    = sigmoid(xagg @ W_xz + b_z)
//   ht   = tanh   (xagg @ W_xh + b_h)
//   out  = ((1-z)*ht) @ W_lin + b_lin                 [N,16]
// Model (R6-R11): scattered global writes cost 32B granules unless clustered;
// gather's 410MB of random 256B row reads miss per-XCD L2 ~2/3 -> served by
// L3 at ~3TB/s, partially latency-bound. MFMA epilogue proven (R10).
// R12: gather unroll 8 (8 independent row loads in flight/wave, 2x MLP).

#define CH 128
#define HEADS 16
#define TM 64          // nodes per block in k_final2 (tier B)
#define KC 32          // K-chunk (tier B)
#define DRANGE 12800   // deg histogram: nodes per range (4 ranges)
#define DSLICES 64     // deg histogram: edge slices per range
#define RN 98          // nodes per partition range
#define NR 512         // partition ranges (512*98 >= 50000)
#define NB 256         // partition blocks (edge slices)
#define SCAP 3840      // sort stage capacity (mean 3136; global fallback)

typedef _Float16 half8 __attribute__((ext_vector_type(8)));
typedef _Float16 half4v __attribute__((ext_vector_type(4)));
typedef float floatx4 __attribute__((ext_vector_type(4)));

// =============== deg partials: LDS histogram over src ===============
__global__ __launch_bounds__(256) void k_deg(const int* __restrict__ src,
                                             const float* __restrict__ w,
                                             float* __restrict__ partial, int E) {
    __shared__ float h[DRANGE];
    const int r = blockIdx.x / DSLICES;
    const int sl = blockIdx.x % DSLICES;
    const int base = r * DRANGE;
    for (int i = threadIdx.x; i < DRANGE; i += 256) h[i] = 0.f;
    __syncthreads();
    const int per = (E + DSLICES - 1) / DSLICES;
    const int lo = sl * per;
    const int hi = min(lo + per, E);
    int e = lo + threadIdx.x * 4;
    for (; e + 3 < hi; e += 1024) {
        int4 s4 = *reinterpret_cast<const int4*>(src + e);
        float4 w4 = *reinterpret_cast<const float4*>(w + e);
        int a;
        a = s4.x - base; if ((unsigned)a < DRANGE) atomicAdd(&h[a], w4.x);
        a = s4.y - base; if ((unsigned)a < DRANGE) atomicAdd(&h[a], w4.y);
        a = s4.z - base; if ((unsigned)a < DRANGE) atomicAdd(&h[a], w4.z);
        a = s4.w - base; if ((unsigned)a < DRANGE) atomicAdd(&h[a], w4.w);
    }
    for (; e < hi; ++e) {
        int a = src[e] - base;
        if ((unsigned)a < DRANGE) atomicAdd(&h[a], w[e]);
    }
    __syncthreads();
    float* dstp = partial + ((size_t)r * DSLICES + sl) * DRANGE;
    for (int i = threadIdx.x; i < DRANGE; i += 256) dstp[i] = h[i];
}

// =============== fused: deg reduce + xh = half(x * rsqrt(deg)) ===============
__global__ __launch_bounds__(256) void k_degxc(const float* __restrict__ partial,
                                               const float* __restrict__ x,
                                               __half* __restrict__ xh, int n) {
    __shared__ float degl[256];
    const int bb = blockIdx.x * 256;
    const int t = threadIdx.x;
    int i = bb + t;
    if (i < n) {
        int r = i / DRANGE;
        int idx = i - r * DRANGE;
        const float* p = partial + (size_t)r * DSLICES * DRANGE + idx;
        float s = 0.f;
#pragma unroll 8
        for (int sl = 0; sl < DSLICES; ++sl) s += p[(size_t)sl * DRANGE];
        degl[t] = s;
    }
    __syncthreads();
#pragma unroll
    for (int g = 0; g < 16; ++g) {
        int ln = g * 16 + (t >> 4);
        int node = bb + ln;
        if (node >= n) break;
        int c8 = (t & 15) * 8;
        float dg = degl[ln];
        float sc = dg > 0.f ? rsqrtf(dg) : 0.f;
        float4 a = *reinterpret_cast<const float4*>(x + (size_t)node * CH + c8);
        float4 b = *reinterpret_cast<const float4*>(x + (size_t)node * CH + c8 + 4);
        __half2 h0 = __floats2half2_rn(a.x * sc, a.y * sc);
        __half2 h1 = __floats2half2_rn(a.z * sc, a.w * sc);
        __half2 h2 = __floats2half2_rn(b.x * sc, b.y * sc);
        __half2 h3 = __floats2half2_rn(b.z * sc, b.w * sc);
        uint4 packed = make_uint4(*(unsigned*)&h0, *(unsigned*)&h1, *(unsigned*)&h2, *(unsigned*)&h3);
        *reinterpret_cast<uint4*>(xh + (size_t)node * CH + c8) = packed;
    }
}

// =============== weight cast: WzT/WhT = fp16 W^T [outcol][k]; WlT [head][k] ===============
__global__ __launch_bounds__(256) void k_wcast(const float* __restrict__ Wxz,
                                               const float* __restrict__ Wxh,
                                               const float* __restrict__ Wlin,
                                               __half* __restrict__ WzT,
                                               __half* __restrict__ WhT,
                                               __half* __restrict__ WlT) {
    int i = blockIdx.x * 256 + threadIdx.x;
    if (i < CH * CH) {
        int nn = i >> 7, k = i & 127;
        WzT[i] = __float2half(Wxz[k * CH + nn]);
        WhT[i] = __float2half(Wxh[k * CH + nn]);
    } else if (i < CH * CH + HEADS * CH) {
        int j = i - CH * CH;
        int nn = j >> 7, k = j & 127;
        WlT[j] = __float2half(Wlin[k * HEADS + nn]);
    }
}

// =============== partition pass 1: per-block dst-range histogram ===============
__global__ __launch_bounds__(256) void k_count(const int* __restrict__ dst,
                                               unsigned* __restrict__ counts, int E) {
    __shared__ unsigned h[NR];
    const int b = blockIdx.x;
    for (int i = threadIdx.x; i < NR; i += 256) h[i] = 0u;
    __syncthreads();
    const int per = (E + NB - 1) / NB;
    const int lo = b * per;
    const int hi = min(lo + per, E);
    for (int e = lo + threadIdx.x; e < hi; e += 256)
        atomicAdd(&h[dst[e] / RN], 1u);
    __syncthreads();
    for (int i = threadIdx.x; i < NR; i += 256) counts[(size_t)i * NB + b] = h[i];
}

// per-range exclusive scan over blocks
__global__ __launch_bounds__(256) void k_scanR(unsigned* __restrict__ counts,
                                               unsigned* __restrict__ total) {
    __shared__ unsigned s[256];
    const int r = blockIdx.x;
    const int t = threadIdx.x;
    unsigned v = counts[(size_t)r * NB + t];
    s[t] = v;
    __syncthreads();
    for (int ofs = 1; ofs < 256; ofs <<= 1) {
        unsigned u = (t >= ofs) ? s[t - ofs] : 0u;
        __syncthreads();
        s[t] += u;
        __syncthreads();
    }
    counts[(size_t)r * NB + t] = s[t] - v;
    if (t == 255) total[r] = s[255];
}

// exclusive scan of total[NR] -> rbase[NR]; also off[n] = E
__global__ __launch_bounds__(512) void k_scanT(const unsigned* __restrict__ total,
                                               unsigned* __restrict__ rbase,
                                               unsigned* __restrict__ node_off,
                                               int n, int E) {
    __shared__ unsigned s[NR];
    const int t = threadIdx.x;
    unsigned v = total[t];
    s[t] = v;
    __syncthreads();
    for (int ofs = 1; ofs < NR; ofs <<= 1) {
        unsigned u = (t >= ofs) ? s[t - ofs] : 0u;
        __syncthreads();
        s[t] += u;
        __syncthreads();
    }
    rbase[t] = s[t] - v;
    if (t == 0) node_off[n] = (unsigned)E;
}

// =============== partition pass 2: scatter into contiguous chunks ===============
// rec2[pos] = { w(f32), dl<<16 | src }  (requires n <= 65536)
__global__ __launch_bounds__(256) void k_part(const int* __restrict__ src,
                                              const int* __restrict__ dst,
                                              const float* __restrict__ w,
                                              const unsigned* __restrict__ counts,
                                              const unsigned* __restrict__ rbase,
                                              int2* __restrict__ rec2, int E) {
    __shared__ unsigned cursor[NR];
    const int b = blockIdx.x;
    for (int r = threadIdx.x; r < NR; r += 256)
        cursor[r] = rbase[r] + counts[(size_t)r * NB + b];
    __syncthreads();
    const int per = (E + NB - 1) / NB;
    const int lo = b * per;
    const int hi = min(lo + per, E);
    for (int e = lo + threadIdx.x; e < hi; e += 256) {
        int d = dst[e];
        int r = d / RN;
        int dl = d - r * RN;
        unsigned pos = atomicAdd(&cursor[r], 1u);
        rec2[pos] = make_int2(__float_as_int(w[e]), (dl << 16) | src[e]);
    }
}

// =============== per-range LDS counting sort -> packed CSR rec3 + node_off ===============
// rec3[pos] = (fp16(w) << 16) | src
__global__ __launch_bounds__(256) void k_sortR(const unsigned* __restrict__ rbase,
                                               const unsigned* __restrict__ total,
                                               const int2* __restrict__ rec2,
                                               unsigned* __restrict__ rec3,
                                               unsigned* __restrict__ node_off, int n) {
    __shared__ int2 stage[SCAP];
    __shared__ unsigned hist[RN];
    __shared__ unsigned curx[RN];
    const int r = blockIdx.x;
    const int bn = r * RN;
    if (bn >= n) return;
    const int rn = min(RN, n - bn);
    const unsigned gbase = rbase[r];
    const unsigned tot = total[r];

    for (int i = threadIdx.x; i < RN; i += 256) hist[i] = 0u;
    __syncthreads();
    for (unsigned i = threadIdx.x; i < tot; i += 256) {
        int2 v = rec2[gbase + i];
        if (i < SCAP) stage[i] = v;
        atomicAdd(&hist[v.y >> 16], 1u);
    }
    __syncthreads();
    if (threadIdx.x == 0) {
        unsigned run = 0;
        for (int j = 0; j < rn; ++j) {
            unsigned c = hist[j];
            hist[j] = run;
            curx[j] = run;
            run += c;
        }
    }
    __syncthreads();
    for (int j = threadIdx.x; j < rn; j += 256)
        node_off[bn + j] = gbase + hist[j];
    for (unsigned i = threadIdx.x; i < tot; i += 256) {
        int2 v = (i < SCAP) ? stage[i] : rec2[gbase + i];
        int dl = v.y >> 16;
        __half hw = __float2half(__int_as_float(v.x));
        unsigned packed = ((unsigned)__half_as_ushort(hw) << 16) | (unsigned)(v.y & 0xFFFF);
        unsigned pos = atomicAdd(&curx[dl], 1u);
        rec3[gbase + pos] = packed;
    }
}

// =============== gather: 2 nodes/wave, 32 lanes/row (half4), unroll 8 ===============
__global__ __launch_bounds__(256) void k_gather5(const unsigned* __restrict__ off,
                                                 const unsigned* __restrict__ rec3,
                                                 const __half* __restrict__ xh,
                                                 __half* __restrict__ xaggh, int n) {
    int node = blockIdx.x * 8 + (threadIdx.x >> 5);
    if (node >= n) return;
    int lane = threadIdx.x & 31;
    const __half* xb = xh + lane * 4;
    unsigned i = off[node];
    unsigned end = off[node + 1];
    float acc0 = 0.f, acc1 = 0.f, acc2 = 0.f, acc3 = 0.f;
    float wsum = 0.f;
    for (; i + 8 <= end; i += 8) {
        unsigned r0 = rec3[i],     r1 = rec3[i + 1], r2 = rec3[i + 2], r3 = rec3[i + 3];
        unsigned r4 = rec3[i + 4], r5 = rec3[i + 5], r6 = rec3[i + 6], r7 = rec3[i + 7];
        half4v v0 = *reinterpret_cast<const half4v*>(xb + (size_t)(r0 & 0xFFFFu) * CH);
        half4v v1 = *reinterpret_cast<const half4v*>(xb + (size_t)(r1 & 0xFFFFu) * CH);
        half4v v2 = *reinterpret_cast<const half4v*>(xb + (size_t)(r2 & 0xFFFFu) * CH);
        half4v v3 = *reinterpret_cast<const half4v*>(xb + (size_t)(r3 & 0xFFFFu) * CH);
        half4v v4 = *reinterpret_cast<const half4v*>(xb + (size_t)(r4 & 0xFFFFu) * CH);
        half4v v5 = *reinterpret_cast<const half4v*>(xb + (size_t)(r5 & 0xFFFFu) * CH);
        half4v v6 = *reinterpret_cast<const half4v*>(xb + (size_t)(r6 & 0xFFFFu) * CH);
        half4v v7 = *reinterpret_cast<const half4v*>(xb + (size_t)(r7 & 0xFFFFu) * CH);
        float w0 = __half2float(__ushort_as_half((unsigned short)(r0 >> 16)));
        float w1 = __half2float(__ushort_as_half((unsigned short)(r1 >> 16)));
        float w2 = __half2float(__ushort_as_half((unsigned short)(r2 >> 16)));
        float w3 = __half2float(__ushort_as_half((unsigned short)(r3 >> 16)));
        float w4 = __half2float(__ushort_as_half((unsigned short)(r4 >> 16)));
        float w5 = __half2float(__ushort_as_half((unsigned short)(r5 >> 16)));
        float w6 = __half2float(__ushort_as_half((unsigned short)(r6 >> 16)));
        float w7 = __half2float(__ushort_as_half((unsigned short)(r7 >> 16)));
        wsum += ((w0 + w1) + (w2 + w3)) + ((w4 + w5) + (w6 + w7));
        acc0 = fmaf(w0, (float)v0[0], acc0); acc1 = fmaf(w0, (float)v0[1], acc1);
        acc2 = fmaf(w0, (float)v0[2], acc2); acc3 = fmaf(w0, (float)v0[3], acc3);
        acc0 = fmaf(w1, (float)v1[0], acc0); acc1 = fmaf(w1, (float)v1[1], acc1);
        acc2 = fmaf(w1, (float)v1[2], acc2); acc3 = fmaf(w1, (float)v1[3], acc3);
        acc0 = fmaf(w2, (float)v2[0], acc0); acc1 = fmaf(w2, (float)v2[1], acc1);
        acc2 = fmaf(w2, (float)v2[2], acc2); acc3 = fmaf(w2, (float)v2[3], acc3);
        acc0 = fmaf(w3, (float)v3[0], acc0); acc1 = fmaf(w3, (float)v3[1], acc1);
        acc2 = fmaf(w3, (float)v3[2], acc2); acc3 = fmaf(w3, (float)v3[3], acc3);
        acc0 = fmaf(w4, (float)v4[0], acc0); acc1 = fmaf(w4, (float)v4[1], acc1);
        acc2 = fmaf(w4, (float)v4[2], acc2); acc3 = fmaf(w4, (float)v4[3], acc3);
        acc0 = fmaf(w5, (float)v5[0], acc0); acc1 = fmaf(w5, (float)v5[1], acc1);
        acc2 = fmaf(w5, (float)v5[2], acc2); acc3 = fmaf(w5, (float)v5[3], acc3);
        acc0 = fmaf(w6, (float)v6[0], acc0); acc1 = fmaf(w6, (float)v6[1], acc1);
        acc2 = fmaf(w6, (float)v6[2], acc2); acc3 = fmaf(w6, (float)v6[3], acc3);
        acc0 = fmaf(w7, (float)v7[0], acc0); acc1 = fmaf(w7, (float)v7[1], acc1);
        acc2 = fmaf(w7, (float)v7[2], acc2); acc3 = fmaf(w7, (float)v7[3], acc3);
    }
    for (; i + 4 <= end; i += 4) {
        unsigned r0 = rec3[i], r1 = rec3[i + 1], r2 = rec3[i + 2], r3 = rec3[i + 3];
        half4v v0 = *reinterpret_cast<const half4v*>(xb + (size_t)(r0 & 0xFFFFu) * CH);
        half4v v1 = *reinterpret_cast<const half4v*>(xb + (size_t)(r1 & 0xFFFFu) * CH);
        half4v v2 = *reinterpret_cast<const half4v*>(xb + (size_t)(r2 & 0xFFFFu) * CH);
        half4v v3 = *reinterpret_cast<const half4v*>(xb + (size_t)(r3 & 0xFFFFu) * CH);
        float w0 = __half2float(__ushort_as_half((unsigned short)(r0 >> 16)));
        float w1 = __half2float(__ushort_as_half((unsigned short)(r1 >> 16)));
        float w2 = __half2float(__ushort_as_half((unsigned short)(r2 >> 16)));
        float w3 = __half2float(__ushort_as_half((unsigned short)(r3 >> 16)));
        wsum += (w0 + w1) + (w2 + w3);
        acc0 = fmaf(w0, (float)v0[0], acc0); acc1 = fmaf(w0, (float)v0[1], acc1);
        acc2 = fmaf(w0, (float)v0[2], acc2); acc3 = fmaf(w0, (float)v0[3], acc3);
        acc0 = fmaf(w1, (float)v1[0], acc0); acc1 = fmaf(w1, (float)v1[1], acc1);
        acc2 = fmaf(w1, (float)v1[2], acc2); acc3 = fmaf(w1, (float)v1[3], acc3);
        acc0 = fmaf(w2, (float)v2[0], acc0); acc1 = fmaf(w2, (float)v2[1], acc1);
        acc2 = fmaf(w2, (float)v2[2], acc2); acc3 = fmaf(w2, (float)v2[3], acc3);
        acc0 = fmaf(w3, (float)v3[0], acc0); acc1 = fmaf(w3, (float)v3[1], acc1);
        acc2 = fmaf(w3, (float)v3[2], acc2); acc3 = fmaf(w3, (float)v3[3], acc3);
    }
    for (; i < end; ++i) {
        unsigned r0 = rec3[i];
        float w0 = __half2float(__ushort_as_half((unsigned short)(r0 >> 16)));
        half4v v0 = *reinterpret_cast<const half4v*>(xb + (size_t)(r0 & 0xFFFFu) * CH);
        wsum += w0;
        acc0 = fmaf(w0, (float)v0[0], acc0); acc1 = fmaf(w0, (float)v0[1], acc1);
        acc2 = fmaf(w0, (float)v0[2], acc2); acc3 = fmaf(w0, (float)v0[3], acc3);
    }
    float sc = wsum > 0.f ? rsqrtf(wsum) : 0.f;
    half4v hv;
    hv[0] = (_Float16)(acc0 * sc); hv[1] = (_Float16)(acc1 * sc);
    hv[2] = (_Float16)(acc2 * sc); hv[3] = (_Float16)(acc3 * sc);
    *reinterpret_cast<half4v*>(xaggh + (size_t)node * CH + lane * 4) = hv;
}

// =============== MFMA epilogue (R10, proven) ===============
__global__ __launch_bounds__(256) void k_final3(const __half* __restrict__ xaggh,
                                                const __half* __restrict__ WzT,
                                                const __half* __restrict__ WhT,
                                                const __half* __restrict__ WlT,
                                                const float* __restrict__ bz,
                                                const float* __restrict__ bh,
                                                const float* __restrict__ blin,
                                                float* __restrict__ out, int n) {
    __shared__ __half gL[4][16][136];
    const int tid = threadIdx.x;
    const int w = tid >> 6;
    const int l = tid & 63;
    const int lr = l & 15;
    const int lk = l >> 4;
    const int nodeb = blockIdx.x * 64 + w * 16;

    int arow = nodeb + lr;
    if (arow > n - 1) arow = n - 1;

    floatx4 accz[8], acch[8];
#pragma unroll
    for (int ct = 0; ct < 8; ++ct) {
        accz[ct] = (floatx4){0.f, 0.f, 0.f, 0.f};
        acch[ct] = (floatx4){0.f, 0.f, 0.f, 0.f};
    }

#pragma unroll
    for (int kc = 0; kc < 4; ++kc) {
        half8 a = *reinterpret_cast<const half8*>(xaggh + (size_t)arow * CH + kc * 32 + lk * 8);
#pragma unroll
        for (int ct = 0; ct < 8; ++ct) {
            half8 bzf = *reinterpret_cast<const half8*>(WzT + (ct * 16 + lr) * CH + kc * 32 + lk * 8);
            accz[ct] = __builtin_amdgcn_mfma_f32_16x16x32_f16(a, bzf, accz[ct], 0, 0, 0);
            half8 bhf = *reinterpret_cast<const half8*>(WhT + (ct * 16 + lr) * CH + kc * 32 + lk * 8);
            acch[ct] = __builtin_amdgcn_mfma_f32_16x16x32_f16(a, bhf, acch[ct], 0, 0, 0);
        }
    }

#pragma unroll
    for (int ct = 0; ct < 8; ++ct) {
        float bzv = bz[ct * 16 + lr];
        float bhv = bh[ct * 16 + lr];
#pragma unroll
        for (int r = 0; r < 4; ++r) {
            float zp = accz[ct][r] + bzv;
            float hp = acch[ct][r] + bhv;
            float g = (1.f - 1.f / (1.f + __expf(-zp))) * tanhf(hp);
            gL[w][lk * 4 + r][ct * 16 + lr] = __float2half(g);
        }
    }
    __syncthreads();

    floatx4 acco = (floatx4){0.f, 0.f, 0.f, 0.f};
#pragma unroll
    for (int kc = 0; kc < 4; ++kc) {
        half8 a = *reinterpret_cast<const half8*>(&gL[w][lr][kc * 32 + lk * 8]);
        half8 b = *reinterpret_cast<const half8*>(WlT + lr * CH + kc * 32 + lk * 8);
        acco = __builtin_amdgcn_mfma_f32_16x16x32_f16(a, b, acco, 0, 0, 0);
    }
    float bl = blin[lr];
#pragma unroll
    for (int r = 0; r < 4; ++r) {
        int node = nodeb + lk * 4 + r;
        if (node < n) out[(size_t)node * HEADS + lr] = acco[r] + bl;
    }
}

// =============== Tier B (CSR fallback, proven) ===============
__global__ __launch_bounds__(256) void k1B(const int* __restrict__ src,
                                           const int* __restrict__ dst,
                                           const float* __restrict__ w,
                                           float* __restrict__ deg_out,
                                           unsigned* __restrict__ cnt, int E) {
    int e = blockIdx.x * blockDim.x + threadIdx.x;
    if (e >= E) return;
    unsafeAtomicAdd(deg_out + src[e], w[e]);
    atomicAdd(cnt + dst[e], 1u);
}

__global__ __launch_bounds__(1024) void k_scan(unsigned* __restrict__ off, int n) {
    __shared__ unsigned s[1024];
    const int t = threadIdx.x;
    const int per = (n + 1023) / 1024;
    int lo = t * per;
    int hi = lo + per; if (hi > n) hi = n;
    unsigned sum = 0;
    for (int i = lo; i < hi; ++i) sum += off[i];
    s[t] = sum;
    __syncthreads();
    for (int ofs = 1; ofs < 1024; ofs <<= 1) {
        unsigned v = (t >= ofs) ? s[t - ofs] : 0u;
        __syncthreads();
        s[t] += v;
        __syncthreads();
    }
    unsigned run = s[t] - sum;
    for (int i = lo; i < hi; ++i) {
        unsigned c = off[i];
        off[i] = run;
        run += c;
    }
}

__global__ __launch_bounds__(256) void k_fillB(const int* __restrict__ src,
                                               const int* __restrict__ dst,
                                               const float* __restrict__ w,
                                               unsigned* __restrict__ off,
                                               int2* __restrict__ rec, int E) {
    int e = blockIdx.x * blockDim.x + threadIdx.x;
    if (e >= E) return;
    unsigned pos = atomicAdd(off + dst[e], 1u);
    rec[pos] = make_int2(__float_as_int(w[e]), src[e]);
}

__global__ __launch_bounds__(256) void k_gatherB(const unsigned* __restrict__ off,
                                                 const int2* __restrict__ rec,
                                                 const float* __restrict__ deg_out,
                                                 const float* __restrict__ x,
                                                 float* __restrict__ xagg, int n) {
    int node = blockIdx.x * 4 + (threadIdx.x >> 6);
    if (node >= n) return;
    int lane = threadIdx.x & 63;
    unsigned i = node ? off[node - 1] : 0u;
    unsigned end = off[node];
    float2 acc = make_float2(0.f, 0.f);
    float wsum = 0.f;
    for (; i < end; ++i) {
        int2 r0 = rec[i];
        float w0 = __int_as_float(r0.x);
        float d0 = deg_out[r0.y];
        float c0 = w0 * (d0 > 0.f ? rsqrtf(d0) : 0.f);
        float2 v = *reinterpret_cast<const float2*>(x + (size_t)r0.y * CH + lane * 2);
        wsum += w0;
        acc.x = fmaf(c0, v.x, acc.x);
        acc.y = fmaf(c0, v.y, acc.y);
    }
    float sc = wsum > 0.f ? rsqrtf(wsum) : 0.f;
    *reinterpret_cast<float2*>(xagg + (size_t)node * CH + lane * 2) =
        make_float2(acc.x * sc, acc.y * sc);
}

__global__ __launch_bounds__(256) void k_final2(const float* __restrict__ xagg,
                                                const float* __restrict__ Wxz,
                                                const float* __restrict__ bz,
                                                const float* __restrict__ Wxh,
                                                const float* __restrict__ bh,
                                                const float* __restrict__ Wlin,
                                                const float* __restrict__ blin,
                                                float* __restrict__ out, int n) {
    __shared__ float smem[10560];
    float* sA = smem;
    float* sWz = smem + 2304;
    float* sWh = smem + 6400;

    const int tid = threadIdx.x;
    const int tx = tid & 31;
    const int ty = tid >> 5;
    const int base = blockIdx.x * TM;

    float az[8][4] = {{0.f}};
    float ah[8][4] = {{0.f}};

    for (int kc = 0; kc < CH; kc += KC) {
        {
            int i = tid;
#pragma unroll
            for (int r2 = 0; r2 < 2; ++r2, i += 256) {
                int row = i >> 3;
                int c4 = (i & 7) * 4;
                int grow = base + row; if (grow > n - 1) grow = n - 1;
                float4 v = *reinterpret_cast<const float4*>(xagg + (size_t)grow * CH + kc + c4);
                *reinterpret_cast<float4*>(&sA[row * 36 + c4]) = v;
            }
            int j = tid;
#pragma unroll
            for (int r2 = 0; r2 < 4; ++r2, j += 256) {
                int row = j >> 5;
                int c4 = (j & 31) * 4;
                *reinterpret_cast<float4*>(&sWz[row * 128 + c4]) =
                    *reinterpret_cast<const float4*>(Wxz + (size_t)(kc + row) * CH + c4);
                *reinterpret_cast<float4*>(&sWh[row * 128 + c4]) =
                    *reinterpret_cast<const float4*>(Wxh + (size_t)(kc + row) * CH + c4);
            }
        }
        __syncthreads();
#pragma unroll 4
        for (int kk = 0; kk < KC; ++kk) {
            float4 wz = *reinterpret_cast<float4*>(&sWz[kk * 128 + tx * 4]);
            float4 wh = *reinterpret_cast<float4*>(&sWh[kk * 128 + tx * 4]);
#pragma unroll
            for (int r = 0; r < 8; ++r) {
                float a = sA[(ty * 8 + r) * 36 + kk];
                az[r][0] = fmaf(a, wz.x, az[r][0]);
                az[r][1] = fmaf(a, wz.y, az[r][1]);
                az[r][2] = fmaf(a, wz.z, az[r][2]);
                az[r][3] = fmaf(a, wz.w, az[r][3]);
                ah[r][0] = fmaf(a, wh.x, ah[r][0]);
                ah[r][1] = fmaf(a, wh.y, ah[r][1]);
                ah[r][2] = fmaf(a, wh.z, ah[r][2]);
                ah[r][3] = fmaf(a, wh.w, ah[r][3]);
            }
        }
        __syncthreads();
    }

    float* sG = smem;
    const float4 bz4 = *reinterpret_cast<const float4*>(bz + tx * 4);
    const float4 bh4 = *reinterpret_cast<const float4*>(bh + tx * 4);
#pragma unroll
    for (int r = 0; r < 8; ++r) {
        int row = ty * 8 + r;
        float4 g4;
        float zp = az[r][0] + bz4.x, hp = ah[r][0] + bh4.x;
        g4.x = (1.f - 1.f / (1.f + __expf(-zp))) * tanhf(hp);
        zp = az[r][1] + bz4.y; hp = ah[r][1] + bh4.y;
        g4.y = (1.f - 1.f / (1.f + __expf(-zp))) * tanhf(hp);
        zp = az[r][2] + bz4.z; hp = ah[r][2] + bh4.z;
        g4.z = (1.f - 1.f / (1.f + __expf(-zp))) * tanhf(hp);
        zp = az[r][3] + bz4.w; hp = ah[r][3] + bh4.w;
        g4.w = (1.f - 1.f / (1.f + __expf(-zp))) * tanhf(hp);
        *reinterpret_cast<float4*>(&sG[row * 132 + tx * 4]) = g4;
    }
    __syncthreads();

#pragma unroll
    for (int it = 0; it < 4; ++it) {
        int idx = it * 256 + tid;
        int node = idx >> 4;
        int hh = idx & 15;
        float acc = blin[hh];
#pragma unroll 8
        for (int j = 0; j < CH; ++j)
            acc = fmaf(sG[node * 132 + j], Wlin[j * HEADS + hh], acc);
        if (base + node < n) out[(size_t)(base + node) * HEADS + hh] = acc;
    }
}

static inline size_t align256(size_t v) { return (v + 255) & ~(size_t)255; }

extern "C" void kernel_launch(void* const* d_in, const int* in_sizes, int n_in,
                              void* d_out, int out_size, void* d_ws, size_t ws_size,
                              hipStream_t stream) {
    const float* x = (const float*)d_in[0];
    const int* ei = (const int*)d_in[1];     // int32 on device (harness narrows int64)
    const float* w = (const float*)d_in[2];
    const float* Wxz = (const float*)d_in[3];
    const float* bz = (const float*)d_in[5];
    const float* Wxh = (const float*)d_in[9];
    const float* bh = (const float*)d_in[11];
    const float* Wlin = (const float*)d_in[12];
    const float* blin = (const float*)d_in[13];
    float* out = (float*)d_out;

    const int Nn = in_sizes[0] / CH;  // 50000
    const int E = in_sizes[2];        // 1,600,000

    const int* src = ei;
    const int* dst = ei + E;
    int eb = (E + 255) / 256;
    char* base = (char*)d_ws;

    // Tier A layout (aligned):
    size_t off_counts = 0;                                         // NR*NB u32
    size_t off_total = align256(off_counts + (size_t)NR * NB * 4); // NR u32
    size_t off_rbase = align256(off_total + NR * 4);               // NR u32
    size_t off_noff = align256(off_rbase + NR * 4);                // (N+1) u32
    size_t off_xh = align256(off_noff + ((size_t)Nn + 1) * 4);     // N*CH half
    size_t off_xaggh = align256(off_xh + (size_t)Nn * CH * 2);     // N*CH half
    size_t off_wz = align256(off_xaggh + (size_t)Nn * CH * 2);     // CH*CH half
    size_t off_wh = align256(off_wz + (size_t)CH * CH * 2);        // CH*CH half
    size_t off_wl = align256(off_wh + (size_t)CH * CH * 2);        // HEADS*CH half
    size_t off_rec2 = align256(off_wl + (size_t)HEADS * CH * 2);   // E int2
    size_t off_rec3 = align256(off_rec2 + (size_t)E * 8);          // E u32 (packed)
    size_t needNew = off_rec3 + (size_t)E * 4;
    size_t partial_bytes = (size_t)4 * DSLICES * DRANGE * 4;       // 13.1MB, overlays rec2+rec3

    if (ws_size >= needNew && Nn <= 65536 && (size_t)NR * RN >= (size_t)Nn &&
        partial_bytes <= (size_t)E * 12) {
        unsigned* counts = (unsigned*)(base + off_counts);
        unsigned* total = (unsigned*)(base + off_total);
        unsigned* rbase = (unsigned*)(base + off_rbase);
        unsigned* noff = (unsigned*)(base + off_noff);
        __half* xh = (__half*)(base + off_xh);
        __half* xaggh = (__half*)(base + off_xaggh);
        __half* WzT = (__half*)(base + off_wz);
        __half* WhT = (__half*)(base + off_wh);
        __half* WlT = (__half*)(base + off_wl);
        int2* rec2 = (int2*)(base + off_rec2);
        unsigned* rec3 = (unsigned*)(base + off_rec3);
        float* partial = (float*)(base + off_rec2);  // overlay: dead after k_degxc

        k_deg<<<4 * DSLICES, 256, 0, stream>>>(src, w, partial, E);
        k_degxc<<<(Nn + 255) / 256, 256, 0, stream>>>(partial, x, xh, Nn);
        k_wcast<<<(CH * CH + HEADS * CH + 255) / 256, 256, 0, stream>>>(Wxz, Wxh, Wlin, WzT, WhT, WlT);
        k_count<<<NB, 256, 0, stream>>>(dst, counts, E);
        k_scanR<<<NR, 256, 0, stream>>>(counts, total);
        k_scanT<<<1, NR, 0, stream>>>(total, rbase, noff, Nn, E);
        k_part<<<NB, 256, 0, stream>>>(src, dst, w, counts, rbase, rec2, E);
        k_sortR<<<NR, 256, 0, stream>>>(rbase, total, rec2, rec3, noff, Nn);
        k_gather5<<<(Nn + 7) / 8, 256, 0, stream>>>(noff, rec3, xh, xaggh, Nn);
        k_final3<<<(Nn + 63) / 64, 256, 0, stream>>>(xaggh, WzT, WhT, WlT, bz, bh, blin, out, Nn);
    } else {
        // Tier B: CSR fallback (proven)
        unsigned* off = (unsigned*)base;
        float* deg_out = (float*)(base + (size_t)Nn * 4);
        int2* rec = (int2*)(base + (size_t)2 * Nn * 4);
        float* xagg = (float*)((char*)rec + (size_t)E * 8);

        hipMemsetAsync(d_ws, 0, (size_t)2 * Nn * 4, stream);
        k1B<<<eb, 256, 0, stream>>>(src, dst, w, deg_out, off, E);
        k_scan<<<1, 1024, 0, stream>>>(off, Nn);
        k_fillB<<<eb, 256, 0, stream>>>(src, dst, w, off, rec, E);
        k_gatherB<<<(Nn + 3) / 4, 256, 0, stream>>>(off, rec, deg_out, x, xagg, Nn);
        k_final2<<<(Nn + TM - 1) / TM, 256, 0, stream>>>(xagg, Wxz, bz, Wxh, bh, Wlin, blin, out, Nn);
    }
}

// Round 13
// 160.202 us; speedup vs baseline: 7.7410x; 1.0700x over previous
//
#include <hip/hip_runtime.h>
#include <hip/hip_bf16.h>
#include <hip/hip_fp16.h>

// GConvGRU with h=0 reduces to:
//   xagg = scatter_add(norm * x[src] -> dst)          [N,128]
//   z    = sigmoid(xagg @ W_xz + b_z)
//   ht   = tanh   (xagg @ W_xh + b_h)
//   out  = ((1-z)*ht) @ W_lin + b_lin                 [N,16]
// Model (R6-R12): scattered global writes cost 32B granules unless clustered;
// gather is at the L2-miss service floor (~3.3TB/s, FETCH 148MB) -> ILP null.
// R13: structural consolidation: sortR+gather fused (LDS-sorted records, no
// rec3 round trip, 1024-thr blocks = full CU), scanT dropped (self-scan),
// wcast folded into degxc. 10 -> 7 launches.

#define CH 128
#define HEADS 16
#define TM 64          // nodes per block in k_final2 (tier B)
#define KC 32          // K-chunk (tier B)
#define DRANGE 12800   // deg histogram: nodes per range (4 ranges)
#define DSLICES 64     // deg histogram: edge slices per range
#define RN 98          // nodes per partition range
#define NR 512         // partition ranges (512*98 >= 50000)
#define NB 256         // partition blocks (edge slices)
#define SCAP 3840      // sort stage capacity (mean 3136; global fallback)

typedef _Float16 half8 __attribute__((ext_vector_type(8)));
typedef _Float16 half4v __attribute__((ext_vector_type(4)));
typedef float floatx4 __attribute__((ext_vector_type(4)));

// =============== deg partials: LDS histogram over src ===============
__global__ __launch_bounds__(256) void k_deg(const int* __restrict__ src,
                                             const float* __restrict__ w,
                                             float* __restrict__ partial, int E) {
    __shared__ float h[DRANGE];
    const int r = blockIdx.x / DSLICES;
    const int sl = blockIdx.x % DSLICES;
    const int base = r * DRANGE;
    for (int i = threadIdx.x; i < DRANGE; i += 256) h[i] = 0.f;
    __syncthreads();
    const int per = (E + DSLICES - 1) / DSLICES;
    const int lo = sl * per;
    const int hi = min(lo + per, E);
    int e = lo + threadIdx.x * 4;
    for (; e + 3 < hi; e += 1024) {
        int4 s4 = *reinterpret_cast<const int4*>(src + e);
        float4 w4 = *reinterpret_cast<const float4*>(w + e);
        int a;
        a = s4.x - base; if ((unsigned)a < DRANGE) atomicAdd(&h[a], w4.x);
        a = s4.y - base; if ((unsigned)a < DRANGE) atomicAdd(&h[a], w4.y);
        a = s4.z - base; if ((unsigned)a < DRANGE) atomicAdd(&h[a], w4.z);
        a = s4.w - base; if ((unsigned)a < DRANGE) atomicAdd(&h[a], w4.w);
    }
    for (; e < hi; ++e) {
        int a = src[e] - base;
        if ((unsigned)a < DRANGE) atomicAdd(&h[a], w[e]);
    }
    __syncthreads();
    float* dstp = partial + ((size_t)r * DSLICES + sl) * DRANGE;
    for (int i = threadIdx.x; i < DRANGE; i += 256) dstp[i] = h[i];
}

// =============== fused: deg reduce + xh cast | weight cast ===============
__global__ __launch_bounds__(256) void k_degxcw(const float* __restrict__ partial,
                                                const float* __restrict__ x,
                                                __half* __restrict__ xh,
                                                const float* __restrict__ Wxz,
                                                const float* __restrict__ Wxh,
                                                const float* __restrict__ Wlin,
                                                __half* __restrict__ WzT,
                                                __half* __restrict__ WhT,
                                                __half* __restrict__ WlT,
                                                int n, int nbdeg) {
    const int t = threadIdx.x;
    if ((int)blockIdx.x >= nbdeg) {
        // weight cast
        int i = (blockIdx.x - nbdeg) * 256 + t;
        if (i < CH * CH) {
            int nn = i >> 7, k = i & 127;
            WzT[i] = __float2half(Wxz[k * CH + nn]);
            WhT[i] = __float2half(Wxh[k * CH + nn]);
        } else if (i < CH * CH + HEADS * CH) {
            int j = i - CH * CH;
            int nn = j >> 7, k = j & 127;
            WlT[j] = __float2half(Wlin[k * HEADS + nn]);
        }
        return;
    }
    __shared__ float degl[256];
    const int bb = blockIdx.x * 256;
    int i = bb + t;
    if (i < n) {
        int r = i / DRANGE;
        int idx = i - r * DRANGE;
        const float* p = partial + (size_t)r * DSLICES * DRANGE + idx;
        float s = 0.f;
#pragma unroll 8
        for (int sl = 0; sl < DSLICES; ++sl) s += p[(size_t)sl * DRANGE];
        degl[t] = s;
    }
    __syncthreads();
#pragma unroll
    for (int g = 0; g < 16; ++g) {
        int ln = g * 16 + (t >> 4);
        int node = bb + ln;
        if (node >= n) break;
        int c8 = (t & 15) * 8;
        float dg = degl[ln];
        float sc = dg > 0.f ? rsqrtf(dg) : 0.f;
        float4 a = *reinterpret_cast<const float4*>(x + (size_t)node * CH + c8);
        float4 b = *reinterpret_cast<const float4*>(x + (size_t)node * CH + c8 + 4);
        __half2 h0 = __floats2half2_rn(a.x * sc, a.y * sc);
        __half2 h1 = __floats2half2_rn(a.z * sc, a.w * sc);
        __half2 h2 = __floats2half2_rn(b.x * sc, b.y * sc);
        __half2 h3 = __floats2half2_rn(b.z * sc, b.w * sc);
        uint4 packed = make_uint4(*(unsigned*)&h0, *(unsigned*)&h1, *(unsigned*)&h2, *(unsigned*)&h3);
        *reinterpret_cast<uint4*>(xh + (size_t)node * CH + c8) = packed;
    }
}

// =============== partition pass 1: per-block dst-range histogram ===============
__global__ __launch_bounds__(256) void k_count(const int* __restrict__ dst,
                                               unsigned* __restrict__ counts, int E) {
    __shared__ unsigned h[NR];
    const int b = blockIdx.x;
    for (int i = threadIdx.x; i < NR; i += 256) h[i] = 0u;
    __syncthreads();
    const int per = (E + NB - 1) / NB;
    const int lo = b * per;
    const int hi = min(lo + per, E);
    for (int e = lo + threadIdx.x; e < hi; e += 256)
        atomicAdd(&h[dst[e] / RN], 1u);
    __syncthreads();
    for (int i = threadIdx.x; i < NR; i += 256) counts[(size_t)i * NB + b] = h[i];
}

// per-range exclusive scan over blocks
__global__ __launch_bounds__(256) void k_scanR(unsigned* __restrict__ counts,
                                               unsigned* __restrict__ total) {
    __shared__ unsigned s[256];
    const int r = blockIdx.x;
    const int t = threadIdx.x;
    unsigned v = counts[(size_t)r * NB + t];
    s[t] = v;
    __syncthreads();
    for (int ofs = 1; ofs < 256; ofs <<= 1) {
        unsigned u = (t >= ofs) ? s[t - ofs] : 0u;
        __syncthreads();
        s[t] += u;
        __syncthreads();
    }
    counts[(size_t)r * NB + t] = s[t] - v;
    if (t == 255) total[r] = s[255];
}

// =============== partition pass 2 (self-scans totals -> rbase) ===============
// rec2[pos] = { w(f32), dl<<16 | src }  (requires n <= 65536)
__global__ __launch_bounds__(256) void k_part(const int* __restrict__ src,
                                              const int* __restrict__ dst,
                                              const float* __restrict__ w,
                                              const unsigned* __restrict__ counts,
                                              const unsigned* __restrict__ total,
                                              int2* __restrict__ rec2, int E) {
    __shared__ unsigned cursor[NR];
    __shared__ unsigned sa[NR], sb[NR];
    const int b = blockIdx.x;
    const int t = threadIdx.x;
    // self-scan 512 totals (inclusive) with 256 threads, ping-pong
    sa[t] = total[t]; sa[t + 256] = total[t + 256];
    __syncthreads();
    unsigned* cur = sa; unsigned* nxt = sb;
    for (int ofs = 1; ofs < NR; ofs <<= 1) {
        for (int k = t; k < NR; k += 256) {
            unsigned v = cur[k];
            if (k >= ofs) v += cur[k - ofs];
            nxt[k] = v;
        }
        __syncthreads();
        unsigned* tmp = cur; cur = nxt; nxt = tmp;
    }
    for (int r = t; r < NR; r += 256) {
        unsigned rb = cur[r] - total[r];   // exclusive base
        cursor[r] = rb + counts[(size_t)r * NB + b];
    }
    __syncthreads();
    const int per = (E + NB - 1) / NB;
    const int lo = b * per;
    const int hi = min(lo + per, E);
    for (int e = lo + t; e < hi; e += 256) {
        int d = dst[e];
        int r = d / RN;
        int dl = d - r * RN;
        unsigned pos = atomicAdd(&cursor[r], 1u);
        rec2[pos] = make_int2(__float_as_int(w[e]), (dl << 16) | src[e]);
    }
}

// =============== fused sort + gather: 512 blocks x 1024 threads ===============
// Sort range's records into LDS (packed u32 = fp16w<<16|src), then gather
// from LDS records with unroll-8 row loads. Global rec3 fallback if tot>SCAP.
__global__ __launch_bounds__(1024) void k_sortgather(const unsigned* __restrict__ total,
                                                     const int2* __restrict__ rec2,
                                                     unsigned* __restrict__ rec3,
                                                     const __half* __restrict__ xh,
                                                     __half* __restrict__ xaggh, int n) {
    __shared__ int2 stage[SCAP];         // 30720 B
    __shared__ unsigned sortedP[SCAP];   // 15360 B
    __shared__ unsigned hist[RN], curx[RN];
    __shared__ unsigned sa[NR], sb[NR];  // 4096 B
    const int r = blockIdx.x;
    const int bn = r * RN;
    if (bn >= n) return;
    const int rn = min(RN, n - bn);
    const int t = threadIdx.x;

    // self-scan totals -> gbase
    if (t < NR) sa[t] = total[t];
    __syncthreads();
    unsigned* cur = sa; unsigned* nxt = sb;
    for (int ofs = 1; ofs < NR; ofs <<= 1) {
        if (t < NR) {
            unsigned v = cur[t];
            if (t >= ofs) v += cur[t - ofs];
            nxt[t] = v;
        }
        __syncthreads();
        unsigned* tmp = cur; cur = nxt; nxt = tmp;
    }
    const unsigned tot = total[r];
    const unsigned gbase = cur[r] - tot;

    // histogram + stage
    if (t < RN) hist[t] = 0u;
    __syncthreads();
    for (unsigned i = t; i < tot; i += 1024) {
        int2 v = rec2[gbase + i];
        if (i < SCAP) stage[i] = v;
        atomicAdd(&hist[v.y >> 16], 1u);
    }
    __syncthreads();
    if (t == 0) {
        unsigned run = 0;
        for (int j = 0; j < rn; ++j) {
            unsigned c = hist[j];
            hist[j] = run;     // start (preserved)
            curx[j] = run;     // cursor -> becomes end
            run += c;
        }
    }
    __syncthreads();
    const bool big = (tot > SCAP);
    for (unsigned i = t; i < tot; i += 1024) {
        int2 v = (i < SCAP) ? stage[i] : rec2[gbase + i];
        int dl = v.y >> 16;
        __half hw = __float2half(__int_as_float(v.x));
        unsigned packed = ((unsigned)__half_as_ushort(hw) << 16) | (unsigned)(v.y & 0xFFFF);
        unsigned pos = atomicAdd(&curx[dl], 1u);
        if (big) rec3[gbase + pos] = packed;
        else sortedP[pos] = packed;
    }
    __syncthreads();

    // gather: 32 half-waves; lane owns 4 channels
    const int hwid = t >> 5;
    const int lane = t & 31;
    const __half* xb = xh + lane * 4;
    const unsigned* grec = rec3 + gbase;
    for (int nd = hwid; nd < rn; nd += 32) {
        unsigned i = hist[nd];
        unsigned end = curx[nd];
        float acc0 = 0.f, acc1 = 0.f, acc2 = 0.f, acc3 = 0.f;
        float wsum = 0.f;
        for (; i + 8 <= end; i += 8) {
            unsigned r0, r1, r2, r3, r4, r5, r6, r7;
            if (big) {
                r0 = grec[i];     r1 = grec[i + 1]; r2 = grec[i + 2]; r3 = grec[i + 3];
                r4 = grec[i + 4]; r5 = grec[i + 5]; r6 = grec[i + 6]; r7 = grec[i + 7];
            } else {
                r0 = sortedP[i];     r1 = sortedP[i + 1]; r2 = sortedP[i + 2]; r3 = sortedP[i + 3];
                r4 = sortedP[i + 4]; r5 = sortedP[i + 5]; r6 = sortedP[i + 6]; r7 = sortedP[i + 7];
            }
            half4v v0 = *reinterpret_cast<const half4v*>(xb + (size_t)(r0 & 0xFFFFu) * CH);
            half4v v1 = *reinterpret_cast<const half4v*>(xb + (size_t)(r1 & 0xFFFFu) * CH);
            half4v v2 = *reinterpret_cast<const half4v*>(xb + (size_t)(r2 & 0xFFFFu) * CH);
            half4v v3 = *reinterpret_cast<const half4v*>(xb + (size_t)(r3 & 0xFFFFu) * CH);
            half4v v4 = *reinterpret_cast<const half4v*>(xb + (size_t)(r4 & 0xFFFFu) * CH);
            half4v v5 = *reinterpret_cast<const half4v*>(xb + (size_t)(r5 & 0xFFFFu) * CH);
            half4v v6 = *reinterpret_cast<const half4v*>(xb + (size_t)(r6 & 0xFFFFu) * CH);
            half4v v7 = *reinterpret_cast<const half4v*>(xb + (size_t)(r7 & 0xFFFFu) * CH);
            float w0 = __half2float(__ushort_as_half((unsigned short)(r0 >> 16)));
            float w1 = __half2float(__ushort_as_half((unsigned short)(r1 >> 16)));
            float w2 = __half2float(__ushort_as_half((unsigned short)(r2 >> 16)));
            float w3 = __half2float(__ushort_as_half((unsigned short)(r3 >> 16)));
            float w4 = __half2float(__ushort_as_half((unsigned short)(r4 >> 16)));
            float w5 = __half2float(__ushort_as_half((unsigned short)(r5 >> 16)));
            float w6 = __half2float(__ushort_as_half((unsigned short)(r6 >> 16)));
            float w7 = __half2float(__ushort_as_half((unsigned short)(r7 >> 16)));
            wsum += ((w0 + w1) + (w2 + w3)) + ((w4 + w5) + (w6 + w7));
            acc0 = fmaf(w0, (float)v0[0], acc0); acc1 = fmaf(w0, (float)v0[1], acc1);
            acc2 = fmaf(w0, (float)v0[2], acc2); acc3 = fmaf(w0, (float)v0[3], acc3);
            acc0 = fmaf(w1, (float)v1[0], acc0); acc1 = fmaf(w1, (float)v1[1], acc1);
            acc2 = fmaf(w1, (float)v1[2], acc2); acc3 = fmaf(w1, (float)v1[3], acc3);
            acc0 = fmaf(w2, (float)v2[0], acc0); acc1 = fmaf(w2, (float)v2[1], acc1);
            acc2 = fmaf(w2, (float)v2[2], acc2); acc3 = fmaf(w2, (float)v2[3], acc3);
            acc0 = fmaf(w3, (float)v3[0], acc0); acc1 = fmaf(w3, (float)v3[1], acc1);
            acc2 = fmaf(w3, (float)v3[2], acc2); acc3 = fmaf(w3, (float)v3[3], acc3);
            acc0 = fmaf(w4, (float)v4[0], acc0); acc1 = fmaf(w4, (float)v4[1], acc1);
            acc2 = fmaf(w4, (float)v4[2], acc2); acc3 = fmaf(w4, (float)v4[3], acc3);
            acc0 = fmaf(w5, (float)v5[0], acc0); acc1 = fmaf(w5, (float)v5[1], acc1);
            acc2 = fmaf(w5, (float)v5[2], acc2); acc3 = fmaf(w5, (float)v5[3], acc3);
            acc0 = fmaf(w6, (float)v6[0], acc0); acc1 = fmaf(w6, (float)v6[1], acc1);
            acc2 = fmaf(w6, (float)v6[2], acc2); acc3 = fmaf(w6, (float)v6[3], acc3);
            acc0 = fmaf(w7, (float)v7[0], acc0); acc1 = fmaf(w7, (float)v7[1], acc1);
            acc2 = fmaf(w7, (float)v7[2], acc2); acc3 = fmaf(w7, (float)v7[3], acc3);
        }
        for (; i < end; ++i) {
            unsigned r0 = big ? grec[i] : sortedP[i];
            float w0 = __half2float(__ushort_as_half((unsigned short)(r0 >> 16)));
            half4v v0 = *reinterpret_cast<const half4v*>(xb + (size_t)(r0 & 0xFFFFu) * CH);
            wsum += w0;
            acc0 = fmaf(w0, (float)v0[0], acc0); acc1 = fmaf(w0, (float)v0[1], acc1);
            acc2 = fmaf(w0, (float)v0[2], acc2); acc3 = fmaf(w0, (float)v0[3], acc3);
        }
        float sc = wsum > 0.f ? rsqrtf(wsum) : 0.f;
        half4v hv;
        hv[0] = (_Float16)(acc0 * sc); hv[1] = (_Float16)(acc1 * sc);
        hv[2] = (_Float16)(acc2 * sc); hv[3] = (_Float16)(acc3 * sc);
        *reinterpret_cast<half4v*>(xaggh + (size_t)(bn + nd) * CH + lane * 4) = hv;
    }
}

// =============== MFMA epilogue (R10, proven) ===============
__global__ __launch_bounds__(256) void k_final3(const __half* __restrict__ xaggh,
                                                const __half* __restrict__ WzT,
                                                const __half* __restrict__ WhT,
                                                const __half* __restrict__ WlT,
                                                const float* __restrict__ bz,
                                                const float* __restrict__ bh,
                                                const float* __restrict__ blin,
                                                float* __restrict__ out, int n) {
    __shared__ __half gL[4][16][136];
    const int tid = threadIdx.x;
    const int w = tid >> 6;
    const int l = tid & 63;
    const int lr = l & 15;
    const int lk = l >> 4;
    const int nodeb = blockIdx.x * 64 + w * 16;

    int arow = nodeb + lr;
    if (arow > n - 1) arow = n - 1;

    floatx4 accz[8], acch[8];
#pragma unroll
    for (int ct = 0; ct < 8; ++ct) {
        accz[ct] = (floatx4){0.f, 0.f, 0.f, 0.f};
        acch[ct] = (floatx4){0.f, 0.f, 0.f, 0.f};
    }

#pragma unroll
    for (int kc = 0; kc < 4; ++kc) {
        half8 a = *reinterpret_cast<const half8*>(xaggh + (size_t)arow * CH + kc * 32 + lk * 8);
#pragma unroll
        for (int ct = 0; ct < 8; ++ct) {
            half8 bzf = *reinterpret_cast<const half8*>(WzT + (ct * 16 + lr) * CH + kc * 32 + lk * 8);
            accz[ct] = __builtin_amdgcn_mfma_f32_16x16x32_f16(a, bzf, accz[ct], 0, 0, 0);
            half8 bhf = *reinterpret_cast<const half8*>(WhT + (ct * 16 + lr) * CH + kc * 32 + lk * 8);
            acch[ct] = __builtin_amdgcn_mfma_f32_16x16x32_f16(a, bhf, acch[ct], 0, 0, 0);
        }
    }

#pragma unroll
    for (int ct = 0; ct < 8; ++ct) {
        float bzv = bz[ct * 16 + lr];
        float bhv = bh[ct * 16 + lr];
#pragma unroll
        for (int r = 0; r < 4; ++r) {
            float zp = accz[ct][r] + bzv;
            float hp = acch[ct][r] + bhv;
            float g = (1.f - 1.f / (1.f + __expf(-zp))) * tanhf(hp);
            gL[w][lk * 4 + r][ct * 16 + lr] = __float2half(g);
        }
    }
    __syncthreads();

    floatx4 acco = (floatx4){0.f, 0.f, 0.f, 0.f};
#pragma unroll
    for (int kc = 0; kc < 4; ++kc) {
        half8 a = *reinterpret_cast<const half8*>(&gL[w][lr][kc * 32 + lk * 8]);
        half8 b = *reinterpret_cast<const half8*>(WlT + lr * CH + kc * 32 + lk * 8);
        acco = __builtin_amdgcn_mfma_f32_16x16x32_f16(a, b, acco, 0, 0, 0);
    }
    float bl = blin[lr];
#pragma unroll
    for (int r = 0; r < 4; ++r) {
        int node = nodeb + lk * 4 + r;
        if (node < n) out[(size_t)node * HEADS + lr] = acco[r] + bl;
    }
}

// =============== Tier B (CSR fallback, proven) ===============
__global__ __launch_bounds__(256) void k1B(const int* __restrict__ src,
                                           const int* __restrict__ dst,
                                           const float* __restrict__ w,
                                           float* __restrict__ deg_out,
                                           unsigned* __restrict__ cnt, int E) {
    int e = blockIdx.x * blockDim.x + threadIdx.x;
    if (e >= E) return;
    unsafeAtomicAdd(deg_out + src[e], w[e]);
    atomicAdd(cnt + dst[e], 1u);
}

__global__ __launch_bounds__(1024) void k_scan(unsigned* __restrict__ off, int n) {
    __shared__ unsigned s[1024];
    const int t = threadIdx.x;
    const int per = (n + 1023) / 1024;
    int lo = t * per;
    int hi = lo + per; if (hi > n) hi = n;
    unsigned sum = 0;
    for (int i = lo; i < hi; ++i) sum += off[i];
    s[t] = sum;
    __syncthreads();
    for (int ofs = 1; ofs < 1024; ofs <<= 1) {
        unsigned v = (t >= ofs) ? s[t - ofs] : 0u;
        __syncthreads();
        s[t] += v;
        __syncthreads();
    }
    unsigned run = s[t] - sum;
    for (int i = lo; i < hi; ++i) {
        unsigned c = off[i];
        off[i] = run;
        run += c;
    }
}

__global__ __launch_bounds__(256) void k_fillB(const int* __restrict__ src,
                                               const int* __restrict__ dst,
                                               const float* __restrict__ w,
                                               unsigned* __restrict__ off,
                                               int2* __restrict__ rec, int E) {
    int e = blockIdx.x * blockDim.x + threadIdx.x;
    if (e >= E) return;
    unsigned pos = atomicAdd(off + dst[e], 1u);
    rec[pos] = make_int2(__float_as_int(w[e]), src[e]);
}

__global__ __launch_bounds__(256) void k_gatherB(const unsigned* __restrict__ off,
                                                 const int2* __restrict__ rec,
                                                 const float* __restrict__ deg_out,
                                                 const float* __restrict__ x,
                                                 float* __restrict__ xagg, int n) {
    int node = blockIdx.x * 4 + (threadIdx.x >> 6);
    if (node >= n) return;
    int lane = threadIdx.x & 63;
    unsigned i = node ? off[node - 1] : 0u;
    unsigned end = off[node];
    float2 acc = make_float2(0.f, 0.f);
    float wsum = 0.f;
    for (; i < end; ++i) {
        int2 r0 = rec[i];
        float w0 = __int_as_float(r0.x);
        float d0 = deg_out[r0.y];
        float c0 = w0 * (d0 > 0.f ? rsqrtf(d0) : 0.f);
        float2 v = *reinterpret_cast<const float2*>(x + (size_t)r0.y * CH + lane * 2);
        wsum += w0;
        acc.x = fmaf(c0, v.x, acc.x);
        acc.y = fmaf(c0, v.y, acc.y);
    }
    float sc = wsum > 0.f ? rsqrtf(wsum) : 0.f;
    *reinterpret_cast<float2*>(xagg + (size_t)node * CH + lane * 2) =
        make_float2(acc.x * sc, acc.y * sc);
}

__global__ __launch_bounds__(256) void k_final2(const float* __restrict__ xagg,
                                                const float* __restrict__ Wxz,
                                                const float* __restrict__ bz,
                                                const float* __restrict__ Wxh,
                                                const float* __restrict__ bh,
                                                const float* __restrict__ Wlin,
                                                const float* __restrict__ blin,
                                                float* __restrict__ out, int n) {
    __shared__ float smem[10560];
    float* sA = smem;
    float* sWz = smem + 2304;
    float* sWh = smem + 6400;

    const int tid = threadIdx.x;
    const int tx = tid & 31;
    const int ty = tid >> 5;
    const int base = blockIdx.x * TM;

    float az[8][4] = {{0.f}};
    float ah[8][4] = {{0.f}};

    for (int kc = 0; kc < CH; kc += KC) {
        {
            int i = tid;
#pragma unroll
            for (int r2 = 0; r2 < 2; ++r2, i += 256) {
                int row = i >> 3;
                int c4 = (i & 7) * 4;
                int grow = base + row; if (grow > n - 1) grow = n - 1;
                float4 v = *reinterpret_cast<const float4*>(xagg + (size_t)grow * CH + kc + c4);
                *reinterpret_cast<float4*>(&sA[row * 36 + c4]) = v;
            }
            int j = tid;
#pragma unroll
            for (int r2 = 0; r2 < 4; ++r2, j += 256) {
                int row = j >> 5;
                int c4 = (j & 31) * 4;
                *reinterpret_cast<float4*>(&sWz[row * 128 + c4]) =
                    *reinterpret_cast<const float4*>(Wxz + (size_t)(kc + row) * CH + c4);
                *reinterpret_cast<float4*>(&sWh[row * 128 + c4]) =
                    *reinterpret_cast<const float4*>(Wxh + (size_t)(kc + row) * CH + c4);
            }
        }
        __syncthreads();
#pragma unroll 4
        for (int kk = 0; kk < KC; ++kk) {
            float4 wz = *reinterpret_cast<float4*>(&sWz[kk * 128 + tx * 4]);
            float4 wh = *reinterpret_cast<float4*>(&sWh[kk * 128 + tx * 4]);
#pragma unroll
            for (int r = 0; r < 8; ++r) {
                float a = sA[(ty * 8 + r) * 36 + kk];
                az[r][0] = fmaf(a, wz.x, az[r][0]);
                az[r][1] = fmaf(a, wz.y, az[r][1]);
                az[r][2] = fmaf(a, wz.z, az[r][2]);
                az[r][3] = fmaf(a, wz.w, az[r][3]);
                ah[r][0] = fmaf(a, wh.x, ah[r][0]);
                ah[r][1] = fmaf(a, wh.y, ah[r][1]);
                ah[r][2] = fmaf(a, wh.z, ah[r][2]);
                ah[r][3] = fmaf(a, wh.w, ah[r][3]);
            }
        }
        __syncthreads();
    }

    float* sG = smem;
    const float4 bz4 = *reinterpret_cast<const float4*>(bz + tx * 4);
    const float4 bh4 = *reinterpret_cast<const float4*>(bh + tx * 4);
#pragma unroll
    for (int r = 0; r < 8; ++r) {
        int row = ty * 8 + r;
        float4 g4;
        float zp = az[r][0] + bz4.x, hp = ah[r][0] + bh4.x;
        g4.x = (1.f - 1.f / (1.f + __expf(-zp))) * tanhf(hp);
        zp = az[r][1] + bz4.y; hp = ah[r][1] + bh4.y;
        g4.y = (1.f - 1.f / (1.f + __expf(-zp))) * tanhf(hp);
        zp = az[r][2] + bz4.z; hp = ah[r][2] + bh4.z;
        g4.z = (1.f - 1.f / (1.f + __expf(-zp))) * tanhf(hp);
        zp = az[r][3] + bz4.w; hp = ah[r][3] + bh4.w;
        g4.w = (1.f - 1.f / (1.f + __expf(-zp))) * tanhf(hp);
        *reinterpret_cast<float4*>(&sG[row * 132 + tx * 4]) = g4;
    }
    __syncthreads();

#pragma unroll
    for (int it = 0; it < 4; ++it) {
        int idx = it * 256 + tid;
        int node = idx >> 4;
        int hh = idx & 15;
        float acc = blin[hh];
#pragma unroll 8
        for (int j = 0; j < CH; ++j)
            acc = fmaf(sG[node * 132 + j], Wlin[j * HEADS + hh], acc);
        if (base + node < n) out[(size_t)(base + node) * HEADS + hh] = acc;
    }
}

static inline size_t align256(size_t v) { return (v + 255) & ~(size_t)255; }

extern "C" void kernel_launch(void* const* d_in, const int* in_sizes, int n_in,
                              void* d_out, int out_size, void* d_ws, size_t ws_size,
                              hipStream_t stream) {
    const float* x = (const float*)d_in[0];
    const int* ei = (const int*)d_in[1];     // int32 on device (harness narrows int64)
    const float* w = (const float*)d_in[2];
    const float* Wxz = (const float*)d_in[3];
    const float* bz = (const float*)d_in[5];
    const float* Wxh = (const float*)d_in[9];
    const float* bh = (const float*)d_in[11];
    const float* Wlin = (const float*)d_in[12];
    const float* blin = (const float*)d_in[13];
    float* out = (float*)d_out;

    const int Nn = in_sizes[0] / CH;  // 50000
    const int E = in_sizes[2];        // 1,600,000

    const int* src = ei;
    const int* dst = ei + E;
    int eb = (E + 255) / 256;
    char* base = (char*)d_ws;

    // Tier A layout (aligned):
    size_t off_counts = 0;                                         // NR*NB u32
    size_t off_total = align256(off_counts + (size_t)NR * NB * 4); // NR u32
    size_t off_xh = align256(off_total + NR * 4);                  // N*CH half
    size_t off_xaggh = align256(off_xh + (size_t)Nn * CH * 2);     // N*CH half
    size_t off_wz = align256(off_xaggh + (size_t)Nn * CH * 2);     // CH*CH half
    size_t off_wh = align256(off_wz + (size_t)CH * CH * 2);        // CH*CH half
    size_t off_wl = align256(off_wh + (size_t)CH * CH * 2);        // HEADS*CH half
    size_t off_rec2 = align256(off_wl + (size_t)HEADS * CH * 2);   // E int2
    size_t off_rec3 = align256(off_rec2 + (size_t)E * 8);          // E u32 (overflow fallback)
    size_t needNew = off_rec3 + (size_t)E * 4;
    size_t partial_bytes = (size_t)4 * DSLICES * DRANGE * 4;       // 13.1MB, overlays rec2+rec3

    if (ws_size >= needNew && Nn <= 65536 && (size_t)NR * RN >= (size_t)Nn &&
        partial_bytes <= (size_t)E * 12) {
        unsigned* counts = (unsigned*)(base + off_counts);
        unsigned* total = (unsigned*)(base + off_total);
        __half* xh = (__half*)(base + off_xh);
        __half* xaggh = (__half*)(base + off_xaggh);
        __half* WzT = (__half*)(base + off_wz);
        __half* WhT = (__half*)(base + off_wh);
        __half* WlT = (__half*)(base + off_wl);
        int2* rec2 = (int2*)(base + off_rec2);
        unsigned* rec3 = (unsigned*)(base + off_rec3);
        float* partial = (float*)(base + off_rec2);  // overlay: dead after k_degxcw

        int nbdeg = (Nn + 255) / 256;
        int nbw = (CH * CH + HEADS * CH + 255) / 256;

        k_deg<<<4 * DSLICES, 256, 0, stream>>>(src, w, partial, E);
        k_degxcw<<<nbdeg + nbw, 256, 0, stream>>>(partial, x, xh, Wxz, Wxh, Wlin,
                                                  WzT, WhT, WlT, Nn, nbdeg);
        k_count<<<NB, 256, 0, stream>>>(dst, counts, E);
        k_scanR<<<NR, 256, 0, stream>>>(counts, total);
        k_part<<<NB, 256, 0, stream>>>(src, dst, w, counts, total, rec2, E);
        k_sortgather<<<NR, 1024, 0, stream>>>(total, rec2, rec3, xh, xaggh, Nn);
        k_final3<<<(Nn + 63) / 64, 256, 0, stream>>>(xaggh, WzT, WhT, WlT, bz, bh, blin, out, Nn);
    } else {
        // Tier B: CSR fallback (proven)
        unsigned* off = (unsigned*)base;
        float* deg_out = (float*)(base + (size_t)Nn * 4);
        int2* rec = (int2*)(base + (size_t)2 * Nn * 4);
        float* xagg = (float*)((char*)rec + (size_t)E * 8);

        hipMemsetAsync(d_ws, 0, (size_t)2 * Nn * 4, stream);
        k1B<<<eb, 256, 0, stream>>>(src, dst, w, deg_out, off, E);
        k_scan<<<1, 1024, 0, stream>>>(off, Nn);
        k_fillB<<<eb, 256, 0, stream>>>(src, dst, w, off, rec, E);
        k_gatherB<<<(Nn + 3) / 4, 256, 0, stream>>>(off, rec, deg_out, x, xagg, Nn);
        k_final2<<<(Nn + TM - 1) / TM, 256, 0, stream>>>(xagg, Wxz, bz, Wxh, bh, Wlin, blin, out, Nn);
    }
}

// Round 14
// 158.492 us; speedup vs baseline: 7.8245x; 1.0108x over previous
//
#include <hip/hip_runtime.h>
#include <hip/hip_bf16.h>
#include <hip/hip_fp16.h>

// GConvGRU with h=0 reduces to:
//   xagg = scatter_add(norm * x[src] -> dst)          [N,128]
//   z    = sigmoid(xagg @ W_xz + b_z)
//   ht   = tanh   (xagg @ W_xh + b_h)
//   out  = ((1-z)*ht) @ W_lin + b_lin                 [N,16]
// Model (R6-R13): scattered global writes cost 32B granules unless clustered;
// gather random 256B rows served at ~3TB/s beyond-L2 (ILP-null R12).
// R14: sortgather re-shaped to 512thr x 1024 blocks (RN=49) -> 4 blocks/CU,
//      100% occupancy (TLP axis test); count fused into degxcw kernel.

#define CH 128
#define HEADS 16
#define TM 64          // nodes per block in k_final2 (tier B)
#define KC 32          // K-chunk (tier B)
#define DRANGE 12800   // deg histogram: nodes per range (4 ranges)
#define DSLICES 64     // deg histogram: edge slices per range
#define RN 49          // nodes per partition range
#define NR 1024        // partition ranges (1024*49 >= 50000)
#define NB 256         // partition blocks (edge slices)
#define SCAP 2048      // sort stage capacity (mean ~1567, +12 sigma; global fallback)

typedef _Float16 half8 __attribute__((ext_vector_type(8)));
typedef _Float16 half4v __attribute__((ext_vector_type(4)));
typedef float floatx4 __attribute__((ext_vector_type(4)));

// =============== deg partials: LDS histogram over src ===============
__global__ __launch_bounds__(256) void k_deg(const int* __restrict__ src,
                                             const float* __restrict__ w,
                                             float* __restrict__ partial, int E) {
    __shared__ float h[DRANGE];
    const int r = blockIdx.x / DSLICES;
    const int sl = blockIdx.x % DSLICES;
    const int base = r * DRANGE;
    for (int i = threadIdx.x; i < DRANGE; i += 256) h[i] = 0.f;
    __syncthreads();
    const int per = (E + DSLICES - 1) / DSLICES;
    const int lo = sl * per;
    const int hi = min(lo + per, E);
    int e = lo + threadIdx.x * 4;
    for (; e + 3 < hi; e += 1024) {
        int4 s4 = *reinterpret_cast<const int4*>(src + e);
        float4 w4 = *reinterpret_cast<const float4*>(w + e);
        int a;
        a = s4.x - base; if ((unsigned)a < DRANGE) atomicAdd(&h[a], w4.x);
        a = s4.y - base; if ((unsigned)a < DRANGE) atomicAdd(&h[a], w4.y);
        a = s4.z - base; if ((unsigned)a < DRANGE) atomicAdd(&h[a], w4.z);
        a = s4.w - base; if ((unsigned)a < DRANGE) atomicAdd(&h[a], w4.w);
    }
    for (; e < hi; ++e) {
        int a = src[e] - base;
        if ((unsigned)a < DRANGE) atomicAdd(&h[a], w[e]);
    }
    __syncthreads();
    float* dstp = partial + ((size_t)r * DSLICES + sl) * DRANGE;
    for (int i = threadIdx.x; i < DRANGE; i += 256) dstp[i] = h[i];
}

// =============== fused: deg reduce + xh cast | weight cast | dst count ===============
__global__ __launch_bounds__(256) void k_dxcwc(const float* __restrict__ partial,
                                               const float* __restrict__ x,
                                               __half* __restrict__ xh,
                                               const float* __restrict__ Wxz,
                                               const float* __restrict__ Wxh,
                                               const float* __restrict__ Wlin,
                                               __half* __restrict__ WzT,
                                               __half* __restrict__ WhT,
                                               __half* __restrict__ WlT,
                                               const int* __restrict__ dst,
                                               unsigned* __restrict__ counts,
                                               int E, int n, int nbdeg, int nbw) {
    const int t = threadIdx.x;
    const int b = blockIdx.x;
    if (b >= nbdeg + nbw) {
        // dst-range count histogram (block cb of NB)
        __shared__ unsigned h[NR];
        const int cb = b - nbdeg - nbw;
        for (int i = t; i < NR; i += 256) h[i] = 0u;
        __syncthreads();
        const int per = (E + NB - 1) / NB;
        const int lo = cb * per;
        const int hi = min(lo + per, E);
        for (int e = lo + t; e < hi; e += 256)
            atomicAdd(&h[dst[e] / RN], 1u);
        __syncthreads();
        for (int i = t; i < NR; i += 256) counts[(size_t)i * NB + cb] = h[i];
        return;
    }
    if (b >= nbdeg) {
        // weight cast
        int i = (b - nbdeg) * 256 + t;
        if (i < CH * CH) {
            int nn = i >> 7, k = i & 127;
            WzT[i] = __float2half(Wxz[k * CH + nn]);
            WhT[i] = __float2half(Wxh[k * CH + nn]);
        } else if (i < CH * CH + HEADS * CH) {
            int j = i - CH * CH;
            int nn = j >> 7, k = j & 127;
            WlT[j] = __float2half(Wlin[k * HEADS + nn]);
        }
        return;
    }
    __shared__ float degl[256];
    const int bb = b * 256;
    int i = bb + t;
    if (i < n) {
        int r = i / DRANGE;
        int idx = i - r * DRANGE;
        const float* p = partial + (size_t)r * DSLICES * DRANGE + idx;
        float s = 0.f;
#pragma unroll 8
        for (int sl = 0; sl < DSLICES; ++sl) s += p[(size_t)sl * DRANGE];
        degl[t] = s;
    }
    __syncthreads();
#pragma unroll
    for (int g = 0; g < 16; ++g) {
        int ln = g * 16 + (t >> 4);
        int node = bb + ln;
        if (node >= n) break;
        int c8 = (t & 15) * 8;
        float dg = degl[ln];
        float sc = dg > 0.f ? rsqrtf(dg) : 0.f;
        float4 a = *reinterpret_cast<const float4*>(x + (size_t)node * CH + c8);
        float4 bq = *reinterpret_cast<const float4*>(x + (size_t)node * CH + c8 + 4);
        __half2 h0 = __floats2half2_rn(a.x * sc, a.y * sc);
        __half2 h1 = __floats2half2_rn(a.z * sc, a.w * sc);
        __half2 h2 = __floats2half2_rn(bq.x * sc, bq.y * sc);
        __half2 h3 = __floats2half2_rn(bq.z * sc, bq.w * sc);
        uint4 packed = make_uint4(*(unsigned*)&h0, *(unsigned*)&h1, *(unsigned*)&h2, *(unsigned*)&h3);
        *reinterpret_cast<uint4*>(xh + (size_t)node * CH + c8) = packed;
    }
}

// per-range exclusive scan over blocks
__global__ __launch_bounds__(256) void k_scanR(unsigned* __restrict__ counts,
                                               unsigned* __restrict__ total) {
    __shared__ unsigned s[256];
    const int r = blockIdx.x;
    const int t = threadIdx.x;
    unsigned v = counts[(size_t)r * NB + t];
    s[t] = v;
    __syncthreads();
    for (int ofs = 1; ofs < 256; ofs <<= 1) {
        unsigned u = (t >= ofs) ? s[t - ofs] : 0u;
        __syncthreads();
        s[t] += u;
        __syncthreads();
    }
    counts[(size_t)r * NB + t] = s[t] - v;
    if (t == 255) total[r] = s[255];
}

// =============== partition pass 2 (self-scans totals -> rbase) ===============
// rec2[pos] = { w(f32), dl<<16 | src }  (requires n <= 65536)
__global__ __launch_bounds__(256) void k_part(const int* __restrict__ src,
                                              const int* __restrict__ dst,
                                              const float* __restrict__ w,
                                              const unsigned* __restrict__ counts,
                                              const unsigned* __restrict__ total,
                                              int2* __restrict__ rec2, int E) {
    __shared__ unsigned cursor[NR];
    __shared__ unsigned sa[NR], sb[NR];
    const int b = blockIdx.x;
    const int t = threadIdx.x;
    for (int k = t; k < NR; k += 256) sa[k] = total[k];
    __syncthreads();
    unsigned* cur = sa; unsigned* nxt = sb;
    for (int ofs = 1; ofs < NR; ofs <<= 1) {
        for (int k = t; k < NR; k += 256) {
            unsigned v = cur[k];
            if (k >= ofs) v += cur[k - ofs];
            nxt[k] = v;
        }
        __syncthreads();
        unsigned* tmp = cur; cur = nxt; nxt = tmp;
    }
    for (int r = t; r < NR; r += 256) {
        unsigned rb = cur[r] - total[r];   // exclusive base
        cursor[r] = rb + counts[(size_t)r * NB + b];
    }
    __syncthreads();
    const int per = (E + NB - 1) / NB;
    const int lo = b * per;
    const int hi = min(lo + per, E);
    for (int e = lo + t; e < hi; e += 256) {
        int d = dst[e];
        int r = d / RN;
        int dl = d - r * RN;
        unsigned pos = atomicAdd(&cursor[r], 1u);
        rec2[pos] = make_int2(__float_as_int(w[e]), (dl << 16) | src[e]);
    }
}

// =============== fused sort + gather: 1024 blocks x 512 threads (4 blk/CU) ===============
__global__ __launch_bounds__(512) void k_sortgather(const unsigned* __restrict__ total,
                                                    const int2* __restrict__ rec2,
                                                    unsigned* __restrict__ rec3,
                                                    const __half* __restrict__ xh,
                                                    __half* __restrict__ xaggh, int n) {
    __shared__ int2 stage[SCAP];         // 16384 B
    __shared__ unsigned sortedP[SCAP];   // 8192 B
    __shared__ unsigned hist[RN], curx[RN];
    __shared__ unsigned sa[NR], sb[NR];  // 8192 B
    const int r = blockIdx.x;
    const int bn = r * RN;
    if (bn >= n) return;
    const int rn = min(RN, n - bn);
    const int t = threadIdx.x;

    // self-scan totals -> gbase
    sa[t] = total[t]; sa[t + 512] = total[t + 512];
    __syncthreads();
    unsigned* cur = sa; unsigned* nxt = sb;
    for (int ofs = 1; ofs < NR; ofs <<= 1) {
        for (int k = t; k < NR; k += 512) {
            unsigned v = cur[k];
            if (k >= ofs) v += cur[k - ofs];
            nxt[k] = v;
        }
        __syncthreads();
        unsigned* tmp = cur; cur = nxt; nxt = tmp;
    }
    const unsigned tot = total[r];
    const unsigned gbase = cur[r] - tot;

    // histogram + stage
    if (t < RN) hist[t] = 0u;
    __syncthreads();
    for (unsigned i = t; i < tot; i += 512) {
        int2 v = rec2[gbase + i];
        if (i < SCAP) stage[i] = v;
        atomicAdd(&hist[v.y >> 16], 1u);
    }
    __syncthreads();
    if (t == 0) {
        unsigned run = 0;
        for (int j = 0; j < rn; ++j) {
            unsigned c = hist[j];
            hist[j] = run;     // start (preserved)
            curx[j] = run;     // cursor -> becomes end
            run += c;
        }
    }
    __syncthreads();
    const bool big = (tot > SCAP);
    for (unsigned i = t; i < tot; i += 512) {
        int2 v = (i < SCAP) ? stage[i] : rec2[gbase + i];
        int dl = v.y >> 16;
        __half hw = __float2half(__int_as_float(v.x));
        unsigned packed = ((unsigned)__half_as_ushort(hw) << 16) | (unsigned)(v.y & 0xFFFF);
        unsigned pos = atomicAdd(&curx[dl], 1u);
        if (big) rec3[gbase + pos] = packed;
        else sortedP[pos] = packed;
    }
    __syncthreads();

    // gather: 16 half-waves; lane owns 4 channels
    const int hwid = t >> 5;
    const int lane = t & 31;
    const __half* xb = xh + lane * 4;
    const unsigned* grec = rec3 + gbase;
    for (int nd = hwid; nd < rn; nd += 16) {
        unsigned i = hist[nd];
        unsigned end = curx[nd];
        float acc0 = 0.f, acc1 = 0.f, acc2 = 0.f, acc3 = 0.f;
        float wsum = 0.f;
        for (; i + 8 <= end; i += 8) {
            unsigned r0, r1, r2, r3, r4, r5, r6, r7;
            if (big) {
                r0 = grec[i];     r1 = grec[i + 1]; r2 = grec[i + 2]; r3 = grec[i + 3];
                r4 = grec[i + 4]; r5 = grec[i + 5]; r6 = grec[i + 6]; r7 = grec[i + 7];
            } else {
                r0 = sortedP[i];     r1 = sortedP[i + 1]; r2 = sortedP[i + 2]; r3 = sortedP[i + 3];
                r4 = sortedP[i + 4]; r5 = sortedP[i + 5]; r6 = sortedP[i + 6]; r7 = sortedP[i + 7];
            }
            half4v v0 = *reinterpret_cast<const half4v*>(xb + (size_t)(r0 & 0xFFFFu) * CH);
            half4v v1 = *reinterpret_cast<const half4v*>(xb + (size_t)(r1 & 0xFFFFu) * CH);
            half4v v2 = *reinterpret_cast<const half4v*>(xb + (size_t)(r2 & 0xFFFFu) * CH);
            half4v v3 = *reinterpret_cast<const half4v*>(xb + (size_t)(r3 & 0xFFFFu) * CH);
            half4v v4 = *reinterpret_cast<const half4v*>(xb + (size_t)(r4 & 0xFFFFu) * CH);
            half4v v5 = *reinterpret_cast<const half4v*>(xb + (size_t)(r5 & 0xFFFFu) * CH);
            half4v v6 = *reinterpret_cast<const half4v*>(xb + (size_t)(r6 & 0xFFFFu) * CH);
            half4v v7 = *reinterpret_cast<const half4v*>(xb + (size_t)(r7 & 0xFFFFu) * CH);
            float w0 = __half2float(__ushort_as_half((unsigned short)(r0 >> 16)));
            float w1 = __half2float(__ushort_as_half((unsigned short)(r1 >> 16)));
            float w2 = __half2float(__ushort_as_half((unsigned short)(r2 >> 16)));
            float w3 = __half2float(__ushort_as_half((unsigned short)(r3 >> 16)));
            float w4 = __half2float(__ushort_as_half((unsigned short)(r4 >> 16)));
            float w5 = __half2float(__ushort_as_half((unsigned short)(r5 >> 16)));
            float w6 = __half2float(__ushort_as_half((unsigned short)(r6 >> 16)));
            float w7 = __half2float(__ushort_as_half((unsigned short)(r7 >> 16)));
            wsum += ((w0 + w1) + (w2 + w3)) + ((w4 + w5) + (w6 + w7));
            acc0 = fmaf(w0, (float)v0[0], acc0); acc1 = fmaf(w0, (float)v0[1], acc1);
            acc2 = fmaf(w0, (float)v0[2], acc2); acc3 = fmaf(w0, (float)v0[3], acc3);
            acc0 = fmaf(w1, (float)v1[0], acc0); acc1 = fmaf(w1, (float)v1[1], acc1);
            acc2 = fmaf(w1, (float)v1[2], acc2); acc3 = fmaf(w1, (float)v1[3], acc3);
            acc0 = fmaf(w2, (float)v2[0], acc0); acc1 = fmaf(w2, (float)v2[1], acc1);
            acc2 = fmaf(w2, (float)v2[2], acc2); acc3 = fmaf(w2, (float)v2[3], acc3);
            acc0 = fmaf(w3, (float)v3[0], acc0); acc1 = fmaf(w3, (float)v3[1], acc1);
            acc2 = fmaf(w3, (float)v3[2], acc2); acc3 = fmaf(w3, (float)v3[3], acc3);
            acc0 = fmaf(w4, (float)v4[0], acc0); acc1 = fmaf(w4, (float)v4[1], acc1);
            acc2 = fmaf(w4, (float)v4[2], acc2); acc3 = fmaf(w4, (float)v4[3], acc3);
            acc0 = fmaf(w5, (float)v5[0], acc0); acc1 = fmaf(w5, (float)v5[1], acc1);
            acc2 = fmaf(w5, (float)v5[2], acc2); acc3 = fmaf(w5, (float)v5[3], acc3);
            acc0 = fmaf(w6, (float)v6[0], acc0); acc1 = fmaf(w6, (float)v6[1], acc1);
            acc2 = fmaf(w6, (float)v6[2], acc2); acc3 = fmaf(w6, (float)v6[3], acc3);
            acc0 = fmaf(w7, (float)v7[0], acc0); acc1 = fmaf(w7, (float)v7[1], acc1);
            acc2 = fmaf(w7, (float)v7[2], acc2); acc3 = fmaf(w7, (float)v7[3], acc3);
        }
        for (; i < end; ++i) {
            unsigned r0 = big ? grec[i] : sortedP[i];
            float w0 = __half2float(__ushort_as_half((unsigned short)(r0 >> 16)));
            half4v v0 = *reinterpret_cast<const half4v*>(xb + (size_t)(r0 & 0xFFFFu) * CH);
            wsum += w0;
            acc0 = fmaf(w0, (float)v0[0], acc0); acc1 = fmaf(w0, (float)v0[1], acc1);
            acc2 = fmaf(w0, (float)v0[2], acc2); acc3 = fmaf(w0, (float)v0[3], acc3);
        }
        float sc = wsum > 0.f ? rsqrtf(wsum) : 0.f;
        half4v hv;
        hv[0] = (_Float16)(acc0 * sc); hv[1] = (_Float16)(acc1 * sc);
        hv[2] = (_Float16)(acc2 * sc); hv[3] = (_Float16)(acc3 * sc);
        *reinterpret_cast<half4v*>(xaggh + (size_t)(bn + nd) * CH + lane * 4) = hv;
    }
}

// =============== MFMA epilogue (R10, proven) ===============
__global__ __launch_bounds__(256) void k_final3(const __half* __restrict__ xaggh,
                                                const __half* __restrict__ WzT,
                                                const __half* __restrict__ WhT,
                                                const __half* __restrict__ WlT,
                                                const float* __restrict__ bz,
                                                const float* __restrict__ bh,
                                                const float* __restrict__ blin,
                                                float* __restrict__ out, int n) {
    __shared__ __half gL[4][16][136];
    const int tid = threadIdx.x;
    const int w = tid >> 6;
    const int l = tid & 63;
    const int lr = l & 15;
    const int lk = l >> 4;
    const int nodeb = blockIdx.x * 64 + w * 16;

    int arow = nodeb + lr;
    if (arow > n - 1) arow = n - 1;

    floatx4 accz[8], acch[8];
#pragma unroll
    for (int ct = 0; ct < 8; ++ct) {
        accz[ct] = (floatx4){0.f, 0.f, 0.f, 0.f};
        acch[ct] = (floatx4){0.f, 0.f, 0.f, 0.f};
    }

#pragma unroll
    for (int kc = 0; kc < 4; ++kc) {
        half8 a = *reinterpret_cast<const half8*>(xaggh + (size_t)arow * CH + kc * 32 + lk * 8);
#pragma unroll
        for (int ct = 0; ct < 8; ++ct) {
            half8 bzf = *reinterpret_cast<const half8*>(WzT + (ct * 16 + lr) * CH + kc * 32 + lk * 8);
            accz[ct] = __builtin_amdgcn_mfma_f32_16x16x32_f16(a, bzf, accz[ct], 0, 0, 0);
            half8 bhf = *reinterpret_cast<const half8*>(WhT + (ct * 16 + lr) * CH + kc * 32 + lk * 8);
            acch[ct] = __builtin_amdgcn_mfma_f32_16x16x32_f16(a, bhf, acch[ct], 0, 0, 0);
        }
    }

#pragma unroll
    for (int ct = 0; ct < 8; ++ct) {
        float bzv = bz[ct * 16 + lr];
        float bhv = bh[ct * 16 + lr];
#pragma unroll
        for (int r = 0; r < 4; ++r) {
            float zp = accz[ct][r] + bzv;
            float hp = acch[ct][r] + bhv;
            float g = (1.f - 1.f / (1.f + __expf(-zp))) * tanhf(hp);
            gL[w][lk * 4 + r][ct * 16 + lr] = __float2half(g);
        }
    }
    __syncthreads();

    floatx4 acco = (floatx4){0.f, 0.f, 0.f, 0.f};
#pragma unroll
    for (int kc = 0; kc < 4; ++kc) {
        half8 a = *reinterpret_cast<const half8*>(&gL[w][lr][kc * 32 + lk * 8]);
        half8 b = *reinterpret_cast<const half8*>(WlT + lr * CH + kc * 32 + lk * 8);
        acco = __builtin_amdgcn_mfma_f32_16x16x32_f16(a, b, acco, 0, 0, 0);
    }
    float bl = blin[lr];
#pragma unroll
    for (int r = 0; r < 4; ++r) {
        int node = nodeb + lk * 4 + r;
        if (node < n) out[(size_t)node * HEADS + lr] = acco[r] + bl;
    }
}

// =============== Tier B (CSR fallback, proven) ===============
__global__ __launch_bounds__(256) void k1B(const int* __restrict__ src,
                                           const int* __restrict__ dst,
                                           const float* __restrict__ w,
                                           float* __restrict__ deg_out,
                                           unsigned* __restrict__ cnt, int E) {
    int e = blockIdx.x * blockDim.x + threadIdx.x;
    if (e >= E) return;
    unsafeAtomicAdd(deg_out + src[e], w[e]);
    atomicAdd(cnt + dst[e], 1u);
}

__global__ __launch_bounds__(1024) void k_scan(unsigned* __restrict__ off, int n) {
    __shared__ unsigned s[1024];
    const int t = threadIdx.x;
    const int per = (n + 1023) / 1024;
    int lo = t * per;
    int hi = lo + per; if (hi > n) hi = n;
    unsigned sum = 0;
    for (int i = lo; i < hi; ++i) sum += off[i];
    s[t] = sum;
    __syncthreads();
    for (int ofs = 1; ofs < 1024; ofs <<= 1) {
        unsigned v = (t >= ofs) ? s[t - ofs] : 0u;
        __syncthreads();
        s[t] += v;
        __syncthreads();
    }
    unsigned run = s[t] - sum;
    for (int i = lo; i < hi; ++i) {
        unsigned c = off[i];
        off[i] = run;
        run += c;
    }
}

__global__ __launch_bounds__(256) void k_fillB(const int* __restrict__ src,
                                               const int* __restrict__ dst,
                                               const float* __restrict__ w,
                                               unsigned* __restrict__ off,
                                               int2* __restrict__ rec, int E) {
    int e = blockIdx.x * blockDim.x + threadIdx.x;
    if (e >= E) return;
    unsigned pos = atomicAdd(off + dst[e], 1u);
    rec[pos] = make_int2(__float_as_int(w[e]), src[e]);
}

__global__ __launch_bounds__(256) void k_gatherB(const unsigned* __restrict__ off,
                                                 const int2* __restrict__ rec,
                                                 const float* __restrict__ deg_out,
                                                 const float* __restrict__ x,
                                                 float* __restrict__ xagg, int n) {
    int node = blockIdx.x * 4 + (threadIdx.x >> 6);
    if (node >= n) return;
    int lane = threadIdx.x & 63;
    unsigned i = node ? off[node - 1] : 0u;
    unsigned end = off[node];
    float2 acc = make_float2(0.f, 0.f);
    float wsum = 0.f;
    for (; i < end; ++i) {
        int2 r0 = rec[i];
        float w0 = __int_as_float(r0.x);
        float d0 = deg_out[r0.y];
        float c0 = w0 * (d0 > 0.f ? rsqrtf(d0) : 0.f);
        float2 v = *reinterpret_cast<const float2*>(x + (size_t)r0.y * CH + lane * 2);
        wsum += w0;
        acc.x = fmaf(c0, v.x, acc.x);
        acc.y = fmaf(c0, v.y, acc.y);
    }
    float sc = wsum > 0.f ? rsqrtf(wsum) : 0.f;
    *reinterpret_cast<float2*>(xagg + (size_t)node * CH + lane * 2) =
        make_float2(acc.x * sc, acc.y * sc);
}

__global__ __launch_bounds__(256) void k_final2(const float* __restrict__ xagg,
                                                const float* __restrict__ Wxz,
                                                const float* __restrict__ bz,
                                                const float* __restrict__ Wxh,
                                                const float* __restrict__ bh,
                                                const float* __restrict__ Wlin,
                                                const float* __restrict__ blin,
                                                float* __restrict__ out, int n) {
    __shared__ float smem[10560];
    float* sA = smem;
    float* sWz = smem + 2304;
    float* sWh = smem + 6400;

    const int tid = threadIdx.x;
    const int tx = tid & 31;
    const int ty = tid >> 5;
    const int base = blockIdx.x * TM;

    float az[8][4] = {{0.f}};
    float ah[8][4] = {{0.f}};

    for (int kc = 0; kc < CH; kc += KC) {
        {
            int i = tid;
#pragma unroll
            for (int r2 = 0; r2 < 2; ++r2, i += 256) {
                int row = i >> 3;
                int c4 = (i & 7) * 4;
                int grow = base + row; if (grow > n - 1) grow = n - 1;
                float4 v = *reinterpret_cast<const float4*>(xagg + (size_t)grow * CH + kc + c4);
                *reinterpret_cast<float4*>(&sA[row * 36 + c4]) = v;
            }
            int j = tid;
#pragma unroll
            for (int r2 = 0; r2 < 4; ++r2, j += 256) {
                int row = j >> 5;
                int c4 = (j & 31) * 4;
                *reinterpret_cast<float4*>(&sWz[row * 128 + c4]) =
                    *reinterpret_cast<const float4*>(Wxz + (size_t)(kc + row) * CH + c4);
                *reinterpret_cast<float4*>(&sWh[row * 128 + c4]) =
                    *reinterpret_cast<const float4*>(Wxh + (size_t)(kc + row) * CH + c4);
            }
        }
        __syncthreads();
#pragma unroll 4
        for (int kk = 0; kk < KC; ++kk) {
            float4 wz = *reinterpret_cast<float4*>(&sWz[kk * 128 + tx * 4]);
            float4 wh = *reinterpret_cast<float4*>(&sWh[kk * 128 + tx * 4]);
#pragma unroll
            for (int r = 0; r < 8; ++r) {
                float a = sA[(ty * 8 + r) * 36 + kk];
                az[r][0] = fmaf(a, wz.x, az[r][0]);
                az[r][1] = fmaf(a, wz.y, az[r][1]);
                az[r][2] = fmaf(a, wz.z, az[r][2]);
                az[r][3] = fmaf(a, wz.w, az[r][3]);
                ah[r][0] = fmaf(a, wh.x, ah[r][0]);
                ah[r][1] = fmaf(a, wh.y, ah[r][1]);
                ah[r][2] = fmaf(a, wh.z, ah[r][2]);
                ah[r][3] = fmaf(a, wh.w, ah[r][3]);
            }
        }
        __syncthreads();
    }

    float* sG = smem;
    const float4 bz4 = *reinterpret_cast<const float4*>(bz + tx * 4);
    const float4 bh4 = *reinterpret_cast<const float4*>(bh + tx * 4);
#pragma unroll
    for (int r = 0; r < 8; ++r) {
        int row = ty * 8 + r;
        float4 g4;
        float zp = az[r][0] + bz4.x, hp = ah[r][0] + bh4.x;
        g4.x = (1.f - 1.f / (1.f + __expf(-zp))) * tanhf(hp);
        zp = az[r][1] + bz4.y; hp = ah[r][1] + bh4.y;
        g4.y = (1.f - 1.f / (1.f + __expf(-zp))) * tanhf(hp);
        zp = az[r][2] + bz4.z; hp = ah[r][2] + bh4.z;
        g4.z = (1.f - 1.f / (1.f + __expf(-zp))) * tanhf(hp);
        zp = az[r][3] + bz4.w; hp = ah[r][3] + bh4.w;
        g4.w = (1.f - 1.f / (1.f + __expf(-zp))) * tanhf(hp);
        *reinterpret_cast<float4*>(&sG[row * 132 + tx * 4]) = g4;
    }
    __syncthreads();

#pragma unroll
    for (int it = 0; it < 4; ++it) {
        int idx = it * 256 + tid;
        int node = idx >> 4;
        int hh = idx & 15;
        float acc = blin[hh];
#pragma unroll 8
        for (int j = 0; j < CH; ++j)
            acc = fmaf(sG[node * 132 + j], Wlin[j * HEADS + hh], acc);
        if (base + node < n) out[(size_t)(base + node) * HEADS + hh] = acc;
    }
}

static inline size_t align256(size_t v) { return (v + 255) & ~(size_t)255; }

extern "C" void kernel_launch(void* const* d_in, const int* in_sizes, int n_in,
                              void* d_out, int out_size, void* d_ws, size_t ws_size,
                              hipStream_t stream) {
    const float* x = (const float*)d_in[0];
    const int* ei = (const int*)d_in[1];     // int32 on device (harness narrows int64)
    const float* w = (const float*)d_in[2];
    const float* Wxz = (const float*)d_in[3];
    const float* bz = (const float*)d_in[5];
    const float* Wxh = (const float*)d_in[9];
    const float* bh = (const float*)d_in[11];
    const float* Wlin = (const float*)d_in[12];
    const float* blin = (const float*)d_in[13];
    float* out = (float*)d_out;

    const int Nn = in_sizes[0] / CH;  // 50000
    const int E = in_sizes[2];        // 1,600,000

    const int* src = ei;
    const int* dst = ei + E;
    int eb = (E + 255) / 256;
    char* base = (char*)d_ws;

    // Tier A layout (aligned):
    size_t off_counts = 0;                                         // NR*NB u32 (1MB)
    size_t off_total = align256(off_counts + (size_t)NR * NB * 4); // NR u32
    size_t off_xh = align256(off_total + NR * 4);                  // N*CH half
    size_t off_xaggh = align256(off_xh + (size_t)Nn * CH * 2);     // N*CH half
    size_t off_wz = align256(off_xaggh + (size_t)Nn * CH * 2);     // CH*CH half
    size_t off_wh = align256(off_wz + (size_t)CH * CH * 2);        // CH*CH half
    size_t off_wl = align256(off_wh + (size_t)CH * CH * 2);        // HEADS*CH half
    size_t off_rec2 = align256(off_wl + (size_t)HEADS * CH * 2);   // E int2
    size_t off_rec3 = align256(off_rec2 + (size_t)E * 8);          // E u32 (overflow fallback)
    size_t needNew = off_rec3 + (size_t)E * 4;
    size_t partial_bytes = (size_t)4 * DSLICES * DRANGE * 4;       // 13.1MB, overlays rec2+rec3

    if (ws_size >= needNew && Nn <= 65536 && (size_t)NR * RN >= (size_t)Nn &&
        partial_bytes <= (size_t)E * 12) {
        unsigned* counts = (unsigned*)(base + off_counts);
        unsigned* total = (unsigned*)(base + off_total);
        __half* xh = (__half*)(base + off_xh);
        __half* xaggh = (__half*)(base + off_xaggh);
        __half* WzT = (__half*)(base + off_wz);
        __half* WhT = (__half*)(base + off_wh);
        __half* WlT = (__half*)(base + off_wl);
        int2* rec2 = (int2*)(base + off_rec2);
        unsigned* rec3 = (unsigned*)(base + off_rec3);
        float* partial = (float*)(base + off_rec2);  // overlay: dead after k_dxcwc

        int nbdeg = (Nn + 255) / 256;
        int nbw = (CH * CH + HEADS * CH + 255) / 256;

        k_deg<<<4 * DSLICES, 256, 0, stream>>>(src, w, partial, E);
        k_dxcwc<<<nbdeg + nbw + NB, 256, 0, stream>>>(partial, x, xh, Wxz, Wxh, Wlin,
                                                      WzT, WhT, WlT, dst, counts,
                                                      E, Nn, nbdeg, nbw);
        k_scanR<<<NR, 256, 0, stream>>>(counts, total);
        k_part<<<NB, 256, 0, stream>>>(src, dst, w, counts, total, rec2, E);
        k_sortgather<<<NR, 512, 0, stream>>>(total, rec2, rec3, xh, xaggh, Nn);
        k_final3<<<(Nn + 63) / 64, 256, 0, stream>>>(xaggh, WzT, WhT, WlT, bz, bh, blin, out, Nn);
    } else {
        // Tier B: CSR fallback (proven)
        unsigned* off = (unsigned*)base;
        float* deg_out = (float*)(base + (size_t)Nn * 4);
        int2* rec = (int2*)(base + (size_t)2 * Nn * 4);
        float* xagg = (float*)((char*)rec + (size_t)E * 8);

        hipMemsetAsync(d_ws, 0, (size_t)2 * Nn * 4, stream);
        k1B<<<eb, 256, 0, stream>>>(src, dst, w, deg_out, off, E);
        k_scan<<<1, 1024, 0, stream>>>(off, Nn);
        k_fillB<<<eb, 256, 0, stream>>>(src, dst, w, off, rec, E);
        k_gatherB<<<(Nn + 3) / 4, 256, 0, stream>>>(off, rec, deg_out, x, xagg, Nn);
        k_final2<<<(Nn + TM - 1) / TM, 256, 0, stream>>>(xagg, Wxz, bz, Wxh, bh, Wlin, blin, out, Nn);
    }
}